// Round 14
// baseline (1136.262 us; speedup 1.0000x reference)
//
#include <hip/hip_runtime.h>

typedef float f32x4 __attribute__((ext_vector_type(4)));
typedef float f32x16 __attribute__((ext_vector_type(16)));
typedef _Float16 f16x8 __attribute__((ext_vector_type(8)));
typedef _Float16 f16x4 __attribute__((ext_vector_type(4)));
typedef _Float16 f16x2 __attribute__((ext_vector_type(2)));

typedef __attribute__((address_space(1))) const unsigned char gbyte;
typedef __attribute__((address_space(3))) unsigned char sbyte;
__device__ __forceinline__ void gload_lds16(const void* gp, void* lp) {
  __builtin_amdgcn_global_load_lds((gbyte*)gp, (sbyte*)lp, 16, 0, 0);
}

// packed f16 dot2 with f32 accumulate (v_dot2_f32_f16); fallback = R8 numerics
#if __has_builtin(__builtin_amdgcn_fdot2)
__device__ __forceinline__ float fdot2(f16x2 a, f16x2 b, float c) {
  return __builtin_amdgcn_fdot2(a, b, c, false);
}
#else
__device__ __forceinline__ float fdot2(f16x2 a, f16x2 b, float c) {
  return c + (float)a[0] * (float)b[0] + (float)a[1] * (float)b[1];
}
#endif

// ---------------- 1. weight-pool transpose to [d][o][i], f32 ----------------
__global__ __launch_bounds__(256) void k_wpoolT(const float* __restrict__ gwp,
                                                const float* __restrict__ uwp,
                                                float* __restrict__ wtg,
                                                float* __restrict__ wtu) {
  int idx = blockIdx.x * 256 + threadIdx.x;
  if (idx < 16 * 128 * 128) {
    int d = idx >> 14, rem = idx & 16383, o = rem >> 7, i = rem & 127;
    wtg[idx] = gwp[(d << 14) + (i << 7) + o];          // gwp[d][i][o]
  } else {
    int j = idx - 16 * 128 * 128;
    if (j < 16 * 64 * 128) {
      int d = j >> 13, rem = j & 8191, o = rem >> 7, i = rem & 127;
      wtu[j] = uwp[(d << 13) + (i << 6) + o];          // uwp[d][i][o(64)]
    }
  }
}

// ---------------- 2. supports = softmax(relu(E E^T)) row-wise, f16 ----------
__global__ __launch_bounds__(256) void k_supports(const float* __restrict__ emb,
                                                  _Float16* __restrict__ S) {
  int n = blockIdx.x, tid = threadIdx.x;
  float en[16];
#pragma unroll
  for (int d = 0; d < 16; d++) en[d] = emb[n * 16 + d];
  float v[16];
  float sum = 0.f;
#pragma unroll
  for (int i = 0; i < 16; i++) {
    int m = i * 256 + tid;
    const float* em = emb + m * 16;
    float acc = 0.f;
#pragma unroll
    for (int d = 0; d < 16; d++) acc += en[d] * em[d];
    acc = fmaxf(acc, 0.f);
    float e = __expf(acc);
    v[i] = e;
    sum += e;
  }
#pragma unroll
  for (int off = 32; off > 0; off >>= 1) sum += __shfl_down(sum, off);
  __shared__ float red[4];
  if ((tid & 63) == 0) red[tid >> 6] = sum;
  __syncthreads();
  float inv = 1.f / (red[0] + red[1] + red[2] + red[3]);
#pragma unroll
  for (int i = 0; i < 16; i++) S[n * 4096 + i * 256 + tid] = (_Float16)(v[i] * inv);
}

// ------- 3. xs_t[b][c][m] = f16(concat(x,state))  (c-major for GEMM B) ------
__global__ __launch_bounds__(256) void k_concat(const float* __restrict__ x,
                                                const float* __restrict__ st,
                                                _Float16* __restrict__ xs_t) {
  int m0 = blockIdx.x * 64, b = blockIdx.y, tid = threadIdx.x;
  __shared__ __attribute__((aligned(16))) _Float16 T[64][130];
#pragma unroll
  for (int i = 0; i < 16; i++) {
    int li = i * 256 + tid;
    int ml = li >> 6, c = li & 63;
    int base = (b * 4096 + m0 + ml) * 64 + c;
    T[ml][c] = (_Float16)x[base];
    T[ml][64 + c] = (_Float16)st[base];
  }
  __syncthreads();
  int cg = tid >> 3, mch = tid & 7;
#pragma unroll
  for (int cb = 0; cb < 4; cb++) {
    int c = cb * 32 + cg;
    f16x8 tmp;
#pragma unroll
    for (int j = 0; j < 8; j++) tmp[j] = T[mch * 8 + j][c];
    *reinterpret_cast<f16x8*>(&xs_t[(b * 128 + c) * 4096 + m0 + mch * 8]) = tmp;
  }
}

// -------- 4. GEMM1 (32x32x16, 128M x 256N tile = 2 batches, 2x2 waves of ----
// 64x128 wave-tiles). Per kk: af[2]+bf[4] -> 8 MFMA (0.75 KB LDS/MFMA) and
// each 2-barrier K-step covers 2x the FLOPs of the 128^2 tile. Staging +
// T2 XOR swizzle identical to R8/R11-proven path. B rows for the batch pair
// are contiguous in xs_t: global row = 256*bp + rt.
__global__ __launch_bounds__(256) void k_gemm(const _Float16* __restrict__ S,
                                              const _Float16* __restrict__ Xt,
                                              _Float16* __restrict__ Y) {
  int nt = blockIdx.x, bp = blockIdx.y;
  int tid = threadIdx.x, lane = tid & 63, w = tid >> 6;
  int wr = w >> 1, wc = w & 1;
  __shared__ __attribute__((aligned(16))) _Float16 As[128 * 64];
  __shared__ __attribute__((aligned(16))) _Float16 Bs[256 * 64];
  const _Float16* Sb = S + nt * 128 * 4096;
  const _Float16* Xb = Xt + (size_t)(256 * bp) * 4096;
  f32x16 acc[2][4];
#pragma unroll
  for (int fm = 0; fm < 2; fm++)
#pragma unroll
    for (int fn = 0; fn < 4; fn++)
#pragma unroll
      for (int q = 0; q < 16; q++) acc[fm][fn][q] = 0.f;

  int lrow = lane >> 3;                       // staging row-within-group
  int lcolsw = (((lane & 7) ^ lrow) * 8);     // pre-swizzled source column
  int r32 = lane & 31, hi32 = lane >> 5;
  int swz = (r32 & 7) * 8;                    // read-side XOR (elem units)
  for (int k0 = 0; k0 < 4096; k0 += 64) {
    __syncthreads();
#pragma unroll
    for (int i = 0; i < 4; i++) {             // A: 128 rows
      int j = w * 4 + i;
      int row = j * 8 + lrow;
      gload_lds16(Sb + row * 4096 + k0 + lcolsw, &As[j * 512]);
    }
#pragma unroll
    for (int i = 0; i < 8; i++) {             // B: 256 rows
      int j = w * 8 + i;
      int row = j * 8 + lrow;
      gload_lds16(Xb + (size_t)row * 4096 + k0 + lcolsw, &Bs[j * 512]);
    }
    __syncthreads();
#pragma unroll
    for (int kk = 0; kk < 4; kk++) {
      int col = (kk * 16 + hi32 * 8) ^ swz;
      f16x8 af[2], bf[4];
#pragma unroll
      for (int fm = 0; fm < 2; fm++)
        af[fm] = *reinterpret_cast<const f16x8*>(&As[(wr * 64 + fm * 32 + r32) * 64 + col]);
#pragma unroll
      for (int fn = 0; fn < 4; fn++)
        bf[fn] = *reinterpret_cast<const f16x8*>(&Bs[(wc * 128 + fn * 32 + r32) * 64 + col]);
#pragma unroll
      for (int fm = 0; fm < 2; fm++)
#pragma unroll
        for (int fn = 0; fn < 4; fn++)
          acc[fm][fn] = __builtin_amdgcn_mfma_f32_32x32x16_f16(af[fm], bf[fn], acc[fm][fn], 0, 0, 0);
    }
  }
#pragma unroll
  for (int fm = 0; fm < 2; fm++)
#pragma unroll
    for (int fn = 0; fn < 4; fn++)
#pragma unroll
      for (int reg = 0; reg < 16; reg++) {
        int row = nt * 128 + wr * 64 + fm * 32 + (reg & 3) + 8 * (reg >> 2) + 4 * hi32;
        int ct = wc * 128 + fn * 32 + r32;     // 0..255 tile col
        int batch = 2 * bp + (ct >> 7);
        int c = ct & 127;
        Y[((size_t)batch * 4096 + row) * 128 + c] = (_Float16)acc[fm][fn][reg];
      }
}

// -------- 4b. GEMM2 (half-N, 128x256 tile): c in [64,128) of 4 batches ------
// Bs row rt -> xs_t row 512*bp + (rt>>6)*128 + 64 + (rt&63). Core = k_gemm.
__global__ __launch_bounds__(256) void k_gemm2(const _Float16* __restrict__ S,
                                               const _Float16* __restrict__ Xt,
                                               _Float16* __restrict__ Y) {
  int nt = blockIdx.x, bp = blockIdx.y;
  int tid = threadIdx.x, lane = tid & 63, w = tid >> 6;
  int wr = w >> 1, wc = w & 1;
  __shared__ __attribute__((aligned(16))) _Float16 As[128 * 64];
  __shared__ __attribute__((aligned(16))) _Float16 Bs[256 * 64];
  const _Float16* Sb = S + nt * 128 * 4096;
  const _Float16* Xb = Xt + (size_t)(512 * bp + 64) * 4096;
  f32x16 acc[2][4];
#pragma unroll
  for (int fm = 0; fm < 2; fm++)
#pragma unroll
    for (int fn = 0; fn < 4; fn++)
#pragma unroll
      for (int q = 0; q < 16; q++) acc[fm][fn][q] = 0.f;

  int lrow = lane >> 3;
  int lcolsw = (((lane & 7) ^ lrow) * 8);
  int r32 = lane & 31, hi32 = lane >> 5;
  int swz = (r32 & 7) * 8;
  for (int k0 = 0; k0 < 4096; k0 += 64) {
    __syncthreads();
#pragma unroll
    for (int i = 0; i < 4; i++) {
      int j = w * 4 + i;
      int row = j * 8 + lrow;
      gload_lds16(Sb + row * 4096 + k0 + lcolsw, &As[j * 512]);
    }
#pragma unroll
    for (int i = 0; i < 8; i++) {
      int j = w * 8 + i;
      int rt = j * 8 + lrow;                               // 0..255 tile row
      int groff = ((rt >> 6) * 128 + (rt & 63)) * 4096;    // 4-batch map
      gload_lds16(Xb + (size_t)groff + k0 + lcolsw, &Bs[j * 512]);
    }
    __syncthreads();
#pragma unroll
    for (int kk = 0; kk < 4; kk++) {
      int col = (kk * 16 + hi32 * 8) ^ swz;
      f16x8 af[2], bf[4];
#pragma unroll
      for (int fm = 0; fm < 2; fm++)
        af[fm] = *reinterpret_cast<const f16x8*>(&As[(wr * 64 + fm * 32 + r32) * 64 + col]);
#pragma unroll
      for (int fn = 0; fn < 4; fn++)
        bf[fn] = *reinterpret_cast<const f16x8*>(&Bs[(wc * 128 + fn * 32 + r32) * 64 + col]);
#pragma unroll
      for (int fm = 0; fm < 2; fm++)
#pragma unroll
        for (int fn = 0; fn < 4; fn++)
          acc[fm][fn] = __builtin_amdgcn_mfma_f32_32x32x16_f16(af[fm], bf[fn], acc[fm][fn], 0, 0, 0);
    }
  }
#pragma unroll
  for (int fm = 0; fm < 2; fm++)
#pragma unroll
    for (int fn = 0; fn < 4; fn++)
#pragma unroll
      for (int reg = 0; reg < 16; reg++) {
        int row = nt * 128 + wr * 64 + fm * 32 + (reg & 3) + 8 * (reg >> 2) + 4 * hi32;
        int ct = wc * 128 + fn * 32 + r32;     // 0..255 tile col
        int batch = 4 * bp + (ct >> 6);
        int c = 64 + (ct & 63);
        Y[((size_t)batch * 4096 + row) * 128 + c] = (_Float16)acc[fm][fn][reg];
      }
}

// ---- 5a. k_wall: W_all[nn][o*i] = f16( sum_d E[n0+nn][d] * wt[d][o*i] ) ----
__global__ __launch_bounds__(256) void k_wall(const float* __restrict__ emb, int n0,
                                              const float* __restrict__ wt, int OI,
                                              _Float16* __restrict__ Wout) {
  int bx = blockIdx.x, by = blockIdx.y, tid = threadIdx.x;
  __shared__ float e_sh[64][16];
  {
    int node = tid >> 2, part = tid & 3;
    f32x4 v = *reinterpret_cast<const f32x4*>(emb + (n0 + bx * 64 + node) * 16 + part * 4);
    *reinterpret_cast<f32x4*>(&e_sh[node][part * 4]) = v;
  }
  __syncthreads();
  int oi0 = by * 2048 + tid * 8;
#pragma unroll
  for (int g = 0; g < 8; g++) {
    f32x4 a0[8], a1[8];
#pragma unroll
    for (int nn = 0; nn < 8; nn++) { a0[nn] = (f32x4){0,0,0,0}; a1[nn] = (f32x4){0,0,0,0}; }
#pragma unroll
    for (int d = 0; d < 16; d++) {
      const f32x4* p = reinterpret_cast<const f32x4*>(wt + d * OI + oi0);
      f32x4 v0 = p[0], v1 = p[1];
#pragma unroll
      for (int nn = 0; nn < 8; nn++) {
        float e = e_sh[g * 8 + nn][d];
        a0[nn] += e * v0;
        a1[nn] += e * v1;
      }
    }
#pragma unroll
    for (int nn = 0; nn < 8; nn++) {
      f16x8 pk;
#pragma unroll
      for (int q = 0; q < 4; q++) { pk[q] = (_Float16)a0[nn][q]; pk[4 + q] = (_Float16)a1[nn][q]; }
      *reinterpret_cast<f16x8*>(Wout + (size_t)(bx * 64 + g * 8 + nn) * OI + oi0) = pk;
    }
  }
}

// ---- 5b. gate (dot2 VALU, precomputed W chunk): sigmoid(x_g @ W_n + b_n) ---
__global__ __launch_bounds__(256) void k_gate(const _Float16* __restrict__ xg,   // [b][n][128]
                                              const float* __restrict__ emb,
                                              const _Float16* __restrict__ Wc,   // chunk [1024][128][128]
                                              const float* __restrict__ gbp,
                                              int n0,
                                              _Float16* __restrict__ zb,         // [n][b][64]
                                              _Float16* __restrict__ rb) {       // [n][b][64]
  int n = n0 + blockIdx.x, tid = threadIdx.x;
  __shared__ __attribute__((aligned(16))) _Float16 A[64][136];
  __shared__ __attribute__((aligned(16))) _Float16 W[128][140];
  __shared__ float bias_sh[128];
  // stage A
  {
    int b = tid >> 2, i0 = (tid & 3) * 32;
    const f16x8* s8 = reinterpret_cast<const f16x8*>(xg + (b * 4096 + n) * 128 + i0);
#pragma unroll
    for (int c = 0; c < 4; c++)
      *reinterpret_cast<f16x8*>(&A[b][i0 + c * 8]) = s8[c];
  }
  // stage W from global chunk (coalesced: 128 contiguous B per thread)
  {
    const _Float16* wrow = Wc + (size_t)blockIdx.x * 16384;
    int o = tid >> 1, ih = tid & 1;
#pragma unroll
    for (int k = 0; k < 8; k++) {
      f16x8 v = *reinterpret_cast<const f16x8*>(wrow + o * 128 + ih * 64 + k * 8);
      f16x4 lo = {v[0], v[1], v[2], v[3]}, hi = {v[4], v[5], v[6], v[7]};
      *reinterpret_cast<f16x4*>(&W[o][ih * 64 + k * 8]) = lo;
      *reinterpret_cast<f16x4*>(&W[o][ih * 64 + k * 8 + 4]) = hi;
    }
  }
  if (tid < 128) {
    float s = 0.f;
#pragma unroll
    for (int d = 0; d < 16; d++) s += emb[n * 16 + d] * gbp[d * 128 + tid];
    bias_sh[tid] = s;
  }
  __syncthreads();
  int b0 = tid & 15, o0 = (tid >> 4) * 8;
  float acc[4][8];
#pragma unroll
  for (int j = 0; j < 4; j++)
#pragma unroll
    for (int k = 0; k < 8; k++) acc[j][k] = bias_sh[o0 + k];
#pragma unroll
  for (int is = 0; is < 128; is += 8) {
    f16x8 av[4];
#pragma unroll
    for (int j = 0; j < 4; j++) av[j] = *reinterpret_cast<const f16x8*>(&A[b0 + j * 16][is]);
    f16x2 ap[4][4];
#pragma unroll
    for (int j = 0; j < 4; j++) {
      ap[j][0] = (f16x2){av[j][0], av[j][1]};
      ap[j][1] = (f16x2){av[j][2], av[j][3]};
      ap[j][2] = (f16x2){av[j][4], av[j][5]};
      ap[j][3] = (f16x2){av[j][6], av[j][7]};
    }
#pragma unroll
    for (int k = 0; k < 8; k++) {
      f16x4 wlo = *reinterpret_cast<const f16x4*>(&W[o0 + k][is]);
      f16x4 whi = *reinterpret_cast<const f16x4*>(&W[o0 + k][is + 4]);
      f16x2 w0 = (f16x2){wlo[0], wlo[1]}, w1 = (f16x2){wlo[2], wlo[3]};
      f16x2 w2 = (f16x2){whi[0], whi[1]}, w3 = (f16x2){whi[2], whi[3]};
#pragma unroll
      for (int j = 0; j < 4; j++) {
        float a = acc[j][k];
        a = fdot2(ap[j][0], w0, a);
        a = fdot2(ap[j][1], w1, a);
        a = fdot2(ap[j][2], w2, a);
        a = fdot2(ap[j][3], w3, a);
        acc[j][k] = a;
      }
    }
  }
#pragma unroll
  for (int j = 0; j < 4; j++) {
    int b = b0 + j * 16;
    f16x8 pk;
#pragma unroll
    for (int k = 0; k < 8; k++) pk[k] = (_Float16)(1.f / (1.f + __expf(-acc[j][k])));
    if (o0 < 64) *reinterpret_cast<f16x8*>(&zb[(n * 64 + b) * 64 + o0]) = pk;
    else         *reinterpret_cast<f16x8*>(&rb[(n * 64 + b) * 64 + (o0 - 64)]) = pk;
  }
}

// ------------- 6. xs_t[b][64+o][m] = f16(z[m][b][o] * state[b][m][o]) -------
__global__ __launch_bounds__(256) void k_cand(const _Float16* __restrict__ zb,
                                              const float* __restrict__ st,
                                              _Float16* __restrict__ xs_t) {
  int m0 = blockIdx.x * 64, b = blockIdx.y, tid = threadIdx.x;
  __shared__ __attribute__((aligned(16))) _Float16 T[64][66];
#pragma unroll
  for (int i = 0; i < 16; i++) {
    int li = i * 256 + tid, ml = li >> 6, o = li & 63;
    float z = (float)zb[((m0 + ml) * 64 + b) * 64 + o];
    float s = st[(b * 4096 + m0 + ml) * 64 + o];
    T[ml][o] = (_Float16)(z * s);
  }
  __syncthreads();
  int og = tid >> 3, mch = tid & 7;
#pragma unroll
  for (int cb = 0; cb < 2; cb++) {
    int o = cb * 32 + og;
    f16x8 tmp;
#pragma unroll
    for (int j = 0; j < 8; j++) tmp[j] = T[mch * 8 + j][o];
    *reinterpret_cast<f16x8*>(&xs_t[(b * 128 + 64 + o) * 4096 + m0 + mch * 8]) = tmp;
  }
}

// ---- 7. update (dot2 VALU, precomputed W chunk): hc=tanh(xg2 @ Wu_n + bu);
//      h = r*state + (1-r)*hc -> out. -----------------------------------------
__global__ __launch_bounds__(256) void k_upd(const _Float16* __restrict__ xg2,   // [b][n][128]
                                             const float* __restrict__ emb,
                                             const _Float16* __restrict__ Wc,    // chunk [2048][64][128]
                                             const float* __restrict__ ubp,
                                             int n0,
                                             const _Float16* __restrict__ rb,    // [n][b][64]
                                             const float* __restrict__ st,
                                             float* __restrict__ out) {
  int n = n0 + blockIdx.x, tid = threadIdx.x;
  __shared__ __attribute__((aligned(16))) _Float16 A[64][136];
  __shared__ __attribute__((aligned(16))) _Float16 W[64][140];
  __shared__ float bias_sh[64];
  // stage A
  {
    int b = tid >> 2, i0 = (tid & 3) * 32;
    const f16x8* s8 = reinterpret_cast<const f16x8*>(xg2 + (b * 4096 + n) * 128 + i0);
#pragma unroll
    for (int c = 0; c < 4; c++)
      *reinterpret_cast<f16x8*>(&A[b][i0 + c * 8]) = s8[c];
  }
  // stage W (quarter-row per thread, 64 contiguous B)
  {
    const _Float16* wrow = Wc + (size_t)blockIdx.x * 8192;
    int o = tid >> 2, q4 = tid & 3;
#pragma unroll
    for (int k = 0; k < 4; k++) {
      f16x8 v = *reinterpret_cast<const f16x8*>(wrow + o * 128 + q4 * 32 + k * 8);
      f16x4 lo = {v[0], v[1], v[2], v[3]}, hi = {v[4], v[5], v[6], v[7]};
      *reinterpret_cast<f16x4*>(&W[o][q4 * 32 + k * 8]) = lo;
      *reinterpret_cast<f16x4*>(&W[o][q4 * 32 + k * 8 + 4]) = hi;
    }
  }
  if (tid < 64) {
    float s = 0.f;
#pragma unroll
    for (int d = 0; d < 16; d++) s += emb[n * 16 + d] * ubp[d * 64 + tid];
    bias_sh[tid] = s;
  }
  __syncthreads();
  int b0 = tid & 15, o0 = (tid >> 4) * 4;
  float acc[4][4];
#pragma unroll
  for (int j = 0; j < 4; j++)
#pragma unroll
    for (int k = 0; k < 4; k++) acc[j][k] = bias_sh[o0 + k];
#pragma unroll
  for (int is = 0; is < 128; is += 8) {
    f16x8 av[4];
#pragma unroll
    for (int j = 0; j < 4; j++) av[j] = *reinterpret_cast<const f16x8*>(&A[b0 + j * 16][is]);
    f16x2 ap[4][4];
#pragma unroll
    for (int j = 0; j < 4; j++) {
      ap[j][0] = (f16x2){av[j][0], av[j][1]};
      ap[j][1] = (f16x2){av[j][2], av[j][3]};
      ap[j][2] = (f16x2){av[j][4], av[j][5]};
      ap[j][3] = (f16x2){av[j][6], av[j][7]};
    }
#pragma unroll
    for (int k = 0; k < 4; k++) {
      f16x4 wlo = *reinterpret_cast<const f16x4*>(&W[o0 + k][is]);
      f16x4 whi = *reinterpret_cast<const f16x4*>(&W[o0 + k][is + 4]);
      f16x2 w0 = (f16x2){wlo[0], wlo[1]}, w1 = (f16x2){wlo[2], wlo[3]};
      f16x2 w2 = (f16x2){whi[0], whi[1]}, w3 = (f16x2){whi[2], whi[3]};
#pragma unroll
      for (int j = 0; j < 4; j++) {
        float a = acc[j][k];
        a = fdot2(ap[j][0], w0, a);
        a = fdot2(ap[j][1], w1, a);
        a = fdot2(ap[j][2], w2, a);
        a = fdot2(ap[j][3], w3, a);
        acc[j][k] = a;
      }
    }
  }
#pragma unroll
  for (int j = 0; j < 4; j++) {
    int b = b0 + j * 16;
    const f32x4 s4 = *reinterpret_cast<const f32x4*>(&st[(b * 4096 + n) * 64 + o0]);
    f16x4 r4 = *reinterpret_cast<const f16x4*>(&rb[(n * 64 + b) * 64 + o0]);
    f32x4 o4;
#pragma unroll
    for (int k = 0; k < 4; k++) {
      float e2 = __expf(2.f * acc[j][k]);
      float hc = 1.f - 2.f / (e2 + 1.f);     // tanh
      float rr = (float)r4[k];
      o4[k] = rr * s4[k] + (1.f - rr) * hc;
    }
    *reinterpret_cast<f32x4*>(&out[(b * 4096 + n) * 64 + o0]) = o4;
  }
}

extern "C" void kernel_launch(void* const* d_in, const int* in_sizes, int n_in,
                              void* d_out, int out_size, void* d_ws, size_t ws_size,
                              hipStream_t stream) {
  const float* x   = (const float*)d_in[0];
  const float* st  = (const float*)d_in[1];
  const float* emb = (const float*)d_in[2];
  const float* gwp = (const float*)d_in[3];
  const float* gbp = (const float*)d_in[4];
  const float* uwp = (const float*)d_in[5];
  const float* ubp = (const float*)d_in[6];
  float* out = (float*)d_out;
  char* ws = (char*)d_ws;

  // slot A [0,33.55M): S for gemm1 -> W_all_g chunks -> S2 for gemm2
  _Float16* slotA = (_Float16*)(ws + 0);
  _Float16* xs_t  = (_Float16*)(ws + 33554432);   // 67 MB [b][c][m]
  _Float16* xg    = (_Float16*)(ws + 100663296);  // 67 MB (gemm1 out; gemm2 fills c>=64)
  _Float16* zb    = (_Float16*)(ws + 167772160);  // 33.5 MB [n][b][64]; -> W_all_u chunks after cand
  _Float16* rb    = (_Float16*)(ws + 201326592);  // 33.5 MB [n][b][64] (alive to upd)
  float* wtg = (float*)(ws + 234881024);          // 1 MB
  float* wtu = (float*)(ws + 235929600);          // 0.5 MB
  if (ws_size < 236453888ull) return;  // fail loudly rather than corrupt

  k_wpoolT<<<1536, 256, 0, stream>>>(gwp, uwp, wtg, wtu);
  k_supports<<<4096, 256, 0, stream>>>(emb, slotA);
  k_concat<<<dim3(64, 64), 256, 0, stream>>>(x, st, xs_t);
  k_gemm<<<dim3(32, 32), 256, 0, stream>>>(slotA, xs_t, xg);
  // gate in 4 chunks of 1024 nodes; W chunk (33.55 MB) reuses slot A (S dead)
  for (int c = 0; c < 4; c++) {
    k_wall<<<dim3(16, 8), 256, 0, stream>>>(emb, c * 1024, wtg, 16384, slotA);
    k_gate<<<1024, 256, 0, stream>>>(xg, emb, slotA, gbp, c * 1024, zb, rb);
  }
  k_cand<<<dim3(64, 64), 256, 0, stream>>>(zb, st, xs_t);
  k_supports<<<4096, 256, 0, stream>>>(emb, slotA);        // recompute S (cheap)
  // GEMM2: only the z*state half (c>=64); S@x half kept from GEMM1 in xg
  k_gemm2<<<dim3(32, 16), 256, 0, stream>>>(slotA, xs_t, xg);
  // update in 2 chunks of 2048 nodes; W chunk (33.55 MB) reuses zb slot (dead)
  for (int c = 0; c < 2; c++) {
    k_wall<<<dim3(32, 4), 256, 0, stream>>>(emb, c * 2048, wtu, 8192, zb);
    k_upd<<<2048, 256, 0, stream>>>(xg, emb, zb, ubp, c * 2048, rb, st, out);
  }
}

// Round 15
// 966.338 us; speedup vs baseline: 1.1758x; 1.1758x over previous
//
#include <hip/hip_runtime.h>

typedef float f32x4 __attribute__((ext_vector_type(4)));
typedef float f32x16 __attribute__((ext_vector_type(16)));
typedef _Float16 f16x8 __attribute__((ext_vector_type(8)));
typedef _Float16 f16x4 __attribute__((ext_vector_type(4)));
typedef _Float16 f16x2 __attribute__((ext_vector_type(2)));

typedef __attribute__((address_space(1))) const unsigned char gbyte;
typedef __attribute__((address_space(3))) unsigned char sbyte;
__device__ __forceinline__ void gload_lds16(const void* gp, void* lp) {
  __builtin_amdgcn_global_load_lds((gbyte*)gp, (sbyte*)lp, 16, 0, 0);
}

// packed f16 dot2 with f32 accumulate (v_dot2_f32_f16); fallback = R8 numerics
#if __has_builtin(__builtin_amdgcn_fdot2)
__device__ __forceinline__ float fdot2(f16x2 a, f16x2 b, float c) {
  return __builtin_amdgcn_fdot2(a, b, c, false);
}
#else
__device__ __forceinline__ float fdot2(f16x2 a, f16x2 b, float c) {
  return c + (float)a[0] * (float)b[0] + (float)a[1] * (float)b[1];
}
#endif

// ---------------- 1. weight-pool transpose to [d][o][i], f32 ----------------
__global__ __launch_bounds__(256) void k_wpoolT(const float* __restrict__ gwp,
                                                const float* __restrict__ uwp,
                                                float* __restrict__ wtg,
                                                float* __restrict__ wtu) {
  int idx = blockIdx.x * 256 + threadIdx.x;
  if (idx < 16 * 128 * 128) {
    int d = idx >> 14, rem = idx & 16383, o = rem >> 7, i = rem & 127;
    wtg[idx] = gwp[(d << 14) + (i << 7) + o];          // gwp[d][i][o]
  } else {
    int j = idx - 16 * 128 * 128;
    if (j < 16 * 64 * 128) {
      int d = j >> 13, rem = j & 8191, o = rem >> 7, i = rem & 127;
      wtu[j] = uwp[(d << 13) + (i << 6) + o];          // uwp[d][i][o(64)]
    }
  }
}

// ---------------- 2. supports = softmax(relu(E E^T)) row-wise, f16 ----------
__global__ __launch_bounds__(256) void k_supports(const float* __restrict__ emb,
                                                  _Float16* __restrict__ S) {
  int n = blockIdx.x, tid = threadIdx.x;
  float en[16];
#pragma unroll
  for (int d = 0; d < 16; d++) en[d] = emb[n * 16 + d];
  float v[16];
  float sum = 0.f;
#pragma unroll
  for (int i = 0; i < 16; i++) {
    int m = i * 256 + tid;
    const float* em = emb + m * 16;
    float acc = 0.f;
#pragma unroll
    for (int d = 0; d < 16; d++) acc += en[d] * em[d];
    acc = fmaxf(acc, 0.f);
    float e = __expf(acc);
    v[i] = e;
    sum += e;
  }
#pragma unroll
  for (int off = 32; off > 0; off >>= 1) sum += __shfl_down(sum, off);
  __shared__ float red[4];
  if ((tid & 63) == 0) red[tid >> 6] = sum;
  __syncthreads();
  float inv = 1.f / (red[0] + red[1] + red[2] + red[3]);
#pragma unroll
  for (int i = 0; i < 16; i++) S[n * 4096 + i * 256 + tid] = (_Float16)(v[i] * inv);
}

// ------- 3. xs_t[b][c][m] = f16(concat(x,state))  (c-major for GEMM B) ------
__global__ __launch_bounds__(256) void k_concat(const float* __restrict__ x,
                                                const float* __restrict__ st,
                                                _Float16* __restrict__ xs_t) {
  int m0 = blockIdx.x * 64, b = blockIdx.y, tid = threadIdx.x;
  __shared__ __attribute__((aligned(16))) _Float16 T[64][130];
#pragma unroll
  for (int i = 0; i < 16; i++) {
    int li = i * 256 + tid;
    int ml = li >> 6, c = li & 63;
    int base = (b * 4096 + m0 + ml) * 64 + c;
    T[ml][c] = (_Float16)x[base];
    T[ml][64 + c] = (_Float16)st[base];
  }
  __syncthreads();
  int cg = tid >> 3, mch = tid & 7;
#pragma unroll
  for (int cb = 0; cb < 4; cb++) {
    int c = cb * 32 + cg;
    f16x8 tmp;
#pragma unroll
    for (int j = 0; j < 8; j++) tmp[j] = T[mch * 8 + j][c];
    *reinterpret_cast<f16x8*>(&xs_t[(b * 128 + c) * 4096 + m0 + mch * 8]) = tmp;
  }
}

// -------- 4. GEMM1 (R11-proven: 32x32x16, 2x2 waves, single 32KB buffer) ----
__global__ __launch_bounds__(256) void k_gemm(const _Float16* __restrict__ S,
                                              const _Float16* __restrict__ Xt,
                                              _Float16* __restrict__ Y) {
  int nt = blockIdx.x, b = blockIdx.y;
  int tid = threadIdx.x, lane = tid & 63, w = tid >> 6;
  int wr = w >> 1, wc = w & 1;
  __shared__ __attribute__((aligned(16))) _Float16 As[128 * 64];
  __shared__ __attribute__((aligned(16))) _Float16 Bs[128 * 64];
  const _Float16* Sb = S + nt * 128 * 4096;
  const _Float16* Xb = Xt + b * 128 * 4096;
  f32x16 acc[2][2];
#pragma unroll
  for (int fm = 0; fm < 2; fm++)
#pragma unroll
    for (int fn = 0; fn < 2; fn++)
#pragma unroll
      for (int q = 0; q < 16; q++) acc[fm][fn][q] = 0.f;

  int lrow = lane >> 3;                       // staging row-within-group
  int lcolsw = (((lane & 7) ^ lrow) * 8);     // pre-swizzled source column
  int r32 = lane & 31, hi32 = lane >> 5;
  int swz = (r32 & 7) * 8;                    // read-side XOR (elem units)
  for (int k0 = 0; k0 < 4096; k0 += 64) {
    __syncthreads();
#pragma unroll
    for (int i = 0; i < 4; i++) {
      int j = w * 4 + i;
      int row = j * 8 + lrow;
      gload_lds16(Sb + row * 4096 + k0 + lcolsw, &As[j * 512]);
      gload_lds16(Xb + row * 4096 + k0 + lcolsw, &Bs[j * 512]);
    }
    __syncthreads();
#pragma unroll
    for (int kk = 0; kk < 4; kk++) {
      int col = (kk * 16 + hi32 * 8) ^ swz;
      f16x8 af[2], bf[2];
#pragma unroll
      for (int fm = 0; fm < 2; fm++)
        af[fm] = *reinterpret_cast<const f16x8*>(&As[(wr * 64 + fm * 32 + r32) * 64 + col]);
#pragma unroll
      for (int fn = 0; fn < 2; fn++)
        bf[fn] = *reinterpret_cast<const f16x8*>(&Bs[(wc * 64 + fn * 32 + r32) * 64 + col]);
#pragma unroll
      for (int fm = 0; fm < 2; fm++)
#pragma unroll
        for (int fn = 0; fn < 2; fn++)
          acc[fm][fn] = __builtin_amdgcn_mfma_f32_32x32x16_f16(af[fm], bf[fn], acc[fm][fn], 0, 0, 0);
    }
  }
#pragma unroll
  for (int fm = 0; fm < 2; fm++)
#pragma unroll
    for (int fn = 0; fn < 2; fn++)
#pragma unroll
      for (int reg = 0; reg < 16; reg++) {
        int row = nt * 128 + wr * 64 + fm * 32 + (reg & 3) + 8 * (reg >> 2) + 4 * hi32;
        int c = wc * 64 + fn * 32 + r32;
        Y[(b * 4096 + row) * 128 + c] = (_Float16)acc[fm][fn][reg];
      }
}

// -------- 4b. GEMM2 (R11-proven half-N): c in [64,128) of batch pair --------
__global__ __launch_bounds__(256) void k_gemm2(const _Float16* __restrict__ S,
                                               const _Float16* __restrict__ Xt,
                                               _Float16* __restrict__ Y) {
  int nt = blockIdx.x, bp = blockIdx.y;
  int tid = threadIdx.x, lane = tid & 63, w = tid >> 6;
  int wr = w >> 1, wc = w & 1;
  __shared__ __attribute__((aligned(16))) _Float16 As[128 * 64];
  __shared__ __attribute__((aligned(16))) _Float16 Bs[128 * 64];
  const _Float16* Sb = S + nt * 128 * 4096;
  const _Float16* Xb = Xt + (size_t)(256 * bp + 64) * 4096;
  f32x16 acc[2][2];
#pragma unroll
  for (int fm = 0; fm < 2; fm++)
#pragma unroll
    for (int fn = 0; fn < 2; fn++)
#pragma unroll
      for (int q = 0; q < 16; q++) acc[fm][fn][q] = 0.f;

  int lrow = lane >> 3;
  int lcolsw = (((lane & 7) ^ lrow) * 8);
  int r32 = lane & 31, hi32 = lane >> 5;
  int swz = (r32 & 7) * 8;
  for (int k0 = 0; k0 < 4096; k0 += 64) {
    __syncthreads();
#pragma unroll
    for (int i = 0; i < 4; i++) {
      int j = w * 4 + i;
      int row = j * 8 + lrow;                              // 0..127 tile row
      int groff = ((row >> 6) * 128 + (row & 63)) * 4096;  // batch-pair map
      gload_lds16(Sb + row * 4096 + k0 + lcolsw, &As[j * 512]);
      gload_lds16(Xb + groff + k0 + lcolsw, &Bs[j * 512]);
    }
    __syncthreads();
#pragma unroll
    for (int kk = 0; kk < 4; kk++) {
      int col = (kk * 16 + hi32 * 8) ^ swz;
      f16x8 af[2], bf[2];
#pragma unroll
      for (int fm = 0; fm < 2; fm++)
        af[fm] = *reinterpret_cast<const f16x8*>(&As[(wr * 64 + fm * 32 + r32) * 64 + col]);
#pragma unroll
      for (int fn = 0; fn < 2; fn++)
        bf[fn] = *reinterpret_cast<const f16x8*>(&Bs[(wc * 64 + fn * 32 + r32) * 64 + col]);
#pragma unroll
      for (int fm = 0; fm < 2; fm++)
#pragma unroll
        for (int fn = 0; fn < 2; fn++)
          acc[fm][fn] = __builtin_amdgcn_mfma_f32_32x32x16_f16(af[fm], bf[fn], acc[fm][fn], 0, 0, 0);
    }
  }
#pragma unroll
  for (int fm = 0; fm < 2; fm++)
#pragma unroll
    for (int fn = 0; fn < 2; fn++)
#pragma unroll
      for (int reg = 0; reg < 16; reg++) {
        int row = nt * 128 + wr * 64 + fm * 32 + (reg & 3) + 8 * (reg >> 2) + 4 * hi32;
        int ct = wc * 64 + fn * 32 + r32;       // 0..127 tile col
        int batch = 2 * bp + (ct >> 6);
        int c = 64 + (ct & 63);
        Y[((size_t)batch * 4096 + row) * 128 + c] = (_Float16)acc[fm][fn][reg];
      }
}

// ---- 5a. k_wall: W_all[nn][o*i] = f16( sum_d E[n0+nn][d] * wt[d][o*i] ) ----
__global__ __launch_bounds__(256) void k_wall(const float* __restrict__ emb, int n0,
                                              const float* __restrict__ wt, int OI,
                                              _Float16* __restrict__ Wout) {
  int bx = blockIdx.x, by = blockIdx.y, tid = threadIdx.x;
  __shared__ float e_sh[64][16];
  {
    int node = tid >> 2, part = tid & 3;
    f32x4 v = *reinterpret_cast<const f32x4*>(emb + (n0 + bx * 64 + node) * 16 + part * 4);
    *reinterpret_cast<f32x4*>(&e_sh[node][part * 4]) = v;
  }
  __syncthreads();
  int oi0 = by * 2048 + tid * 8;
#pragma unroll
  for (int g = 0; g < 8; g++) {
    f32x4 a0[8], a1[8];
#pragma unroll
    for (int nn = 0; nn < 8; nn++) { a0[nn] = (f32x4){0,0,0,0}; a1[nn] = (f32x4){0,0,0,0}; }
#pragma unroll
    for (int d = 0; d < 16; d++) {
      const f32x4* p = reinterpret_cast<const f32x4*>(wt + d * OI + oi0);
      f32x4 v0 = p[0], v1 = p[1];
#pragma unroll
      for (int nn = 0; nn < 8; nn++) {
        float e = e_sh[g * 8 + nn][d];
        a0[nn] += e * v0;
        a1[nn] += e * v1;
      }
    }
#pragma unroll
    for (int nn = 0; nn < 8; nn++) {
      f16x8 pk;
#pragma unroll
      for (int q = 0; q < 4; q++) { pk[q] = (_Float16)a0[nn][q]; pk[4 + q] = (_Float16)a1[nn][q]; }
      *reinterpret_cast<f16x8*>(Wout + (size_t)(bx * 64 + g * 8 + nn) * OI + oi0) = pk;
    }
  }
}

// ---- 5b. gate (MFMA, R11-proven staging/fragment patterns, precomputed W) --
// Block = node n. A = xg[:, n, :] (64x128), B = Wc[n] (128x128, [o][i]).
// K=128 in two 64-wide chunks staged exactly like k_gemm (global_load_lds,
// pre-swizzled source, read-side XOR). Wave w owns o-strip [w*32, w*32+32).
__global__ __launch_bounds__(256) void k_gate(const _Float16* __restrict__ xg,   // [b][n][128]
                                              const float* __restrict__ emb,
                                              const _Float16* __restrict__ Wc,   // chunk [1024][128][128]
                                              const float* __restrict__ gbp,
                                              int n0,
                                              _Float16* __restrict__ zb,         // [n][b][64]
                                              _Float16* __restrict__ rb) {       // [n][b][64]
  int n = n0 + blockIdx.x, tid = threadIdx.x, lane = tid & 63, w = tid >> 6;
  __shared__ __attribute__((aligned(16))) _Float16 As[64 * 64];
  __shared__ __attribute__((aligned(16))) _Float16 Bs[128 * 64];
  __shared__ float bias_sh[128];
  const _Float16* wrow = Wc + (size_t)blockIdx.x * 16384;
  if (tid < 128) {
    float s = 0.f;
#pragma unroll
    for (int d = 0; d < 16; d++) s += emb[n * 16 + d] * gbp[d * 128 + tid];
    bias_sh[tid] = s;
  }
  f32x16 acc[2];
#pragma unroll
  for (int fm = 0; fm < 2; fm++)
#pragma unroll
    for (int q = 0; q < 16; q++) acc[fm][q] = 0.f;

  int lrow = lane >> 3;                       // staging row-within-group
  int lcolsw = (((lane & 7) ^ lrow) * 8);     // pre-swizzled source column
  int r32 = lane & 31, hi32 = lane >> 5;
  int swz = (r32 & 7) * 8;                    // read-side XOR (elem units)
  for (int k0 = 0; k0 < 128; k0 += 64) {
    __syncthreads();
#pragma unroll
    for (int i = 0; i < 2; i++) {             // A: 64 rows (b)
      int j = w * 2 + i;
      int row = j * 8 + lrow;
      gload_lds16(xg + ((size_t)row * 4096 + n) * 128 + k0 + lcolsw, &As[j * 512]);
    }
#pragma unroll
    for (int i = 0; i < 4; i++) {             // B: 128 rows (o)
      int j = w * 4 + i;
      int row = j * 8 + lrow;
      gload_lds16(wrow + row * 128 + k0 + lcolsw, &Bs[j * 512]);
    }
    __syncthreads();
#pragma unroll
    for (int kk = 0; kk < 4; kk++) {
      int col = (kk * 16 + hi32 * 8) ^ swz;
      f16x8 bf = *reinterpret_cast<const f16x8*>(&Bs[(w * 32 + r32) * 64 + col]);
#pragma unroll
      for (int fm = 0; fm < 2; fm++) {
        f16x8 af = *reinterpret_cast<const f16x8*>(&As[(fm * 32 + r32) * 64 + col]);
        acc[fm] = __builtin_amdgcn_mfma_f32_32x32x16_f16(af, bf, acc[fm], 0, 0, 0);
      }
    }
  }
  int o = w * 32 + r32;                       // wave-uniform half: w<2 -> z
  float bias = bias_sh[o];
#pragma unroll
  for (int fm = 0; fm < 2; fm++)
#pragma unroll
    for (int reg = 0; reg < 16; reg++) {
      int brow = fm * 32 + (reg & 3) + 8 * (reg >> 2) + 4 * hi32;
      float val = acc[fm][reg] + bias;
      float sg = 1.f / (1.f + __expf(-val));
      if (o < 64) zb[(n * 64 + brow) * 64 + o] = (_Float16)sg;
      else        rb[(n * 64 + brow) * 64 + (o - 64)] = (_Float16)sg;
    }
}

// ------------- 6. xs_t[b][64+o][m] = f16(z[m][b][o] * state[b][m][o]) -------
__global__ __launch_bounds__(256) void k_cand(const _Float16* __restrict__ zb,
                                              const float* __restrict__ st,
                                              _Float16* __restrict__ xs_t) {
  int m0 = blockIdx.x * 64, b = blockIdx.y, tid = threadIdx.x;
  __shared__ __attribute__((aligned(16))) _Float16 T[64][66];
#pragma unroll
  for (int i = 0; i < 16; i++) {
    int li = i * 256 + tid, ml = li >> 6, o = li & 63;
    float z = (float)zb[((m0 + ml) * 64 + b) * 64 + o];
    float s = st[(b * 4096 + m0 + ml) * 64 + o];
    T[ml][o] = (_Float16)(z * s);
  }
  __syncthreads();
  int og = tid >> 3, mch = tid & 7;
#pragma unroll
  for (int cb = 0; cb < 2; cb++) {
    int o = cb * 32 + og;
    f16x8 tmp;
#pragma unroll
    for (int j = 0; j < 8; j++) tmp[j] = T[mch * 8 + j][o];
    *reinterpret_cast<f16x8*>(&xs_t[(b * 128 + 64 + o) * 4096 + m0 + mch * 8]) = tmp;
  }
}

// ---- 7. update (dot2 VALU, precomputed W chunk): hc=tanh(xg2 @ Wu_n + bu);
//      h = r*state + (1-r)*hc -> out. -----------------------------------------
__global__ __launch_bounds__(256) void k_upd(const _Float16* __restrict__ xg2,   // [b][n][128]
                                             const float* __restrict__ emb,
                                             const _Float16* __restrict__ Wc,    // chunk [2048][64][128]
                                             const float* __restrict__ ubp,
                                             int n0,
                                             const _Float16* __restrict__ rb,    // [n][b][64]
                                             const float* __restrict__ st,
                                             float* __restrict__ out) {
  int n = n0 + blockIdx.x, tid = threadIdx.x;
  __shared__ __attribute__((aligned(16))) _Float16 A[64][136];
  __shared__ __attribute__((aligned(16))) _Float16 W[64][140];
  __shared__ float bias_sh[64];
  // stage A
  {
    int b = tid >> 2, i0 = (tid & 3) * 32;
    const f16x8* s8 = reinterpret_cast<const f16x8*>(xg2 + (b * 4096 + n) * 128 + i0);
#pragma unroll
    for (int c = 0; c < 4; c++)
      *reinterpret_cast<f16x8*>(&A[b][i0 + c * 8]) = s8[c];
  }
  // stage W (quarter-row per thread, 64 contiguous B)
  {
    const _Float16* wrow = Wc + (size_t)blockIdx.x * 8192;
    int o = tid >> 2, q4 = tid & 3;
#pragma unroll
    for (int k = 0; k < 4; k++) {
      f16x8 v = *reinterpret_cast<const f16x8*>(wrow + o * 128 + q4 * 32 + k * 8);
      f16x4 lo = {v[0], v[1], v[2], v[3]}, hi = {v[4], v[5], v[6], v[7]};
      *reinterpret_cast<f16x4*>(&W[o][q4 * 32 + k * 8]) = lo;
      *reinterpret_cast<f16x4*>(&W[o][q4 * 32 + k * 8 + 4]) = hi;
    }
  }
  if (tid < 64) {
    float s = 0.f;
#pragma unroll
    for (int d = 0; d < 16; d++) s += emb[n * 16 + d] * ubp[d * 64 + tid];
    bias_sh[tid] = s;
  }
  __syncthreads();
  int b0 = tid & 15, o0 = (tid >> 4) * 4;
  float acc[4][4];
#pragma unroll
  for (int j = 0; j < 4; j++)
#pragma unroll
    for (int k = 0; k < 4; k++) acc[j][k] = bias_sh[o0 + k];
#pragma unroll
  for (int is = 0; is < 128; is += 8) {
    f16x8 av[4];
#pragma unroll
    for (int j = 0; j < 4; j++) av[j] = *reinterpret_cast<const f16x8*>(&A[b0 + j * 16][is]);
    f16x2 ap[4][4];
#pragma unroll
    for (int j = 0; j < 4; j++) {
      ap[j][0] = (f16x2){av[j][0], av[j][1]};
      ap[j][1] = (f16x2){av[j][2], av[j][3]};
      ap[j][2] = (f16x2){av[j][4], av[j][5]};
      ap[j][3] = (f16x2){av[j][6], av[j][7]};
    }
#pragma unroll
    for (int k = 0; k < 4; k++) {
      f16x4 wlo = *reinterpret_cast<const f16x4*>(&W[o0 + k][is]);
      f16x4 whi = *reinterpret_cast<const f16x4*>(&W[o0 + k][is + 4]);
      f16x2 w0 = (f16x2){wlo[0], wlo[1]}, w1 = (f16x2){wlo[2], wlo[3]};
      f16x2 w2 = (f16x2){whi[0], whi[1]}, w3 = (f16x2){whi[2], whi[3]};
#pragma unroll
      for (int j = 0; j < 4; j++) {
        float a = acc[j][k];
        a = fdot2(ap[j][0], w0, a);
        a = fdot2(ap[j][1], w1, a);
        a = fdot2(ap[j][2], w2, a);
        a = fdot2(ap[j][3], w3, a);
        acc[j][k] = a;
      }
    }
  }
#pragma unroll
  for (int j = 0; j < 4; j++) {
    int b = b0 + j * 16;
    const f32x4 s4 = *reinterpret_cast<const f32x4*>(&st[(b * 4096 + n) * 64 + o0]);
    f16x4 r4 = *reinterpret_cast<const f16x4*>(&rb[(n * 64 + b) * 64 + o0]);
    f32x4 o4;
#pragma unroll
    for (int k = 0; k < 4; k++) {
      float e2 = __expf(2.f * acc[j][k]);
      float hc = 1.f - 2.f / (e2 + 1.f);     // tanh
      float rr = (float)r4[k];
      o4[k] = rr * s4[k] + (1.f - rr) * hc;
    }
    *reinterpret_cast<f32x4*>(&out[(b * 4096 + n) * 64 + o0]) = o4;
  }
}

extern "C" void kernel_launch(void* const* d_in, const int* in_sizes, int n_in,
                              void* d_out, int out_size, void* d_ws, size_t ws_size,
                              hipStream_t stream) {
  const float* x   = (const float*)d_in[0];
  const float* st  = (const float*)d_in[1];
  const float* emb = (const float*)d_in[2];
  const float* gwp = (const float*)d_in[3];
  const float* gbp = (const float*)d_in[4];
  const float* uwp = (const float*)d_in[5];
  const float* ubp = (const float*)d_in[6];
  float* out = (float*)d_out;
  char* ws = (char*)d_ws;

  // slot A [0,33.55M): S for gemm1 -> W_all_g chunks -> S2 for gemm2
  _Float16* slotA = (_Float16*)(ws + 0);
  _Float16* xs_t  = (_Float16*)(ws + 33554432);   // 67 MB [b][c][m]
  _Float16* xg    = (_Float16*)(ws + 100663296);  // 67 MB (gemm1 out; gemm2 fills c>=64)
  _Float16* zb    = (_Float16*)(ws + 167772160);  // 33.5 MB [n][b][64]; -> W_all_u chunks after cand
  _Float16* rb    = (_Float16*)(ws + 201326592);  // 33.5 MB [n][b][64] (alive to upd)
  float* wtg = (float*)(ws + 234881024);          // 1 MB
  float* wtu = (float*)(ws + 235929600);          // 0.5 MB
  if (ws_size < 236453888ull) return;  // fail loudly rather than corrupt

  k_wpoolT<<<1536, 256, 0, stream>>>(gwp, uwp, wtg, wtu);
  k_supports<<<4096, 256, 0, stream>>>(emb, slotA);
  k_concat<<<dim3(64, 64), 256, 0, stream>>>(x, st, xs_t);
  k_gemm<<<dim3(32, 64), 256, 0, stream>>>(slotA, xs_t, xg);
  // gate in 4 chunks of 1024 nodes; W chunk (33.55 MB) reuses slot A (S dead)
  for (int c = 0; c < 4; c++) {
    k_wall<<<dim3(16, 8), 256, 0, stream>>>(emb, c * 1024, wtg, 16384, slotA);
    k_gate<<<1024, 256, 0, stream>>>(xg, emb, slotA, gbp, c * 1024, zb, rb);
  }
  k_cand<<<dim3(64, 64), 256, 0, stream>>>(zb, st, xs_t);
  k_supports<<<4096, 256, 0, stream>>>(emb, slotA);        // recompute S (cheap)
  // GEMM2: only the z*state half (c>=64); S@x half kept from GEMM1 in xg
  k_gemm2<<<dim3(32, 32), 256, 0, stream>>>(slotA, xs_t, xg);
  // update in 2 chunks of 2048 nodes; W chunk (33.55 MB) reuses zb slot (dead)
  for (int c = 0; c < 2; c++) {
    k_wall<<<dim3(32, 4), 256, 0, stream>>>(emb, c * 2048, wtu, 8192, zb);
    k_upd<<<2048, 256, 0, stream>>>(xg, emb, zb, ubp, c * 2048, rb, st, out);
  }
}

// Round 16
// 947.386 us; speedup vs baseline: 1.1994x; 1.0200x over previous
//
#include <hip/hip_runtime.h>

typedef float f32x4 __attribute__((ext_vector_type(4)));
typedef float f32x16 __attribute__((ext_vector_type(16)));
typedef _Float16 f16x8 __attribute__((ext_vector_type(8)));
typedef _Float16 f16x4 __attribute__((ext_vector_type(4)));
typedef _Float16 f16x2 __attribute__((ext_vector_type(2)));

typedef __attribute__((address_space(1))) const unsigned char gbyte;
typedef __attribute__((address_space(3))) unsigned char sbyte;
__device__ __forceinline__ void gload_lds16(const void* gp, void* lp) {
  __builtin_amdgcn_global_load_lds((gbyte*)gp, (sbyte*)lp, 16, 0, 0);
}

// ---------------- 1. weight-pool transpose to [d][o][i], f32 ----------------
__global__ __launch_bounds__(256) void k_wpoolT(const float* __restrict__ gwp,
                                                const float* __restrict__ uwp,
                                                float* __restrict__ wtg,
                                                float* __restrict__ wtu) {
  int idx = blockIdx.x * 256 + threadIdx.x;
  if (idx < 16 * 128 * 128) {
    int d = idx >> 14, rem = idx & 16383, o = rem >> 7, i = rem & 127;
    wtg[idx] = gwp[(d << 14) + (i << 7) + o];          // gwp[d][i][o]
  } else {
    int j = idx - 16 * 128 * 128;
    if (j < 16 * 64 * 128) {
      int d = j >> 13, rem = j & 8191, o = rem >> 7, i = rem & 127;
      wtu[j] = uwp[(d << 13) + (i << 6) + o];          // uwp[d][i][o(64)]
    }
  }
}

// ---------------- 2. supports = softmax(relu(E E^T)) row-wise, f16 ----------
__global__ __launch_bounds__(256) void k_supports(const float* __restrict__ emb,
                                                  _Float16* __restrict__ S) {
  int n = blockIdx.x, tid = threadIdx.x;
  float en[16];
#pragma unroll
  for (int d = 0; d < 16; d++) en[d] = emb[n * 16 + d];
  float v[16];
  float sum = 0.f;
#pragma unroll
  for (int i = 0; i < 16; i++) {
    int m = i * 256 + tid;
    const float* em = emb + m * 16;
    float acc = 0.f;
#pragma unroll
    for (int d = 0; d < 16; d++) acc += en[d] * em[d];
    acc = fmaxf(acc, 0.f);
    float e = __expf(acc);
    v[i] = e;
    sum += e;
  }
#pragma unroll
  for (int off = 32; off > 0; off >>= 1) sum += __shfl_down(sum, off);
  __shared__ float red[4];
  if ((tid & 63) == 0) red[tid >> 6] = sum;
  __syncthreads();
  float inv = 1.f / (red[0] + red[1] + red[2] + red[3]);
#pragma unroll
  for (int i = 0; i < 16; i++) S[n * 4096 + i * 256 + tid] = (_Float16)(v[i] * inv);
}

// ------- 3. xs_t[b][c][m] = f16(concat(x,state))  (c-major for GEMM B) ------
__global__ __launch_bounds__(256) void k_concat(const float* __restrict__ x,
                                                const float* __restrict__ st,
                                                _Float16* __restrict__ xs_t) {
  int m0 = blockIdx.x * 64, b = blockIdx.y, tid = threadIdx.x;
  __shared__ __attribute__((aligned(16))) _Float16 T[64][130];
#pragma unroll
  for (int i = 0; i < 16; i++) {
    int li = i * 256 + tid;
    int ml = li >> 6, c = li & 63;
    int base = (b * 4096 + m0 + ml) * 64 + c;
    T[ml][c] = (_Float16)x[base];
    T[ml][64 + c] = (_Float16)st[base];
  }
  __syncthreads();
  int cg = tid >> 3, mch = tid & 7;
#pragma unroll
  for (int cb = 0; cb < 4; cb++) {
    int c = cb * 32 + cg;
    f16x8 tmp;
#pragma unroll
    for (int j = 0; j < 8; j++) tmp[j] = T[mch * 8 + j][c];
    *reinterpret_cast<f16x8*>(&xs_t[(b * 128 + c) * 4096 + m0 + mch * 8]) = tmp;
  }
}

// -------- 4. GEMM1 (R11-proven: 32x32x16, 2x2 waves, single 32KB buffer) ----
__global__ __launch_bounds__(256) void k_gemm(const _Float16* __restrict__ S,
                                              const _Float16* __restrict__ Xt,
                                              _Float16* __restrict__ Y) {
  int nt = blockIdx.x, b = blockIdx.y;
  int tid = threadIdx.x, lane = tid & 63, w = tid >> 6;
  int wr = w >> 1, wc = w & 1;
  __shared__ __attribute__((aligned(16))) _Float16 As[128 * 64];
  __shared__ __attribute__((aligned(16))) _Float16 Bs[128 * 64];
  const _Float16* Sb = S + nt * 128 * 4096;
  const _Float16* Xb = Xt + b * 128 * 4096;
  f32x16 acc[2][2];
#pragma unroll
  for (int fm = 0; fm < 2; fm++)
#pragma unroll
    for (int fn = 0; fn < 2; fn++)
#pragma unroll
      for (int q = 0; q < 16; q++) acc[fm][fn][q] = 0.f;

  int lrow = lane >> 3;                       // staging row-within-group
  int lcolsw = (((lane & 7) ^ lrow) * 8);     // pre-swizzled source column
  int r32 = lane & 31, hi32 = lane >> 5;
  int swz = (r32 & 7) * 8;                    // read-side XOR (elem units)
  for (int k0 = 0; k0 < 4096; k0 += 64) {
    __syncthreads();
#pragma unroll
    for (int i = 0; i < 4; i++) {
      int j = w * 4 + i;
      int row = j * 8 + lrow;
      gload_lds16(Sb + row * 4096 + k0 + lcolsw, &As[j * 512]);
      gload_lds16(Xb + row * 4096 + k0 + lcolsw, &Bs[j * 512]);
    }
    __syncthreads();
#pragma unroll
    for (int kk = 0; kk < 4; kk++) {
      int col = (kk * 16 + hi32 * 8) ^ swz;
      f16x8 af[2], bf[2];
#pragma unroll
      for (int fm = 0; fm < 2; fm++)
        af[fm] = *reinterpret_cast<const f16x8*>(&As[(wr * 64 + fm * 32 + r32) * 64 + col]);
#pragma unroll
      for (int fn = 0; fn < 2; fn++)
        bf[fn] = *reinterpret_cast<const f16x8*>(&Bs[(wc * 64 + fn * 32 + r32) * 64 + col]);
#pragma unroll
      for (int fm = 0; fm < 2; fm++)
#pragma unroll
        for (int fn = 0; fn < 2; fn++)
          acc[fm][fn] = __builtin_amdgcn_mfma_f32_32x32x16_f16(af[fm], bf[fn], acc[fm][fn], 0, 0, 0);
    }
  }
#pragma unroll
  for (int fm = 0; fm < 2; fm++)
#pragma unroll
    for (int fn = 0; fn < 2; fn++)
#pragma unroll
      for (int reg = 0; reg < 16; reg++) {
        int row = nt * 128 + wr * 64 + fm * 32 + (reg & 3) + 8 * (reg >> 2) + 4 * hi32;
        int c = wc * 64 + fn * 32 + r32;
        Y[(b * 4096 + row) * 128 + c] = (_Float16)acc[fm][fn][reg];
      }
}

// -------- 4b. GEMM2 (R11-proven half-N): c in [64,128) of batch pair --------
__global__ __launch_bounds__(256) void k_gemm2(const _Float16* __restrict__ S,
                                               const _Float16* __restrict__ Xt,
                                               _Float16* __restrict__ Y) {
  int nt = blockIdx.x, bp = blockIdx.y;
  int tid = threadIdx.x, lane = tid & 63, w = tid >> 6;
  int wr = w >> 1, wc = w & 1;
  __shared__ __attribute__((aligned(16))) _Float16 As[128 * 64];
  __shared__ __attribute__((aligned(16))) _Float16 Bs[128 * 64];
  const _Float16* Sb = S + nt * 128 * 4096;
  const _Float16* Xb = Xt + (size_t)(256 * bp + 64) * 4096;
  f32x16 acc[2][2];
#pragma unroll
  for (int fm = 0; fm < 2; fm++)
#pragma unroll
    for (int fn = 0; fn < 2; fn++)
#pragma unroll
      for (int q = 0; q < 16; q++) acc[fm][fn][q] = 0.f;

  int lrow = lane >> 3;
  int lcolsw = (((lane & 7) ^ lrow) * 8);
  int r32 = lane & 31, hi32 = lane >> 5;
  int swz = (r32 & 7) * 8;
  for (int k0 = 0; k0 < 4096; k0 += 64) {
    __syncthreads();
#pragma unroll
    for (int i = 0; i < 4; i++) {
      int j = w * 4 + i;
      int row = j * 8 + lrow;                              // 0..127 tile row
      int groff = ((row >> 6) * 128 + (row & 63)) * 4096;  // batch-pair map
      gload_lds16(Sb + row * 4096 + k0 + lcolsw, &As[j * 512]);
      gload_lds16(Xb + groff + k0 + lcolsw, &Bs[j * 512]);
    }
    __syncthreads();
#pragma unroll
    for (int kk = 0; kk < 4; kk++) {
      int col = (kk * 16 + hi32 * 8) ^ swz;
      f16x8 af[2], bf[2];
#pragma unroll
      for (int fm = 0; fm < 2; fm++)
        af[fm] = *reinterpret_cast<const f16x8*>(&As[(wr * 64 + fm * 32 + r32) * 64 + col]);
#pragma unroll
      for (int fn = 0; fn < 2; fn++)
        bf[fn] = *reinterpret_cast<const f16x8*>(&Bs[(wc * 64 + fn * 32 + r32) * 64 + col]);
#pragma unroll
      for (int fm = 0; fm < 2; fm++)
#pragma unroll
        for (int fn = 0; fn < 2; fn++)
          acc[fm][fn] = __builtin_amdgcn_mfma_f32_32x32x16_f16(af[fm], bf[fn], acc[fm][fn], 0, 0, 0);
    }
  }
#pragma unroll
  for (int fm = 0; fm < 2; fm++)
#pragma unroll
    for (int fn = 0; fn < 2; fn++)
#pragma unroll
      for (int reg = 0; reg < 16; reg++) {
        int row = nt * 128 + wr * 64 + fm * 32 + (reg & 3) + 8 * (reg >> 2) + 4 * hi32;
        int ct = wc * 64 + fn * 32 + r32;       // 0..127 tile col
        int batch = 2 * bp + (ct >> 6);
        int c = 64 + (ct & 63);
        Y[((size_t)batch * 4096 + row) * 128 + c] = (_Float16)acc[fm][fn][reg];
      }
}

// ---- 5a. k_wall: W_all[nn][o*i] = f16( sum_d E[n0+nn][d] * wt[d][o*i] ) ----
__global__ __launch_bounds__(256) void k_wall(const float* __restrict__ emb, int n0,
                                              const float* __restrict__ wt, int OI,
                                              _Float16* __restrict__ Wout) {
  int bx = blockIdx.x, by = blockIdx.y, tid = threadIdx.x;
  __shared__ float e_sh[64][16];
  {
    int node = tid >> 2, part = tid & 3;
    f32x4 v = *reinterpret_cast<const f32x4*>(emb + (n0 + bx * 64 + node) * 16 + part * 4);
    *reinterpret_cast<f32x4*>(&e_sh[node][part * 4]) = v;
  }
  __syncthreads();
  int oi0 = by * 2048 + tid * 8;
#pragma unroll
  for (int g = 0; g < 8; g++) {
    f32x4 a0[8], a1[8];
#pragma unroll
    for (int nn = 0; nn < 8; nn++) { a0[nn] = (f32x4){0,0,0,0}; a1[nn] = (f32x4){0,0,0,0}; }
#pragma unroll
    for (int d = 0; d < 16; d++) {
      const f32x4* p = reinterpret_cast<const f32x4*>(wt + d * OI + oi0);
      f32x4 v0 = p[0], v1 = p[1];
#pragma unroll
      for (int nn = 0; nn < 8; nn++) {
        float e = e_sh[g * 8 + nn][d];
        a0[nn] += e * v0;
        a1[nn] += e * v1;
      }
    }
#pragma unroll
    for (int nn = 0; nn < 8; nn++) {
      f16x8 pk;
#pragma unroll
      for (int q = 0; q < 4; q++) { pk[q] = (_Float16)a0[nn][q]; pk[4 + q] = (_Float16)a1[nn][q]; }
      *reinterpret_cast<f16x8*>(Wout + (size_t)(bx * 64 + g * 8 + nn) * OI + oi0) = pk;
    }
  }
}

// ---- 5b. gate (MFMA, R15-proven): z_r = sigmoid(x_g @ W_n + b_n) -----------
__global__ __launch_bounds__(256) void k_gate(const _Float16* __restrict__ xg,   // [b][n][128]
                                              const float* __restrict__ emb,
                                              const _Float16* __restrict__ Wc,   // chunk [1024][128][128]
                                              const float* __restrict__ gbp,
                                              int n0,
                                              _Float16* __restrict__ zb,         // [n][b][64]
                                              _Float16* __restrict__ rb) {       // [n][b][64]
  int n = n0 + blockIdx.x, tid = threadIdx.x, lane = tid & 63, w = tid >> 6;
  __shared__ __attribute__((aligned(16))) _Float16 As[64 * 64];
  __shared__ __attribute__((aligned(16))) _Float16 Bs[128 * 64];
  __shared__ float bias_sh[128];
  const _Float16* wrow = Wc + (size_t)blockIdx.x * 16384;
  if (tid < 128) {
    float s = 0.f;
#pragma unroll
    for (int d = 0; d < 16; d++) s += emb[n * 16 + d] * gbp[d * 128 + tid];
    bias_sh[tid] = s;
  }
  f32x16 acc[2];
#pragma unroll
  for (int fm = 0; fm < 2; fm++)
#pragma unroll
    for (int q = 0; q < 16; q++) acc[fm][q] = 0.f;

  int lrow = lane >> 3;                       // staging row-within-group
  int lcolsw = (((lane & 7) ^ lrow) * 8);     // pre-swizzled source column
  int r32 = lane & 31, hi32 = lane >> 5;
  int swz = (r32 & 7) * 8;                    // read-side XOR (elem units)
  for (int k0 = 0; k0 < 128; k0 += 64) {
    __syncthreads();
#pragma unroll
    for (int i = 0; i < 2; i++) {             // A: 64 rows (b)
      int j = w * 2 + i;
      int row = j * 8 + lrow;
      gload_lds16(xg + ((size_t)row * 4096 + n) * 128 + k0 + lcolsw, &As[j * 512]);
    }
#pragma unroll
    for (int i = 0; i < 4; i++) {             // B: 128 rows (o)
      int j = w * 4 + i;
      int row = j * 8 + lrow;
      gload_lds16(wrow + row * 128 + k0 + lcolsw, &Bs[j * 512]);
    }
    __syncthreads();
#pragma unroll
    for (int kk = 0; kk < 4; kk++) {
      int col = (kk * 16 + hi32 * 8) ^ swz;
      f16x8 bf = *reinterpret_cast<const f16x8*>(&Bs[(w * 32 + r32) * 64 + col]);
#pragma unroll
      for (int fm = 0; fm < 2; fm++) {
        f16x8 af = *reinterpret_cast<const f16x8*>(&As[(fm * 32 + r32) * 64 + col]);
        acc[fm] = __builtin_amdgcn_mfma_f32_32x32x16_f16(af, bf, acc[fm], 0, 0, 0);
      }
    }
  }
  int o = w * 32 + r32;                       // wave-uniform half: w<2 -> z
  float bias = bias_sh[o];
#pragma unroll
  for (int fm = 0; fm < 2; fm++)
#pragma unroll
    for (int reg = 0; reg < 16; reg++) {
      int brow = fm * 32 + (reg & 3) + 8 * (reg >> 2) + 4 * hi32;
      float val = acc[fm][reg] + bias;
      float sg = 1.f / (1.f + __expf(-val));
      if (o < 64) zb[(n * 64 + brow) * 64 + o] = (_Float16)sg;
      else        rb[(n * 64 + brow) * 64 + (o - 64)] = (_Float16)sg;
    }
}

// ------------- 6. xs_t[b][64+o][m] = f16(z[m][b][o] * state[b][m][o]) -------
__global__ __launch_bounds__(256) void k_cand(const _Float16* __restrict__ zb,
                                              const float* __restrict__ st,
                                              _Float16* __restrict__ xs_t) {
  int m0 = blockIdx.x * 64, b = blockIdx.y, tid = threadIdx.x;
  __shared__ __attribute__((aligned(16))) _Float16 T[64][66];
#pragma unroll
  for (int i = 0; i < 16; i++) {
    int li = i * 256 + tid, ml = li >> 6, o = li & 63;
    float z = (float)zb[((m0 + ml) * 64 + b) * 64 + o];
    float s = st[(b * 4096 + m0 + ml) * 64 + o];
    T[ml][o] = (_Float16)(z * s);
  }
  __syncthreads();
  int og = tid >> 3, mch = tid & 7;
#pragma unroll
  for (int cb = 0; cb < 2; cb++) {
    int o = cb * 32 + og;
    f16x8 tmp;
#pragma unroll
    for (int j = 0; j < 8; j++) tmp[j] = T[mch * 8 + j][o];
    *reinterpret_cast<f16x8*>(&xs_t[(b * 128 + 64 + o) * 4096 + m0 + mch * 8]) = tmp;
  }
}

// ---- 7. update (MFMA, mirrors R15 gate): hc=tanh(xg2 @ Wu_n + bu);
//      h = r*state + (1-r)*hc -> out. Wave w owns fragment (fm=w>>1, fn=w&1).
__global__ __launch_bounds__(256) void k_upd(const _Float16* __restrict__ xg2,   // [b][n][128]
                                             const float* __restrict__ emb,
                                             const _Float16* __restrict__ Wc,    // chunk [2048][64][128]
                                             const float* __restrict__ ubp,
                                             int n0,
                                             const _Float16* __restrict__ rb,    // [n][b][64]
                                             const float* __restrict__ st,
                                             float* __restrict__ out) {
  int n = n0 + blockIdx.x, tid = threadIdx.x, lane = tid & 63, w = tid >> 6;
  int fm = w >> 1, fn = w & 1;
  __shared__ __attribute__((aligned(16))) _Float16 As[64 * 64];
  __shared__ __attribute__((aligned(16))) _Float16 Bs[64 * 64];
  __shared__ float bias_sh[64];
  const _Float16* wrow = Wc + (size_t)blockIdx.x * 8192;
  if (tid < 64) {
    float s = 0.f;
#pragma unroll
    for (int d = 0; d < 16; d++) s += emb[n * 16 + d] * ubp[d * 64 + tid];
    bias_sh[tid] = s;
  }
  f32x16 acc;
#pragma unroll
  for (int q = 0; q < 16; q++) acc[q] = 0.f;

  int lrow = lane >> 3;                       // staging row-within-group
  int lcolsw = (((lane & 7) ^ lrow) * 8);     // pre-swizzled source column
  int r32 = lane & 31, hi32 = lane >> 5;
  int swz = (r32 & 7) * 8;                    // read-side XOR (elem units)
  for (int k0 = 0; k0 < 128; k0 += 64) {
    __syncthreads();
#pragma unroll
    for (int i = 0; i < 2; i++) {             // A: 64 rows (b)
      int j = w * 2 + i;
      int row = j * 8 + lrow;
      gload_lds16(xg2 + ((size_t)row * 4096 + n) * 128 + k0 + lcolsw, &As[j * 512]);
    }
#pragma unroll
    for (int i = 0; i < 2; i++) {             // B: 64 rows (o)
      int j = w * 2 + i;
      int row = j * 8 + lrow;
      gload_lds16(wrow + row * 128 + k0 + lcolsw, &Bs[j * 512]);
    }
    __syncthreads();
#pragma unroll
    for (int kk = 0; kk < 4; kk++) {
      int col = (kk * 16 + hi32 * 8) ^ swz;
      f16x8 af = *reinterpret_cast<const f16x8*>(&As[(fm * 32 + r32) * 64 + col]);
      f16x8 bf = *reinterpret_cast<const f16x8*>(&Bs[(fn * 32 + r32) * 64 + col]);
      acc = __builtin_amdgcn_mfma_f32_32x32x16_f16(af, bf, acc, 0, 0, 0);
    }
  }
  int o = fn * 32 + r32;
  float bias = bias_sh[o];
#pragma unroll
  for (int reg = 0; reg < 16; reg++) {
    int brow = fm * 32 + (reg & 3) + 8 * (reg >> 2) + 4 * hi32;
    float val = acc[reg] + bias;
    float e2 = __expf(2.f * val);
    float hc = 1.f - 2.f / (e2 + 1.f);        // tanh
    float rr = (float)rb[(n * 64 + brow) * 64 + o];
    float s = st[((size_t)brow * 4096 + n) * 64 + o];
    out[((size_t)brow * 4096 + n) * 64 + o] = rr * s + (1.f - rr) * hc;
  }
}

extern "C" void kernel_launch(void* const* d_in, const int* in_sizes, int n_in,
                              void* d_out, int out_size, void* d_ws, size_t ws_size,
                              hipStream_t stream) {
  const float* x   = (const float*)d_in[0];
  const float* st  = (const float*)d_in[1];
  const float* emb = (const float*)d_in[2];
  const float* gwp = (const float*)d_in[3];
  const float* gbp = (const float*)d_in[4];
  const float* uwp = (const float*)d_in[5];
  const float* ubp = (const float*)d_in[6];
  float* out = (float*)d_out;
  char* ws = (char*)d_ws;

  // slot A [0,33.55M): S for gemm1 -> W_all_g chunks -> S2 for gemm2
  _Float16* slotA = (_Float16*)(ws + 0);
  _Float16* xs_t  = (_Float16*)(ws + 33554432);   // 67 MB [b][c][m]
  _Float16* xg    = (_Float16*)(ws + 100663296);  // 67 MB (gemm1 out; gemm2 fills c>=64)
  _Float16* zb    = (_Float16*)(ws + 167772160);  // 33.5 MB [n][b][64]; -> W_all_u chunks after cand
  _Float16* rb    = (_Float16*)(ws + 201326592);  // 33.5 MB [n][b][64] (alive to upd)
  float* wtg = (float*)(ws + 234881024);          // 1 MB
  float* wtu = (float*)(ws + 235929600);          // 0.5 MB
  if (ws_size < 236453888ull) return;  // fail loudly rather than corrupt

  k_wpoolT<<<1536, 256, 0, stream>>>(gwp, uwp, wtg, wtu);
  k_supports<<<4096, 256, 0, stream>>>(emb, slotA);
  k_concat<<<dim3(64, 64), 256, 0, stream>>>(x, st, xs_t);
  k_gemm<<<dim3(32, 64), 256, 0, stream>>>(slotA, xs_t, xg);
  // gate in 4 chunks of 1024 nodes; W chunk (33.55 MB) reuses slot A (S dead)
  for (int c = 0; c < 4; c++) {
    k_wall<<<dim3(16, 8), 256, 0, stream>>>(emb, c * 1024, wtg, 16384, slotA);
    k_gate<<<1024, 256, 0, stream>>>(xg, emb, slotA, gbp, c * 1024, zb, rb);
  }
  k_cand<<<dim3(64, 64), 256, 0, stream>>>(zb, st, xs_t);
  k_supports<<<4096, 256, 0, stream>>>(emb, slotA);        // recompute S (cheap)
  // GEMM2: only the z*state half (c>=64); S@x half kept from GEMM1 in xg
  k_gemm2<<<dim3(32, 32), 256, 0, stream>>>(slotA, xs_t, xg);
  // update in 2 chunks of 2048 nodes; W chunk (33.55 MB) reuses zb slot (dead)
  for (int c = 0; c < 2; c++) {
    k_wall<<<dim3(32, 4), 256, 0, stream>>>(emb, c * 2048, wtu, 8192, zb);
    k_upd<<<2048, 256, 0, stream>>>(xg, emb, zb, ubp, c * 2048, rb, st, out);
  }
}

// Round 17
// 859.464 us; speedup vs baseline: 1.3221x; 1.1023x over previous
//
#include <hip/hip_runtime.h>

typedef float f32x4 __attribute__((ext_vector_type(4)));
typedef float f32x16 __attribute__((ext_vector_type(16)));
typedef _Float16 f16x8 __attribute__((ext_vector_type(8)));
typedef _Float16 f16x4 __attribute__((ext_vector_type(4)));
typedef _Float16 f16x2 __attribute__((ext_vector_type(2)));

typedef __attribute__((address_space(1))) const unsigned char gbyte;
typedef __attribute__((address_space(3))) unsigned char sbyte;
__device__ __forceinline__ void gload_lds16(const void* gp, void* lp) {
  __builtin_amdgcn_global_load_lds((gbyte*)gp, (sbyte*)lp, 16, 0, 0);
}

// gate-W chunk mapping into the xs_t state-half region (dead gemm1->cand):
// chunk-local node nl (0..1023) -> 16384 contiguous f16 at
//   xs_t + (nl>>4)*524288 + 262144 + (nl&15)*16384
__device__ __forceinline__ size_t wmap_gate(int nl) {
  return (size_t)(nl >> 4) * 524288 + 262144 + (size_t)(nl & 15) * 16384;
}

// ---------------- 1. weight-pool transpose to [d][o][i], f32 ----------------
__global__ __launch_bounds__(256) void k_wpoolT(const float* __restrict__ gwp,
                                                const float* __restrict__ uwp,
                                                float* __restrict__ wtg,
                                                float* __restrict__ wtu) {
  int idx = blockIdx.x * 256 + threadIdx.x;
  if (idx < 16 * 128 * 128) {
    int d = idx >> 14, rem = idx & 16383, o = rem >> 7, i = rem & 127;
    wtg[idx] = gwp[(d << 14) + (i << 7) + o];          // gwp[d][i][o]
  } else {
    int j = idx - 16 * 128 * 128;
    if (j < 16 * 64 * 128) {
      int d = j >> 13, rem = j & 8191, o = rem >> 7, i = rem & 127;
      wtu[j] = uwp[(d << 13) + (i << 6) + o];          // uwp[d][i][o(64)]
    }
  }
}

// -------- 2. supports = softmax(relu(E E^T)), 4 rows/block (emb reuse) ------
// Per-element op sequence identical to the R16-proven version (f32 d-order
// dot -> relu -> expf -> *inv -> f16); only the denominator reduction order
// differs (epsilon-level). emb L2 traffic: 1 GB -> 256 MB.
__global__ __launch_bounds__(256) void k_supports(const float* __restrict__ emb,
                                                  _Float16* __restrict__ S) {
  int n0 = blockIdx.x * 4, tid = threadIdx.x;
  __shared__ float e_sh[4][16];
  __shared__ float red[4][4];
  if (tid < 16) {
    int r = tid >> 2, part = tid & 3;
    f32x4 v = *reinterpret_cast<const f32x4*>(emb + (n0 + r) * 16 + part * 4);
    *reinterpret_cast<f32x4*>(&e_sh[r][part * 4]) = v;
  }
  __syncthreads();
  float v[4][16];
  float sum[4] = {0.f, 0.f, 0.f, 0.f};
#pragma unroll
  for (int i = 0; i < 16; i++) {
    int m = i * 256 + tid;
    const f32x4* em = reinterpret_cast<const f32x4*>(emb + m * 16);
    f32x4 e0 = em[0], e1 = em[1], e2 = em[2], e3 = em[3];
#pragma unroll
    for (int r = 0; r < 4; r++) {
      float acc = 0.f;
#pragma unroll
      for (int q = 0; q < 4; q++) acc += e_sh[r][q] * e0[q];
#pragma unroll
      for (int q = 0; q < 4; q++) acc += e_sh[r][4 + q] * e1[q];
#pragma unroll
      for (int q = 0; q < 4; q++) acc += e_sh[r][8 + q] * e2[q];
#pragma unroll
      for (int q = 0; q < 4; q++) acc += e_sh[r][12 + q] * e3[q];
      acc = fmaxf(acc, 0.f);
      float e = __expf(acc);
      v[r][i] = e;
      sum[r] += e;
    }
  }
#pragma unroll
  for (int r = 0; r < 4; r++)
#pragma unroll
    for (int off = 32; off > 0; off >>= 1) sum[r] += __shfl_down(sum[r], off);
  if ((tid & 63) == 0) {
#pragma unroll
    for (int r = 0; r < 4; r++) red[tid >> 6][r] = sum[r];
  }
  __syncthreads();
  float inv[4];
#pragma unroll
  for (int r = 0; r < 4; r++)
    inv[r] = 1.f / (red[0][r] + red[1][r] + red[2][r] + red[3][r]);
#pragma unroll
  for (int i = 0; i < 16; i++)
#pragma unroll
    for (int r = 0; r < 4; r++)
      S[(size_t)(n0 + r) * 4096 + i * 256 + tid] = (_Float16)(v[r][i] * inv[r]);
}

// ------- 3. xs_t[b][c][m] = f16(concat(x,state))  (c-major for GEMM B) ------
__global__ __launch_bounds__(256) void k_concat(const float* __restrict__ x,
                                                const float* __restrict__ st,
                                                _Float16* __restrict__ xs_t) {
  int m0 = blockIdx.x * 64, b = blockIdx.y, tid = threadIdx.x;
  __shared__ __attribute__((aligned(16))) _Float16 T[64][130];
#pragma unroll
  for (int i = 0; i < 16; i++) {
    int li = i * 256 + tid;
    int ml = li >> 6, c = li & 63;
    int base = (b * 4096 + m0 + ml) * 64 + c;
    T[ml][c] = (_Float16)x[base];
    T[ml][64 + c] = (_Float16)st[base];
  }
  __syncthreads();
  int cg = tid >> 3, mch = tid & 7;
#pragma unroll
  for (int cb = 0; cb < 4; cb++) {
    int c = cb * 32 + cg;
    f16x8 tmp;
#pragma unroll
    for (int j = 0; j < 8; j++) tmp[j] = T[mch * 8 + j][c];
    *reinterpret_cast<f16x8*>(&xs_t[(b * 128 + c) * 4096 + m0 + mch * 8]) = tmp;
  }
}

// -------- 4. GEMM1 (R11-proven: 32x32x16, 2x2 waves, single 32KB buffer) ----
__global__ __launch_bounds__(256) void k_gemm(const _Float16* __restrict__ S,
                                              const _Float16* __restrict__ Xt,
                                              _Float16* __restrict__ Y) {
  int nt = blockIdx.x, b = blockIdx.y;
  int tid = threadIdx.x, lane = tid & 63, w = tid >> 6;
  int wr = w >> 1, wc = w & 1;
  __shared__ __attribute__((aligned(16))) _Float16 As[128 * 64];
  __shared__ __attribute__((aligned(16))) _Float16 Bs[128 * 64];
  const _Float16* Sb = S + nt * 128 * 4096;
  const _Float16* Xb = Xt + b * 128 * 4096;
  f32x16 acc[2][2];
#pragma unroll
  for (int fm = 0; fm < 2; fm++)
#pragma unroll
    for (int fn = 0; fn < 2; fn++)
#pragma unroll
      for (int q = 0; q < 16; q++) acc[fm][fn][q] = 0.f;

  int lrow = lane >> 3;                       // staging row-within-group
  int lcolsw = (((lane & 7) ^ lrow) * 8);     // pre-swizzled source column
  int r32 = lane & 31, hi32 = lane >> 5;
  int swz = (r32 & 7) * 8;                    // read-side XOR (elem units)
  for (int k0 = 0; k0 < 4096; k0 += 64) {
    __syncthreads();
#pragma unroll
    for (int i = 0; i < 4; i++) {
      int j = w * 4 + i;
      int row = j * 8 + lrow;
      gload_lds16(Sb + row * 4096 + k0 + lcolsw, &As[j * 512]);
      gload_lds16(Xb + row * 4096 + k0 + lcolsw, &Bs[j * 512]);
    }
    __syncthreads();
#pragma unroll
    for (int kk = 0; kk < 4; kk++) {
      int col = (kk * 16 + hi32 * 8) ^ swz;
      f16x8 af[2], bf[2];
#pragma unroll
      for (int fm = 0; fm < 2; fm++)
        af[fm] = *reinterpret_cast<const f16x8*>(&As[(wr * 64 + fm * 32 + r32) * 64 + col]);
#pragma unroll
      for (int fn = 0; fn < 2; fn++)
        bf[fn] = *reinterpret_cast<const f16x8*>(&Bs[(wc * 64 + fn * 32 + r32) * 64 + col]);
#pragma unroll
      for (int fm = 0; fm < 2; fm++)
#pragma unroll
        for (int fn = 0; fn < 2; fn++)
          acc[fm][fn] = __builtin_amdgcn_mfma_f32_32x32x16_f16(af[fm], bf[fn], acc[fm][fn], 0, 0, 0);
    }
  }
#pragma unroll
  for (int fm = 0; fm < 2; fm++)
#pragma unroll
    for (int fn = 0; fn < 2; fn++)
#pragma unroll
      for (int reg = 0; reg < 16; reg++) {
        int row = nt * 128 + wr * 64 + fm * 32 + (reg & 3) + 8 * (reg >> 2) + 4 * hi32;
        int c = wc * 64 + fn * 32 + r32;
        Y[(b * 4096 + row) * 128 + c] = (_Float16)acc[fm][fn][reg];
      }
}

// -------- 4b. GEMM2 (R11-proven half-N): c in [64,128) of batch pair --------
__global__ __launch_bounds__(256) void k_gemm2(const _Float16* __restrict__ S,
                                               const _Float16* __restrict__ Xt,
                                               _Float16* __restrict__ Y) {
  int nt = blockIdx.x, bp = blockIdx.y;
  int tid = threadIdx.x, lane = tid & 63, w = tid >> 6;
  int wr = w >> 1, wc = w & 1;
  __shared__ __attribute__((aligned(16))) _Float16 As[128 * 64];
  __shared__ __attribute__((aligned(16))) _Float16 Bs[128 * 64];
  const _Float16* Sb = S + nt * 128 * 4096;
  const _Float16* Xb = Xt + (size_t)(256 * bp + 64) * 4096;
  f32x16 acc[2][2];
#pragma unroll
  for (int fm = 0; fm < 2; fm++)
#pragma unroll
    for (int fn = 0; fn < 2; fn++)
#pragma unroll
      for (int q = 0; q < 16; q++) acc[fm][fn][q] = 0.f;

  int lrow = lane >> 3;
  int lcolsw = (((lane & 7) ^ lrow) * 8);
  int r32 = lane & 31, hi32 = lane >> 5;
  int swz = (r32 & 7) * 8;
  for (int k0 = 0; k0 < 4096; k0 += 64) {
    __syncthreads();
#pragma unroll
    for (int i = 0; i < 4; i++) {
      int j = w * 4 + i;
      int row = j * 8 + lrow;                              // 0..127 tile row
      int groff = ((row >> 6) * 128 + (row & 63)) * 4096;  // batch-pair map
      gload_lds16(Sb + row * 4096 + k0 + lcolsw, &As[j * 512]);
      gload_lds16(Xb + groff + k0 + lcolsw, &Bs[j * 512]);
    }
    __syncthreads();
#pragma unroll
    for (int kk = 0; kk < 4; kk++) {
      int col = (kk * 16 + hi32 * 8) ^ swz;
      f16x8 af[2], bf[2];
#pragma unroll
      for (int fm = 0; fm < 2; fm++)
        af[fm] = *reinterpret_cast<const f16x8*>(&As[(wr * 64 + fm * 32 + r32) * 64 + col]);
#pragma unroll
      for (int fn = 0; fn < 2; fn++)
        bf[fn] = *reinterpret_cast<const f16x8*>(&Bs[(wc * 64 + fn * 32 + r32) * 64 + col]);
#pragma unroll
      for (int fm = 0; fm < 2; fm++)
#pragma unroll
        for (int fn = 0; fn < 2; fn++)
          acc[fm][fn] = __builtin_amdgcn_mfma_f32_32x32x16_f16(af[fm], bf[fn], acc[fm][fn], 0, 0, 0);
    }
  }
#pragma unroll
  for (int fm = 0; fm < 2; fm++)
#pragma unroll
    for (int fn = 0; fn < 2; fn++)
#pragma unroll
      for (int reg = 0; reg < 16; reg++) {
        int row = nt * 128 + wr * 64 + fm * 32 + (reg & 3) + 8 * (reg >> 2) + 4 * hi32;
        int ct = wc * 64 + fn * 32 + r32;       // 0..127 tile col
        int batch = 2 * bp + (ct >> 6);
        int c = 64 + (ct & 63);
        Y[((size_t)batch * 4096 + row) * 128 + c] = (_Float16)acc[fm][fn][reg];
      }
}

// ---- 5a. k_wall: W_all[node][o*i] = f16( sum_d E[n0+node][d] * wt[d][o*i] )
// MAPPED=1: write via wmap_gate into the xs_t state-half region.
template <int MAPPED>
__global__ __launch_bounds__(256) void k_wall(const float* __restrict__ emb, int n0,
                                              const float* __restrict__ wt, int OI,
                                              _Float16* __restrict__ Wout) {
  int bx = blockIdx.x, by = blockIdx.y, tid = threadIdx.x;
  __shared__ float e_sh[64][16];
  {
    int node = tid >> 2, part = tid & 3;
    f32x4 v = *reinterpret_cast<const f32x4*>(emb + (n0 + bx * 64 + node) * 16 + part * 4);
    *reinterpret_cast<f32x4*>(&e_sh[node][part * 4]) = v;
  }
  __syncthreads();
  int oi0 = by * 2048 + tid * 8;
#pragma unroll
  for (int g = 0; g < 8; g++) {
    f32x4 a0[8], a1[8];
#pragma unroll
    for (int nn = 0; nn < 8; nn++) { a0[nn] = (f32x4){0,0,0,0}; a1[nn] = (f32x4){0,0,0,0}; }
#pragma unroll
    for (int d = 0; d < 16; d++) {
      const f32x4* p = reinterpret_cast<const f32x4*>(wt + d * OI + oi0);
      f32x4 v0 = p[0], v1 = p[1];
#pragma unroll
      for (int nn = 0; nn < 8; nn++) {
        float e = e_sh[g * 8 + nn][d];
        a0[nn] += e * v0;
        a1[nn] += e * v1;
      }
    }
#pragma unroll
    for (int nn = 0; nn < 8; nn++) {
      f16x8 pk;
#pragma unroll
      for (int q = 0; q < 4; q++) { pk[q] = (_Float16)a0[nn][q]; pk[4 + q] = (_Float16)a1[nn][q]; }
      int node = bx * 64 + g * 8 + nn;                 // chunk-local
      size_t base = MAPPED ? wmap_gate(node) : (size_t)node * OI;
      *reinterpret_cast<f16x8*>(Wout + base + oi0) = pk;
    }
  }
}

// ---- 5b. gate (MFMA, R15-proven): z_r = sigmoid(x_g @ W_n + b_n) -----------
// W read from the mapped region in xs_t.
__global__ __launch_bounds__(256) void k_gate(const _Float16* __restrict__ xg,   // [b][n][128]
                                              const float* __restrict__ emb,
                                              const _Float16* __restrict__ Wc,   // = xs_t (mapped)
                                              const float* __restrict__ gbp,
                                              int n0,
                                              _Float16* __restrict__ zb,         // [n][b][64]
                                              _Float16* __restrict__ rb) {       // [n][b][64]
  int n = n0 + blockIdx.x, tid = threadIdx.x, lane = tid & 63, w = tid >> 6;
  __shared__ __attribute__((aligned(16))) _Float16 As[64 * 64];
  __shared__ __attribute__((aligned(16))) _Float16 Bs[128 * 64];
  __shared__ float bias_sh[128];
  const _Float16* wrow = Wc + wmap_gate(blockIdx.x);
  if (tid < 128) {
    float s = 0.f;
#pragma unroll
    for (int d = 0; d < 16; d++) s += emb[n * 16 + d] * gbp[d * 128 + tid];
    bias_sh[tid] = s;
  }
  f32x16 acc[2];
#pragma unroll
  for (int fm = 0; fm < 2; fm++)
#pragma unroll
    for (int q = 0; q < 16; q++) acc[fm][q] = 0.f;

  int lrow = lane >> 3;                       // staging row-within-group
  int lcolsw = (((lane & 7) ^ lrow) * 8);     // pre-swizzled source column
  int r32 = lane & 31, hi32 = lane >> 5;
  int swz = (r32 & 7) * 8;                    // read-side XOR (elem units)
  for (int k0 = 0; k0 < 128; k0 += 64) {
    __syncthreads();
#pragma unroll
    for (int i = 0; i < 2; i++) {             // A: 64 rows (b)
      int j = w * 2 + i;
      int row = j * 8 + lrow;
      gload_lds16(xg + ((size_t)row * 4096 + n) * 128 + k0 + lcolsw, &As[j * 512]);
    }
#pragma unroll
    for (int i = 0; i < 4; i++) {             // B: 128 rows (o)
      int j = w * 4 + i;
      int row = j * 8 + lrow;
      gload_lds16(wrow + row * 128 + k0 + lcolsw, &Bs[j * 512]);
    }
    __syncthreads();
#pragma unroll
    for (int kk = 0; kk < 4; kk++) {
      int col = (kk * 16 + hi32 * 8) ^ swz;
      f16x8 bf = *reinterpret_cast<const f16x8*>(&Bs[(w * 32 + r32) * 64 + col]);
#pragma unroll
      for (int fm = 0; fm < 2; fm++) {
        f16x8 af = *reinterpret_cast<const f16x8*>(&As[(fm * 32 + r32) * 64 + col]);
        acc[fm] = __builtin_amdgcn_mfma_f32_32x32x16_f16(af, bf, acc[fm], 0, 0, 0);
      }
    }
  }
  int o = w * 32 + r32;                       // wave-uniform half: w<2 -> z
  float bias = bias_sh[o];
#pragma unroll
  for (int fm = 0; fm < 2; fm++)
#pragma unroll
    for (int reg = 0; reg < 16; reg++) {
      int brow = fm * 32 + (reg & 3) + 8 * (reg >> 2) + 4 * hi32;
      float val = acc[fm][reg] + bias;
      float sg = 1.f / (1.f + __expf(-val));
      if (o < 64) zb[(n * 64 + brow) * 64 + o] = (_Float16)sg;
      else        rb[(n * 64 + brow) * 64 + (o - 64)] = (_Float16)sg;
    }
}

// ------------- 6. xs_t[b][64+o][m] = f16(z[m][b][o] * state[b][m][o]) -------
__global__ __launch_bounds__(256) void k_cand(const _Float16* __restrict__ zb,
                                              const float* __restrict__ st,
                                              _Float16* __restrict__ xs_t) {
  int m0 = blockIdx.x * 64, b = blockIdx.y, tid = threadIdx.x;
  __shared__ __attribute__((aligned(16))) _Float16 T[64][66];
#pragma unroll
  for (int i = 0; i < 16; i++) {
    int li = i * 256 + tid, ml = li >> 6, o = li & 63;
    float z = (float)zb[((m0 + ml) * 64 + b) * 64 + o];
    float s = st[(b * 4096 + m0 + ml) * 64 + o];
    T[ml][o] = (_Float16)(z * s);
  }
  __syncthreads();
  int og = tid >> 3, mch = tid & 7;
#pragma unroll
  for (int cb = 0; cb < 2; cb++) {
    int o = cb * 32 + og;
    f16x8 tmp;
#pragma unroll
    for (int j = 0; j < 8; j++) tmp[j] = T[mch * 8 + j][o];
    *reinterpret_cast<f16x8*>(&xs_t[(b * 128 + 64 + o) * 4096 + m0 + mch * 8]) = tmp;
  }
}

// ---- 7. update (MFMA, R16-proven): hc=tanh(xg2 @ Wu_n + bu);
//      h = r*state + (1-r)*hc -> out. Wave w owns fragment (fm=w>>1, fn=w&1).
__global__ __launch_bounds__(256) void k_upd(const _Float16* __restrict__ xg2,   // [b][n][128]
                                             const float* __restrict__ emb,
                                             const _Float16* __restrict__ Wc,    // chunk [2048][64][128]
                                             const float* __restrict__ ubp,
                                             int n0,
                                             const _Float16* __restrict__ rb,    // [n][b][64]
                                             const float* __restrict__ st,
                                             float* __restrict__ out) {
  int n = n0 + blockIdx.x, tid = threadIdx.x, lane = tid & 63, w = tid >> 6;
  int fm = w >> 1, fn = w & 1;
  __shared__ __attribute__((aligned(16))) _Float16 As[64 * 64];
  __shared__ __attribute__((aligned(16))) _Float16 Bs[64 * 64];
  __shared__ float bias_sh[64];
  const _Float16* wrow = Wc + (size_t)blockIdx.x * 8192;
  if (tid < 64) {
    float s = 0.f;
#pragma unroll
    for (int d = 0; d < 16; d++) s += emb[n * 16 + d] * ubp[d * 64 + tid];
    bias_sh[tid] = s;
  }
  f32x16 acc;
#pragma unroll
  for (int q = 0; q < 16; q++) acc[q] = 0.f;

  int lrow = lane >> 3;                       // staging row-within-group
  int lcolsw = (((lane & 7) ^ lrow) * 8);     // pre-swizzled source column
  int r32 = lane & 31, hi32 = lane >> 5;
  int swz = (r32 & 7) * 8;                    // read-side XOR (elem units)
  for (int k0 = 0; k0 < 128; k0 += 64) {
    __syncthreads();
#pragma unroll
    for (int i = 0; i < 2; i++) {             // A: 64 rows (b)
      int j = w * 2 + i;
      int row = j * 8 + lrow;
      gload_lds16(xg2 + ((size_t)row * 4096 + n) * 128 + k0 + lcolsw, &As[j * 512]);
    }
#pragma unroll
    for (int i = 0; i < 2; i++) {             // B: 64 rows (o)
      int j = w * 2 + i;
      int row = j * 8 + lrow;
      gload_lds16(wrow + row * 128 + k0 + lcolsw, &Bs[j * 512]);
    }
    __syncthreads();
#pragma unroll
    for (int kk = 0; kk < 4; kk++) {
      int col = (kk * 16 + hi32 * 8) ^ swz;
      f16x8 af = *reinterpret_cast<const f16x8*>(&As[(fm * 32 + r32) * 64 + col]);
      f16x8 bf = *reinterpret_cast<const f16x8*>(&Bs[(fn * 32 + r32) * 64 + col]);
      acc = __builtin_amdgcn_mfma_f32_32x32x16_f16(af, bf, acc, 0, 0, 0);
    }
  }
  int o = fn * 32 + r32;
  float bias = bias_sh[o];
#pragma unroll
  for (int reg = 0; reg < 16; reg++) {
    int brow = fm * 32 + (reg & 3) + 8 * (reg >> 2) + 4 * hi32;
    float val = acc[reg] + bias;
    float e2 = __expf(2.f * val);
    float hc = 1.f - 2.f / (e2 + 1.f);        // tanh
    float rr = (float)rb[(n * 64 + brow) * 64 + o];
    float s = st[((size_t)brow * 4096 + n) * 64 + o];
    out[((size_t)brow * 4096 + n) * 64 + o] = rr * s + (1.f - rr) * hc;
  }
}

extern "C" void kernel_launch(void* const* d_in, const int* in_sizes, int n_in,
                              void* d_out, int out_size, void* d_ws, size_t ws_size,
                              hipStream_t stream) {
  const float* x   = (const float*)d_in[0];
  const float* st  = (const float*)d_in[1];
  const float* emb = (const float*)d_in[2];
  const float* gwp = (const float*)d_in[3];
  const float* gbp = (const float*)d_in[4];
  const float* uwp = (const float*)d_in[5];
  const float* ubp = (const float*)d_in[6];
  float* out = (float*)d_out;
  char* ws = (char*)d_ws;

  // slot A [0,33.55M): S (alive through gemm2 -- gate W now lives in xs_t's
  // dead state-half region between gemm1 and cand)
  _Float16* slotA = (_Float16*)(ws + 0);
  _Float16* xs_t  = (_Float16*)(ws + 33554432);   // 67 MB [b][c][m]
  _Float16* xg    = (_Float16*)(ws + 100663296);  // 67 MB (gemm1 out; gemm2 fills c>=64)
  _Float16* zb    = (_Float16*)(ws + 167772160);  // 33.5 MB [n][b][64]; -> W_all_u chunks after cand
  _Float16* rb    = (_Float16*)(ws + 201326592);  // 33.5 MB [n][b][64] (alive to upd)
  float* wtg = (float*)(ws + 234881024);          // 1 MB
  float* wtu = (float*)(ws + 235929600);          // 0.5 MB
  if (ws_size < 236453888ull) return;  // fail loudly rather than corrupt

  k_wpoolT<<<1536, 256, 0, stream>>>(gwp, uwp, wtg, wtu);
  k_supports<<<1024, 256, 0, stream>>>(emb, slotA);
  k_concat<<<dim3(64, 64), 256, 0, stream>>>(x, st, xs_t);
  k_gemm<<<dim3(32, 64), 256, 0, stream>>>(slotA, xs_t, xg);
  // gate in 4 chunks of 1024 nodes; W chunks live in xs_t's dead state half
  for (int c = 0; c < 4; c++) {
    k_wall<1><<<dim3(16, 8), 256, 0, stream>>>(emb, c * 1024, wtg, 16384, xs_t);
    k_gate<<<1024, 256, 0, stream>>>(xg, emb, xs_t, gbp, c * 1024, zb, rb);
  }
  k_cand<<<dim3(64, 64), 256, 0, stream>>>(zb, st, xs_t);
  // GEMM2: S still alive in slotA (no recompute); only the z*state half
  k_gemm2<<<dim3(32, 32), 256, 0, stream>>>(slotA, xs_t, xg);
  // update in 2 chunks of 2048 nodes; W chunk (33.55 MB) reuses zb slot (dead)
  for (int c = 0; c < 2; c++) {
    k_wall<0><<<dim3(32, 4), 256, 0, stream>>>(emb, c * 2048, wtu, 8192, zb);
    k_upd<<<2048, 256, 0, stream>>>(xg, emb, zb, ubp, c * 2048, rb, st, out);
  }
}

// Round 18
// 827.893 us; speedup vs baseline: 1.3725x; 1.0381x over previous
//
#include <hip/hip_runtime.h>

typedef float f32x4 __attribute__((ext_vector_type(4)));
typedef float f32x16 __attribute__((ext_vector_type(16)));
typedef _Float16 f16x8 __attribute__((ext_vector_type(8)));
typedef _Float16 f16x4 __attribute__((ext_vector_type(4)));
typedef _Float16 f16x2 __attribute__((ext_vector_type(2)));

typedef __attribute__((address_space(1))) const unsigned char gbyte;
typedef __attribute__((address_space(3))) unsigned char sbyte;
__device__ __forceinline__ void gload_lds16(const void* gp, void* lp) {
  __builtin_amdgcn_global_load_lds((gbyte*)gp, (sbyte*)lp, 16, 0, 0);
}

// ---------------- 1. weight-pool transpose to [d][o][i], f32 ----------------
__global__ __launch_bounds__(256) void k_wpoolT(const float* __restrict__ gwp,
                                                const float* __restrict__ uwp,
                                                float* __restrict__ wtg,
                                                float* __restrict__ wtu) {
  int idx = blockIdx.x * 256 + threadIdx.x;
  if (idx < 16 * 128 * 128) {
    int d = idx >> 14, rem = idx & 16383, o = rem >> 7, i = rem & 127;
    wtg[idx] = gwp[(d << 14) + (i << 7) + o];          // gwp[d][i][o]
  } else {
    int j = idx - 16 * 128 * 128;
    if (j < 16 * 64 * 128) {
      int d = j >> 13, rem = j & 8191, o = rem >> 7, i = rem & 127;
      wtu[j] = uwp[(d << 13) + (i << 6) + o];          // uwp[d][i][o(64)]
    }
  }
}

// -------- 2. supports = softmax(relu(E E^T)), 4 rows/block (emb reuse) ------
__global__ __launch_bounds__(256) void k_supports(const float* __restrict__ emb,
                                                  _Float16* __restrict__ S) {
  int n0 = blockIdx.x * 4, tid = threadIdx.x;
  __shared__ float e_sh[4][16];
  __shared__ float red[4][4];
  if (tid < 16) {
    int r = tid >> 2, part = tid & 3;
    f32x4 v = *reinterpret_cast<const f32x4*>(emb + (n0 + r) * 16 + part * 4);
    *reinterpret_cast<f32x4*>(&e_sh[r][part * 4]) = v;
  }
  __syncthreads();
  float v[4][16];
  float sum[4] = {0.f, 0.f, 0.f, 0.f};
#pragma unroll
  for (int i = 0; i < 16; i++) {
    int m = i * 256 + tid;
    const f32x4* em = reinterpret_cast<const f32x4*>(emb + m * 16);
    f32x4 e0 = em[0], e1 = em[1], e2 = em[2], e3 = em[3];
#pragma unroll
    for (int r = 0; r < 4; r++) {
      float acc = 0.f;
#pragma unroll
      for (int q = 0; q < 4; q++) acc += e_sh[r][q] * e0[q];
#pragma unroll
      for (int q = 0; q < 4; q++) acc += e_sh[r][4 + q] * e1[q];
#pragma unroll
      for (int q = 0; q < 4; q++) acc += e_sh[r][8 + q] * e2[q];
#pragma unroll
      for (int q = 0; q < 4; q++) acc += e_sh[r][12 + q] * e3[q];
      acc = fmaxf(acc, 0.f);
      float e = __expf(acc);
      v[r][i] = e;
      sum[r] += e;
    }
  }
#pragma unroll
  for (int r = 0; r < 4; r++)
#pragma unroll
    for (int off = 32; off > 0; off >>= 1) sum[r] += __shfl_down(sum[r], off);
  if ((tid & 63) == 0) {
#pragma unroll
    for (int r = 0; r < 4; r++) red[tid >> 6][r] = sum[r];
  }
  __syncthreads();
  float inv[4];
#pragma unroll
  for (int r = 0; r < 4; r++)
    inv[r] = 1.f / (red[0][r] + red[1][r] + red[2][r] + red[3][r]);
#pragma unroll
  for (int i = 0; i < 16; i++)
#pragma unroll
    for (int r = 0; r < 4; r++)
      S[(size_t)(n0 + r) * 4096 + i * 256 + tid] = (_Float16)(v[r][i] * inv[r]);
}

// ------- 3. xs_t[b][c][m] = f16(concat(x,state))  (c-major for GEMM B) ------
__global__ __launch_bounds__(256) void k_concat(const float* __restrict__ x,
                                                const float* __restrict__ st,
                                                _Float16* __restrict__ xs_t) {
  int m0 = blockIdx.x * 64, b = blockIdx.y, tid = threadIdx.x;
  __shared__ __attribute__((aligned(16))) _Float16 T[64][130];
#pragma unroll
  for (int i = 0; i < 16; i++) {
    int li = i * 256 + tid;
    int ml = li >> 6, c = li & 63;
    int base = (b * 4096 + m0 + ml) * 64 + c;
    T[ml][c] = (_Float16)x[base];
    T[ml][64 + c] = (_Float16)st[base];
  }
  __syncthreads();
  int cg = tid >> 3, mch = tid & 7;
#pragma unroll
  for (int cb = 0; cb < 4; cb++) {
    int c = cb * 32 + cg;
    f16x8 tmp;
#pragma unroll
    for (int j = 0; j < 8; j++) tmp[j] = T[mch * 8 + j][c];
    *reinterpret_cast<f16x8*>(&xs_t[(b * 128 + c) * 4096 + m0 + mch * 8]) = tmp;
  }
}

// -------- 4. GEMM1 (R11-proven core + T1 XCD swizzle, 1D grid 2048) ---------
__global__ __launch_bounds__(256) void k_gemm(const _Float16* __restrict__ S,
                                              const _Float16* __restrict__ Xt,
                                              _Float16* __restrict__ Y) {
  // bijective XCD swizzle (nwg=2048, %8==0): same-XCD blocks get consecutive
  // wgid -> share Xb panels in that XCD's L2.
  int orig = blockIdx.x;
  int wgid = (orig & 7) * 256 + (orig >> 3);
  int nt = wgid & 31, b = wgid >> 5;
  int tid = threadIdx.x, lane = tid & 63, w = tid >> 6;
  int wr = w >> 1, wc = w & 1;
  __shared__ __attribute__((aligned(16))) _Float16 As[128 * 64];
  __shared__ __attribute__((aligned(16))) _Float16 Bs[128 * 64];
  const _Float16* Sb = S + nt * 128 * 4096;
  const _Float16* Xb = Xt + (size_t)b * 128 * 4096;
  f32x16 acc[2][2];
#pragma unroll
  for (int fm = 0; fm < 2; fm++)
#pragma unroll
    for (int fn = 0; fn < 2; fn++)
#pragma unroll
      for (int q = 0; q < 16; q++) acc[fm][fn][q] = 0.f;

  int lrow = lane >> 3;                       // staging row-within-group
  int lcolsw = (((lane & 7) ^ lrow) * 8);     // pre-swizzled source column
  int r32 = lane & 31, hi32 = lane >> 5;
  int swz = (r32 & 7) * 8;                    // read-side XOR (elem units)
  for (int k0 = 0; k0 < 4096; k0 += 64) {
    __syncthreads();
#pragma unroll
    for (int i = 0; i < 4; i++) {
      int j = w * 4 + i;
      int row = j * 8 + lrow;
      gload_lds16(Sb + row * 4096 + k0 + lcolsw, &As[j * 512]);
      gload_lds16(Xb + row * 4096 + k0 + lcolsw, &Bs[j * 512]);
    }
    __syncthreads();
#pragma unroll
    for (int kk = 0; kk < 4; kk++) {
      int col = (kk * 16 + hi32 * 8) ^ swz;
      f16x8 af[2], bf[2];
#pragma unroll
      for (int fm = 0; fm < 2; fm++)
        af[fm] = *reinterpret_cast<const f16x8*>(&As[(wr * 64 + fm * 32 + r32) * 64 + col]);
#pragma unroll
      for (int fn = 0; fn < 2; fn++)
        bf[fn] = *reinterpret_cast<const f16x8*>(&Bs[(wc * 64 + fn * 32 + r32) * 64 + col]);
#pragma unroll
      for (int fm = 0; fm < 2; fm++)
#pragma unroll
        for (int fn = 0; fn < 2; fn++)
          acc[fm][fn] = __builtin_amdgcn_mfma_f32_32x32x16_f16(af[fm], bf[fn], acc[fm][fn], 0, 0, 0);
    }
  }
#pragma unroll
  for (int fm = 0; fm < 2; fm++)
#pragma unroll
    for (int fn = 0; fn < 2; fn++)
#pragma unroll
      for (int reg = 0; reg < 16; reg++) {
        int row = nt * 128 + wr * 64 + fm * 32 + (reg & 3) + 8 * (reg >> 2) + 4 * hi32;
        int c = wc * 64 + fn * 32 + r32;
        Y[((size_t)b * 4096 + row) * 128 + c] = (_Float16)acc[fm][fn][reg];
      }
}

// -------- 4b. GEMM2 (half-N, T1 swizzle, 1D grid 1024): c in [64,128) -------
__global__ __launch_bounds__(256) void k_gemm2(const _Float16* __restrict__ S,
                                               const _Float16* __restrict__ Xt,
                                               _Float16* __restrict__ Y) {
  int orig = blockIdx.x;
  int wgid = (orig & 7) * 128 + (orig >> 3);
  int nt = wgid & 31, bp = wgid >> 5;
  int tid = threadIdx.x, lane = tid & 63, w = tid >> 6;
  int wr = w >> 1, wc = w & 1;
  __shared__ __attribute__((aligned(16))) _Float16 As[128 * 64];
  __shared__ __attribute__((aligned(16))) _Float16 Bs[128 * 64];
  const _Float16* Sb = S + nt * 128 * 4096;
  const _Float16* Xb = Xt + (size_t)(256 * bp + 64) * 4096;
  f32x16 acc[2][2];
#pragma unroll
  for (int fm = 0; fm < 2; fm++)
#pragma unroll
    for (int fn = 0; fn < 2; fn++)
#pragma unroll
      for (int q = 0; q < 16; q++) acc[fm][fn][q] = 0.f;

  int lrow = lane >> 3;
  int lcolsw = (((lane & 7) ^ lrow) * 8);
  int r32 = lane & 31, hi32 = lane >> 5;
  int swz = (r32 & 7) * 8;
  for (int k0 = 0; k0 < 4096; k0 += 64) {
    __syncthreads();
#pragma unroll
    for (int i = 0; i < 4; i++) {
      int j = w * 4 + i;
      int row = j * 8 + lrow;                              // 0..127 tile row
      int groff = ((row >> 6) * 128 + (row & 63)) * 4096;  // batch-pair map
      gload_lds16(Sb + row * 4096 + k0 + lcolsw, &As[j * 512]);
      gload_lds16(Xb + groff + k0 + lcolsw, &Bs[j * 512]);
    }
    __syncthreads();
#pragma unroll
    for (int kk = 0; kk < 4; kk++) {
      int col = (kk * 16 + hi32 * 8) ^ swz;
      f16x8 af[2], bf[2];
#pragma unroll
      for (int fm = 0; fm < 2; fm++)
        af[fm] = *reinterpret_cast<const f16x8*>(&As[(wr * 64 + fm * 32 + r32) * 64 + col]);
#pragma unroll
      for (int fn = 0; fn < 2; fn++)
        bf[fn] = *reinterpret_cast<const f16x8*>(&Bs[(wc * 64 + fn * 32 + r32) * 64 + col]);
#pragma unroll
      for (int fm = 0; fm < 2; fm++)
#pragma unroll
        for (int fn = 0; fn < 2; fn++)
          acc[fm][fn] = __builtin_amdgcn_mfma_f32_32x32x16_f16(af[fm], bf[fn], acc[fm][fn], 0, 0, 0);
    }
  }
#pragma unroll
  for (int fm = 0; fm < 2; fm++)
#pragma unroll
    for (int fn = 0; fn < 2; fn++)
#pragma unroll
      for (int reg = 0; reg < 16; reg++) {
        int row = nt * 128 + wr * 64 + fm * 32 + (reg & 3) + 8 * (reg >> 2) + 4 * hi32;
        int ct = wc * 64 + fn * 32 + r32;       // 0..127 tile col
        int batch = 2 * bp + (ct >> 6);
        int c = 64 + (ct & 63);
        Y[((size_t)batch * 4096 + row) * 128 + c] = (_Float16)acc[fm][fn][reg];
      }
}

// ---- 5a. k_wall: W_all[node][o*i] = f16( sum_d E[n0+node][d] * wt[d][o*i] )
// Linear layout: node (chunk-local) * OI.
__global__ __launch_bounds__(256) void k_wall(const float* __restrict__ emb, int n0,
                                              const float* __restrict__ wt, int OI,
                                              _Float16* __restrict__ Wout) {
  int bx = blockIdx.x, by = blockIdx.y, tid = threadIdx.x;
  __shared__ float e_sh[64][16];
  {
    int node = tid >> 2, part = tid & 3;
    f32x4 v = *reinterpret_cast<const f32x4*>(emb + (n0 + bx * 64 + node) * 16 + part * 4);
    *reinterpret_cast<f32x4*>(&e_sh[node][part * 4]) = v;
  }
  __syncthreads();
  int oi0 = by * 2048 + tid * 8;
#pragma unroll
  for (int g = 0; g < 8; g++) {
    f32x4 a0[8], a1[8];
#pragma unroll
    for (int nn = 0; nn < 8; nn++) { a0[nn] = (f32x4){0,0,0,0}; a1[nn] = (f32x4){0,0,0,0}; }
#pragma unroll
    for (int d = 0; d < 16; d++) {
      const f32x4* p = reinterpret_cast<const f32x4*>(wt + d * OI + oi0);
      f32x4 v0 = p[0], v1 = p[1];
#pragma unroll
      for (int nn = 0; nn < 8; nn++) {
        float e = e_sh[g * 8 + nn][d];
        a0[nn] += e * v0;
        a1[nn] += e * v1;
      }
    }
#pragma unroll
    for (int nn = 0; nn < 8; nn++) {
      f16x8 pk;
#pragma unroll
      for (int q = 0; q < 4; q++) { pk[q] = (_Float16)a0[nn][q]; pk[4 + q] = (_Float16)a1[nn][q]; }
      int node = bx * 64 + g * 8 + nn;                 // chunk-local
      *reinterpret_cast<f16x8*>(Wout + (size_t)node * OI + oi0) = pk;
    }
  }
}

// ---- 5b. gate (MFMA, R15-proven): z_r = sigmoid(x_g @ W_n + b_n) -----------
__global__ __launch_bounds__(256) void k_gate(const _Float16* __restrict__ xg,   // [b][n][128]
                                              const float* __restrict__ emb,
                                              const _Float16* __restrict__ Wc,   // chunk [2048][128][128] (in xs_t)
                                              const float* __restrict__ gbp,
                                              int n0,
                                              _Float16* __restrict__ zb,         // [n][b][64]
                                              _Float16* __restrict__ rb) {       // [n][b][64]
  int n = n0 + blockIdx.x, tid = threadIdx.x, lane = tid & 63, w = tid >> 6;
  __shared__ __attribute__((aligned(16))) _Float16 As[64 * 64];
  __shared__ __attribute__((aligned(16))) _Float16 Bs[128 * 64];
  __shared__ float bias_sh[128];
  const _Float16* wrow = Wc + (size_t)blockIdx.x * 16384;
  if (tid < 128) {
    float s = 0.f;
#pragma unroll
    for (int d = 0; d < 16; d++) s += emb[n * 16 + d] * gbp[d * 128 + tid];
    bias_sh[tid] = s;
  }
  f32x16 acc[2];
#pragma unroll
  for (int fm = 0; fm < 2; fm++)
#pragma unroll
    for (int q = 0; q < 16; q++) acc[fm][q] = 0.f;

  int lrow = lane >> 3;                       // staging row-within-group
  int lcolsw = (((lane & 7) ^ lrow) * 8);     // pre-swizzled source column
  int r32 = lane & 31, hi32 = lane >> 5;
  int swz = (r32 & 7) * 8;                    // read-side XOR (elem units)
  for (int k0 = 0; k0 < 128; k0 += 64) {
    __syncthreads();
#pragma unroll
    for (int i = 0; i < 2; i++) {             // A: 64 rows (b)
      int j = w * 2 + i;
      int row = j * 8 + lrow;
      gload_lds16(xg + ((size_t)row * 4096 + n) * 128 + k0 + lcolsw, &As[j * 512]);
    }
#pragma unroll
    for (int i = 0; i < 4; i++) {             // B: 128 rows (o)
      int j = w * 4 + i;
      int row = j * 8 + lrow;
      gload_lds16(wrow + row * 128 + k0 + lcolsw, &Bs[j * 512]);
    }
    __syncthreads();
#pragma unroll
    for (int kk = 0; kk < 4; kk++) {
      int col = (kk * 16 + hi32 * 8) ^ swz;
      f16x8 bf = *reinterpret_cast<const f16x8*>(&Bs[(w * 32 + r32) * 64 + col]);
#pragma unroll
      for (int fm = 0; fm < 2; fm++) {
        f16x8 af = *reinterpret_cast<const f16x8*>(&As[(fm * 32 + r32) * 64 + col]);
        acc[fm] = __builtin_amdgcn_mfma_f32_32x32x16_f16(af, bf, acc[fm], 0, 0, 0);
      }
    }
  }
  int o = w * 32 + r32;                       // wave-uniform half: w<2 -> z
  float bias = bias_sh[o];
#pragma unroll
  for (int fm = 0; fm < 2; fm++)
#pragma unroll
    for (int reg = 0; reg < 16; reg++) {
      int brow = fm * 32 + (reg & 3) + 8 * (reg >> 2) + 4 * hi32;
      float val = acc[fm][reg] + bias;
      float sg = 1.f / (1.f + __expf(-val));
      if (o < 64) zb[(n * 64 + brow) * 64 + o] = (_Float16)sg;
      else        rb[(n * 64 + brow) * 64 + (o - 64)] = (_Float16)sg;
    }
}

// ------------- 6. xs_t[b][64+o][m] = f16(z[m][b][o] * state[b][m][o]) -------
__global__ __launch_bounds__(256) void k_cand(const _Float16* __restrict__ zb,
                                              const float* __restrict__ st,
                                              _Float16* __restrict__ xs_t) {
  int m0 = blockIdx.x * 64, b = blockIdx.y, tid = threadIdx.x;
  __shared__ __attribute__((aligned(16))) _Float16 T[64][66];
#pragma unroll
  for (int i = 0; i < 16; i++) {
    int li = i * 256 + tid, ml = li >> 6, o = li & 63;
    float z = (float)zb[((m0 + ml) * 64 + b) * 64 + o];
    float s = st[(b * 4096 + m0 + ml) * 64 + o];
    T[ml][o] = (_Float16)(z * s);
  }
  __syncthreads();
  int og = tid >> 3, mch = tid & 7;
#pragma unroll
  for (int cb = 0; cb < 2; cb++) {
    int o = cb * 32 + og;
    f16x8 tmp;
#pragma unroll
    for (int j = 0; j < 8; j++) tmp[j] = T[mch * 8 + j][o];
    *reinterpret_cast<f16x8*>(&xs_t[(b * 128 + 64 + o) * 4096 + m0 + mch * 8]) = tmp;
  }
}

// ---- 7. update (MFMA, R16-proven): hc=tanh(xg2 @ Wu_n + bu);
//      h = r*state + (1-r)*hc -> out. Wave w owns fragment (fm=w>>1, fn=w&1).
__global__ __launch_bounds__(256) void k_upd(const _Float16* __restrict__ xg2,   // [b][n][128]
                                             const float* __restrict__ emb,
                                             const _Float16* __restrict__ Wc,    // chunk [2048][64][128]
                                             const float* __restrict__ ubp,
                                             int n0,
                                             const _Float16* __restrict__ rb,    // [n][b][64]
                                             const float* __restrict__ st,
                                             float* __restrict__ out) {
  int n = n0 + blockIdx.x, tid = threadIdx.x, lane = tid & 63, w = tid >> 6;
  int fm = w >> 1, fn = w & 1;
  __shared__ __attribute__((aligned(16))) _Float16 As[64 * 64];
  __shared__ __attribute__((aligned(16))) _Float16 Bs[64 * 64];
  __shared__ float bias_sh[64];
  const _Float16* wrow = Wc + (size_t)blockIdx.x * 8192;
  if (tid < 64) {
    float s = 0.f;
#pragma unroll
    for (int d = 0; d < 16; d++) s += emb[n * 16 + d] * ubp[d * 64 + tid];
    bias_sh[tid] = s;
  }
  f32x16 acc;
#pragma unroll
  for (int q = 0; q < 16; q++) acc[q] = 0.f;

  int lrow = lane >> 3;                       // staging row-within-group
  int lcolsw = (((lane & 7) ^ lrow) * 8);     // pre-swizzled source column
  int r32 = lane & 31, hi32 = lane >> 5;
  int swz = (r32 & 7) * 8;                    // read-side XOR (elem units)
  for (int k0 = 0; k0 < 128; k0 += 64) {
    __syncthreads();
#pragma unroll
    for (int i = 0; i < 2; i++) {             // A: 64 rows (b)
      int j = w * 2 + i;
      int row = j * 8 + lrow;
      gload_lds16(xg2 + ((size_t)row * 4096 + n) * 128 + k0 + lcolsw, &As[j * 512]);
    }
#pragma unroll
    for (int i = 0; i < 2; i++) {             // B: 64 rows (o)
      int j = w * 2 + i;
      int row = j * 8 + lrow;
      gload_lds16(wrow + row * 128 + k0 + lcolsw, &Bs[j * 512]);
    }
    __syncthreads();
#pragma unroll
    for (int kk = 0; kk < 4; kk++) {
      int col = (kk * 16 + hi32 * 8) ^ swz;
      f16x8 af = *reinterpret_cast<const f16x8*>(&As[(fm * 32 + r32) * 64 + col]);
      f16x8 bf = *reinterpret_cast<const f16x8*>(&Bs[(fn * 32 + r32) * 64 + col]);
      acc = __builtin_amdgcn_mfma_f32_32x32x16_f16(af, bf, acc, 0, 0, 0);
    }
  }
  int o = fn * 32 + r32;
  float bias = bias_sh[o];
#pragma unroll
  for (int reg = 0; reg < 16; reg++) {
    int brow = fm * 32 + (reg & 3) + 8 * (reg >> 2) + 4 * hi32;
    float val = acc[reg] + bias;
    float e2 = __expf(2.f * val);
    float hc = 1.f - 2.f / (e2 + 1.f);        // tanh
    float rr = (float)rb[(n * 64 + brow) * 64 + o];
    float s = st[((size_t)brow * 4096 + n) * 64 + o];
    out[((size_t)brow * 4096 + n) * 64 + o] = rr * s + (1.f - rr) * hc;
  }
}

extern "C" void kernel_launch(void* const* d_in, const int* in_sizes, int n_in,
                              void* d_out, int out_size, void* d_ws, size_t ws_size,
                              hipStream_t stream) {
  const float* x   = (const float*)d_in[0];
  const float* st  = (const float*)d_in[1];
  const float* emb = (const float*)d_in[2];
  const float* gwp = (const float*)d_in[3];
  const float* gbp = (const float*)d_in[4];
  const float* uwp = (const float*)d_in[5];
  const float* ubp = (const float*)d_in[6];
  float* out = (float*)d_out;
  char* ws = (char*)d_ws;

  // slot A [0,33.55M): S (alive through gemm2). Gate W chunks live in the
  // ENTIRE xs_t (dead between gemm1 and cand), 2 chunks x 2048 nodes linear.
  _Float16* slotA = (_Float16*)(ws + 0);
  _Float16* xs_t  = (_Float16*)(ws + 33554432);   // 67 MB [b][c][m]
  _Float16* xg    = (_Float16*)(ws + 100663296);  // 67 MB (gemm1 out; gemm2 fills c>=64)
  _Float16* zb    = (_Float16*)(ws + 167772160);  // 33.5 MB [n][b][64]; -> W_u chunks after cand
  _Float16* rb    = (_Float16*)(ws + 201326592);  // 33.5 MB [n][b][64] (alive to upd)
  float* wtg = (float*)(ws + 234881024);          // 1 MB
  float* wtu = (float*)(ws + 235929600);          // 0.5 MB
  if (ws_size < 236453888ull) return;  // fail loudly rather than corrupt

  k_wpoolT<<<1536, 256, 0, stream>>>(gwp, uwp, wtg, wtu);
  k_supports<<<1024, 256, 0, stream>>>(emb, slotA);
  k_concat<<<dim3(64, 64), 256, 0, stream>>>(x, st, xs_t);
  k_gemm<<<2048, 256, 0, stream>>>(slotA, xs_t, xg);
  // gate in 2 chunks of 2048 nodes; W chunks fill all of xs_t linearly
  for (int c = 0; c < 2; c++) {
    k_wall<<<dim3(32, 8), 256, 0, stream>>>(emb, c * 2048, wtg, 16384, xs_t);
    k_gate<<<2048, 256, 0, stream>>>(xg, emb, xs_t, gbp, c * 2048, zb, rb);
  }
  k_cand<<<dim3(64, 64), 256, 0, stream>>>(zb, st, xs_t);
  // GEMM2: S still alive in slotA; only the z*state half
  k_gemm2<<<1024, 256, 0, stream>>>(slotA, xs_t, xg);
  // update in 2 chunks of 2048 nodes; W chunk (33.55 MB) reuses zb slot (dead)
  for (int c = 0; c < 2; c++) {
    k_wall<<<dim3(32, 4), 256, 0, stream>>>(emb, c * 2048, wtu, 8192, zb);
    k_upd<<<2048, 256, 0, stream>>>(xg, emb, zb, ubp, c * 2048, rb, st, out);
  }
}

// Round 19
// 787.810 us; speedup vs baseline: 1.4423x; 1.0509x over previous
//
#include <hip/hip_runtime.h>

typedef float f32x4 __attribute__((ext_vector_type(4)));
typedef float f32x16 __attribute__((ext_vector_type(16)));
typedef _Float16 f16x8 __attribute__((ext_vector_type(8)));
typedef _Float16 f16x4 __attribute__((ext_vector_type(4)));
typedef _Float16 f16x2 __attribute__((ext_vector_type(2)));

typedef __attribute__((address_space(1))) const unsigned char gbyte;
typedef __attribute__((address_space(3))) unsigned char sbyte;
__device__ __forceinline__ void gload_lds16(const void* gp, void* lp) {
  __builtin_amdgcn_global_load_lds((gbyte*)gp, (sbyte*)lp, 16, 0, 0);
}

// ---------------- 1. weight-pool transpose to [d][o][i], f32 ----------------
__global__ __launch_bounds__(256) void k_wpoolT(const float* __restrict__ gwp,
                                                const float* __restrict__ uwp,
                                                float* __restrict__ wtg,
                                                float* __restrict__ wtu) {
  int idx = blockIdx.x * 256 + threadIdx.x;
  if (idx < 16 * 128 * 128) {
    int d = idx >> 14, rem = idx & 16383, o = rem >> 7, i = rem & 127;
    wtg[idx] = gwp[(d << 14) + (i << 7) + o];          // gwp[d][i][o]
  } else {
    int j = idx - 16 * 128 * 128;
    if (j < 16 * 64 * 128) {
      int d = j >> 13, rem = j & 8191, o = rem >> 7, i = rem & 127;
      wtu[j] = uwp[(d << 13) + (i << 6) + o];          // uwp[d][i][o(64)]
    }
  }
}

// -------- 2. supports = softmax(relu(E E^T)), 4 rows/block (emb reuse) ------
__global__ __launch_bounds__(256) void k_supports(const float* __restrict__ emb,
                                                  _Float16* __restrict__ S) {
  int n0 = blockIdx.x * 4, tid = threadIdx.x;
  __shared__ float e_sh[4][16];
  __shared__ float red[4][4];
  if (tid < 16) {
    int r = tid >> 2, part = tid & 3;
    f32x4 v = *reinterpret_cast<const f32x4*>(emb + (n0 + r) * 16 + part * 4);
    *reinterpret_cast<f32x4*>(&e_sh[r][part * 4]) = v;
  }
  __syncthreads();
  float v[4][16];
  float sum[4] = {0.f, 0.f, 0.f, 0.f};
#pragma unroll
  for (int i = 0; i < 16; i++) {
    int m = i * 256 + tid;
    const f32x4* em = reinterpret_cast<const f32x4*>(emb + m * 16);
    f32x4 e0 = em[0], e1 = em[1], e2 = em[2], e3 = em[3];
#pragma unroll
    for (int r = 0; r < 4; r++) {
      float acc = 0.f;
#pragma unroll
      for (int q = 0; q < 4; q++) acc += e_sh[r][q] * e0[q];
#pragma unroll
      for (int q = 0; q < 4; q++) acc += e_sh[r][4 + q] * e1[q];
#pragma unroll
      for (int q = 0; q < 4; q++) acc += e_sh[r][8 + q] * e2[q];
#pragma unroll
      for (int q = 0; q < 4; q++) acc += e_sh[r][12 + q] * e3[q];
      acc = fmaxf(acc, 0.f);
      float e = __expf(acc);
      v[r][i] = e;
      sum[r] += e;
    }
  }
#pragma unroll
  for (int r = 0; r < 4; r++)
#pragma unroll
    for (int off = 32; off > 0; off >>= 1) sum[r] += __shfl_down(sum[r], off);
  if ((tid & 63) == 0) {
#pragma unroll
    for (int r = 0; r < 4; r++) red[tid >> 6][r] = sum[r];
  }
  __syncthreads();
  float inv[4];
#pragma unroll
  for (int r = 0; r < 4; r++)
    inv[r] = 1.f / (red[0][r] + red[1][r] + red[2][r] + red[3][r]);
#pragma unroll
  for (int i = 0; i < 16; i++)
#pragma unroll
    for (int r = 0; r < 4; r++)
      S[(size_t)(n0 + r) * 4096 + i * 256 + tid] = (_Float16)(v[r][i] * inv[r]);
}

// ------- 3. xs_t[b][c][m] = f16(concat(x,state))  (c-major for GEMM B) ------
__global__ __launch_bounds__(256) void k_concat(const float* __restrict__ x,
                                                const float* __restrict__ st,
                                                _Float16* __restrict__ xs_t) {
  int m0 = blockIdx.x * 64, b = blockIdx.y, tid = threadIdx.x;
  __shared__ __attribute__((aligned(16))) _Float16 T[64][130];
#pragma unroll
  for (int i = 0; i < 16; i++) {
    int li = i * 256 + tid;
    int ml = li >> 6, c = li & 63;
    int base = (b * 4096 + m0 + ml) * 64 + c;
    T[ml][c] = (_Float16)x[base];
    T[ml][64 + c] = (_Float16)st[base];
  }
  __syncthreads();
  int cg = tid >> 3, mch = tid & 7;
#pragma unroll
  for (int cb = 0; cb < 4; cb++) {
    int c = cb * 32 + cg;
    f16x8 tmp;
#pragma unroll
    for (int j = 0; j < 8; j++) tmp[j] = T[mch * 8 + j][c];
    *reinterpret_cast<f16x8*>(&xs_t[(b * 128 + c) * 4096 + m0 + mch * 8]) = tmp;
  }
}

// -------- 4. GEMM1 (R11/R17-proven: 32x32x16, 2x2 waves, x-major order) -----
__global__ __launch_bounds__(256) void k_gemm(const _Float16* __restrict__ S,
                                              const _Float16* __restrict__ Xt,
                                              _Float16* __restrict__ Y) {
  int nt = blockIdx.x & 31, b = blockIdx.x >> 5;     // R17 x-major mapping
  int tid = threadIdx.x, lane = tid & 63, w = tid >> 6;
  int wr = w >> 1, wc = w & 1;
  __shared__ __attribute__((aligned(16))) _Float16 As[128 * 64];
  __shared__ __attribute__((aligned(16))) _Float16 Bs[128 * 64];
  const _Float16* Sb = S + nt * 128 * 4096;
  const _Float16* Xb = Xt + (size_t)b * 128 * 4096;
  f32x16 acc[2][2];
#pragma unroll
  for (int fm = 0; fm < 2; fm++)
#pragma unroll
    for (int fn = 0; fn < 2; fn++)
#pragma unroll
      for (int q = 0; q < 16; q++) acc[fm][fn][q] = 0.f;

  int lrow = lane >> 3;                       // staging row-within-group
  int lcolsw = (((lane & 7) ^ lrow) * 8);     // pre-swizzled source column
  int r32 = lane & 31, hi32 = lane >> 5;
  int swz = (r32 & 7) * 8;                    // read-side XOR (elem units)
  for (int k0 = 0; k0 < 4096; k0 += 64) {
    __syncthreads();
#pragma unroll
    for (int i = 0; i < 4; i++) {
      int j = w * 4 + i;
      int row = j * 8 + lrow;
      gload_lds16(Sb + row * 4096 + k0 + lcolsw, &As[j * 512]);
      gload_lds16(Xb + row * 4096 + k0 + lcolsw, &Bs[j * 512]);
    }
    __syncthreads();
#pragma unroll
    for (int kk = 0; kk < 4; kk++) {
      int col = (kk * 16 + hi32 * 8) ^ swz;
      f16x8 af[2], bf[2];
#pragma unroll
      for (int fm = 0; fm < 2; fm++)
        af[fm] = *reinterpret_cast<const f16x8*>(&As[(wr * 64 + fm * 32 + r32) * 64 + col]);
#pragma unroll
      for (int fn = 0; fn < 2; fn++)
        bf[fn] = *reinterpret_cast<const f16x8*>(&Bs[(wc * 64 + fn * 32 + r32) * 64 + col]);
#pragma unroll
      for (int fm = 0; fm < 2; fm++)
#pragma unroll
        for (int fn = 0; fn < 2; fn++)
          acc[fm][fn] = __builtin_amdgcn_mfma_f32_32x32x16_f16(af[fm], bf[fn], acc[fm][fn], 0, 0, 0);
    }
  }
#pragma unroll
  for (int fm = 0; fm < 2; fm++)
#pragma unroll
    for (int fn = 0; fn < 2; fn++)
#pragma unroll
      for (int reg = 0; reg < 16; reg++) {
        int row = nt * 128 + wr * 64 + fm * 32 + (reg & 3) + 8 * (reg >> 2) + 4 * hi32;
        int c = wc * 64 + fn * 32 + r32;
        Y[((size_t)b * 4096 + row) * 128 + c] = (_Float16)acc[fm][fn][reg];
      }
}

// -------- 4b. GEMM2 (R17-proven half-N, x-major): c in [64,128) -------------
__global__ __launch_bounds__(256) void k_gemm2(const _Float16* __restrict__ S,
                                               const _Float16* __restrict__ Xt,
                                               _Float16* __restrict__ Y) {
  int nt = blockIdx.x & 31, bp = blockIdx.x >> 5;
  int tid = threadIdx.x, lane = tid & 63, w = tid >> 6;
  int wr = w >> 1, wc = w & 1;
  __shared__ __attribute__((aligned(16))) _Float16 As[128 * 64];
  __shared__ __attribute__((aligned(16))) _Float16 Bs[128 * 64];
  const _Float16* Sb = S + nt * 128 * 4096;
  const _Float16* Xb = Xt + (size_t)(256 * bp + 64) * 4096;
  f32x16 acc[2][2];
#pragma unroll
  for (int fm = 0; fm < 2; fm++)
#pragma unroll
    for (int fn = 0; fn < 2; fn++)
#pragma unroll
      for (int q = 0; q < 16; q++) acc[fm][fn][q] = 0.f;

  int lrow = lane >> 3;
  int lcolsw = (((lane & 7) ^ lrow) * 8);
  int r32 = lane & 31, hi32 = lane >> 5;
  int swz = (r32 & 7) * 8;
  for (int k0 = 0; k0 < 4096; k0 += 64) {
    __syncthreads();
#pragma unroll
    for (int i = 0; i < 4; i++) {
      int j = w * 4 + i;
      int row = j * 8 + lrow;                              // 0..127 tile row
      int groff = ((row >> 6) * 128 + (row & 63)) * 4096;  // batch-pair map
      gload_lds16(Sb + row * 4096 + k0 + lcolsw, &As[j * 512]);
      gload_lds16(Xb + groff + k0 + lcolsw, &Bs[j * 512]);
    }
    __syncthreads();
#pragma unroll
    for (int kk = 0; kk < 4; kk++) {
      int col = (kk * 16 + hi32 * 8) ^ swz;
      f16x8 af[2], bf[2];
#pragma unroll
      for (int fm = 0; fm < 2; fm++)
        af[fm] = *reinterpret_cast<const f16x8*>(&As[(wr * 64 + fm * 32 + r32) * 64 + col]);
#pragma unroll
      for (int fn = 0; fn < 2; fn++)
        bf[fn] = *reinterpret_cast<const f16x8*>(&Bs[(wc * 64 + fn * 32 + r32) * 64 + col]);
#pragma unroll
      for (int fm = 0; fm < 2; fm++)
#pragma unroll
        for (int fn = 0; fn < 2; fn++)
          acc[fm][fn] = __builtin_amdgcn_mfma_f32_32x32x16_f16(af[fm], bf[fn], acc[fm][fn], 0, 0, 0);
    }
  }
#pragma unroll
  for (int fm = 0; fm < 2; fm++)
#pragma unroll
    for (int fn = 0; fn < 2; fn++)
#pragma unroll
      for (int reg = 0; reg < 16; reg++) {
        int row = nt * 128 + wr * 64 + fm * 32 + (reg & 3) + 8 * (reg >> 2) + 4 * hi32;
        int ct = wc * 64 + fn * 32 + r32;       // 0..127 tile col
        int batch = 2 * bp + (ct >> 6);
        int c = 64 + (ct & 63);
        Y[((size_t)batch * 4096 + row) * 128 + c] = (_Float16)acc[fm][fn][reg];
      }
}

// ---- 5a. k_wall: W_all[node][o*i] = f16( sum_d E[n0+node][d] * wt[d][o*i] )
__global__ __launch_bounds__(256) void k_wall(const float* __restrict__ emb, int n0,
                                              const float* __restrict__ wt, int OI,
                                              _Float16* __restrict__ Wout) {
  int bx = blockIdx.x, by = blockIdx.y, tid = threadIdx.x;
  __shared__ float e_sh[64][16];
  {
    int node = tid >> 2, part = tid & 3;
    f32x4 v = *reinterpret_cast<const f32x4*>(emb + (n0 + bx * 64 + node) * 16 + part * 4);
    *reinterpret_cast<f32x4*>(&e_sh[node][part * 4]) = v;
  }
  __syncthreads();
  int oi0 = by * 2048 + tid * 8;
#pragma unroll
  for (int g = 0; g < 8; g++) {
    f32x4 a0[8], a1[8];
#pragma unroll
    for (int nn = 0; nn < 8; nn++) { a0[nn] = (f32x4){0,0,0,0}; a1[nn] = (f32x4){0,0,0,0}; }
#pragma unroll
    for (int d = 0; d < 16; d++) {
      const f32x4* p = reinterpret_cast<const f32x4*>(wt + d * OI + oi0);
      f32x4 v0 = p[0], v1 = p[1];
#pragma unroll
      for (int nn = 0; nn < 8; nn++) {
        float e = e_sh[g * 8 + nn][d];
        a0[nn] += e * v0;
        a1[nn] += e * v1;
      }
    }
#pragma unroll
    for (int nn = 0; nn < 8; nn++) {
      f16x8 pk;
#pragma unroll
      for (int q = 0; q < 4; q++) { pk[q] = (_Float16)a0[nn][q]; pk[4 + q] = (_Float16)a1[nn][q]; }
      int node = bx * 64 + g * 8 + nn;                 // chunk-local
      *reinterpret_cast<f16x8*>(Wout + (size_t)node * OI + oi0) = pk;
    }
  }
}

// ---- 5b. gate (MFMA, R15-proven): z_r = sigmoid(x_g @ W_n + b_n) -----------
__global__ __launch_bounds__(256) void k_gate(const _Float16* __restrict__ xg,   // [b][n][128]
                                              const float* __restrict__ emb,
                                              const _Float16* __restrict__ Wc,   // chunk [2048][128][128] (in xs_t)
                                              const float* __restrict__ gbp,
                                              int n0,
                                              _Float16* __restrict__ zb,         // [n][b][64]
                                              _Float16* __restrict__ rb) {       // [n][b][64]
  int n = n0 + blockIdx.x, tid = threadIdx.x, lane = tid & 63, w = tid >> 6;
  __shared__ __attribute__((aligned(16))) _Float16 As[64 * 64];
  __shared__ __attribute__((aligned(16))) _Float16 Bs[128 * 64];
  __shared__ float bias_sh[128];
  const _Float16* wrow = Wc + (size_t)blockIdx.x * 16384;
  if (tid < 128) {
    float s = 0.f;
#pragma unroll
    for (int d = 0; d < 16; d++) s += emb[n * 16 + d] * gbp[d * 128 + tid];
    bias_sh[tid] = s;
  }
  f32x16 acc[2];
#pragma unroll
  for (int fm = 0; fm < 2; fm++)
#pragma unroll
    for (int q = 0; q < 16; q++) acc[fm][q] = 0.f;

  int lrow = lane >> 3;                       // staging row-within-group
  int lcolsw = (((lane & 7) ^ lrow) * 8);     // pre-swizzled source column
  int r32 = lane & 31, hi32 = lane >> 5;
  int swz = (r32 & 7) * 8;                    // read-side XOR (elem units)
  for (int k0 = 0; k0 < 128; k0 += 64) {
    __syncthreads();
#pragma unroll
    for (int i = 0; i < 2; i++) {             // A: 64 rows (b)
      int j = w * 2 + i;
      int row = j * 8 + lrow;
      gload_lds16(xg + ((size_t)row * 4096 + n) * 128 + k0 + lcolsw, &As[j * 512]);
    }
#pragma unroll
    for (int i = 0; i < 4; i++) {             // B: 128 rows (o)
      int j = w * 4 + i;
      int row = j * 8 + lrow;
      gload_lds16(wrow + row * 128 + k0 + lcolsw, &Bs[j * 512]);
    }
    __syncthreads();
#pragma unroll
    for (int kk = 0; kk < 4; kk++) {
      int col = (kk * 16 + hi32 * 8) ^ swz;
      f16x8 bf = *reinterpret_cast<const f16x8*>(&Bs[(w * 32 + r32) * 64 + col]);
#pragma unroll
      for (int fm = 0; fm < 2; fm++) {
        f16x8 af = *reinterpret_cast<const f16x8*>(&As[(fm * 32 + r32) * 64 + col]);
        acc[fm] = __builtin_amdgcn_mfma_f32_32x32x16_f16(af, bf, acc[fm], 0, 0, 0);
      }
    }
  }
  int o = w * 32 + r32;                       // wave-uniform half: w<2 -> z
  float bias = bias_sh[o];
#pragma unroll
  for (int fm = 0; fm < 2; fm++)
#pragma unroll
    for (int reg = 0; reg < 16; reg++) {
      int brow = fm * 32 + (reg & 3) + 8 * (reg >> 2) + 4 * hi32;
      float val = acc[fm][reg] + bias;
      float sg = 1.f / (1.f + __expf(-val));
      if (o < 64) zb[(n * 64 + brow) * 64 + o] = (_Float16)sg;
      else        rb[(n * 64 + brow) * 64 + (o - 64)] = (_Float16)sg;
    }
}

// ------------- 6. xs_t[b][64+o][m] = f16(z[m][b][o] * state[b][m][o]) -------
__global__ __launch_bounds__(256) void k_cand(const _Float16* __restrict__ zb,
                                              const float* __restrict__ st,
                                              _Float16* __restrict__ xs_t) {
  int m0 = blockIdx.x * 64, b = blockIdx.y, tid = threadIdx.x;
  __shared__ __attribute__((aligned(16))) _Float16 T[64][66];
#pragma unroll
  for (int i = 0; i < 16; i++) {
    int li = i * 256 + tid, ml = li >> 6, o = li & 63;
    float z = (float)zb[((m0 + ml) * 64 + b) * 64 + o];
    float s = st[(b * 4096 + m0 + ml) * 64 + o];
    T[ml][o] = (_Float16)(z * s);
  }
  __syncthreads();
  int og = tid >> 3, mch = tid & 7;
#pragma unroll
  for (int cb = 0; cb < 2; cb++) {
    int o = cb * 32 + og;
    f16x8 tmp;
#pragma unroll
    for (int j = 0; j < 8; j++) tmp[j] = T[mch * 8 + j][o];
    *reinterpret_cast<f16x8*>(&xs_t[(b * 128 + 64 + o) * 4096 + m0 + mch * 8]) = tmp;
  }
}

// ---- 7. update (MFMA, R16-proven): hc=tanh(xg2 @ Wu_n + bu);
//      h = r*state + (1-r)*hc -> out. Wave w owns fragment (fm=w>>1, fn=w&1).
__global__ __launch_bounds__(256) void k_upd(const _Float16* __restrict__ xg2,   // [b][n][128]
                                             const float* __restrict__ emb,
                                             const _Float16* __restrict__ Wc,    // chunk [2048][64][128]
                                             const float* __restrict__ ubp,
                                             int n0,
                                             const _Float16* __restrict__ rb,    // [n][b][64]
                                             const float* __restrict__ st,
                                             float* __restrict__ out) {
  int n = n0 + blockIdx.x, tid = threadIdx.x, lane = tid & 63, w = tid >> 6;
  int fm = w >> 1, fn = w & 1;
  __shared__ __attribute__((aligned(16))) _Float16 As[64 * 64];
  __shared__ __attribute__((aligned(16))) _Float16 Bs[64 * 64];
  __shared__ float bias_sh[64];
  const _Float16* wrow = Wc + (size_t)blockIdx.x * 8192;
  if (tid < 64) {
    float s = 0.f;
#pragma unroll
    for (int d = 0; d < 16; d++) s += emb[n * 16 + d] * ubp[d * 64 + tid];
    bias_sh[tid] = s;
  }
  f32x16 acc;
#pragma unroll
  for (int q = 0; q < 16; q++) acc[q] = 0.f;

  int lrow = lane >> 3;                       // staging row-within-group
  int lcolsw = (((lane & 7) ^ lrow) * 8);     // pre-swizzled source column
  int r32 = lane & 31, hi32 = lane >> 5;
  int swz = (r32 & 7) * 8;                    // read-side XOR (elem units)
  for (int k0 = 0; k0 < 128; k0 += 64) {
    __syncthreads();
#pragma unroll
    for (int i = 0; i < 2; i++) {             // A: 64 rows (b)
      int j = w * 2 + i;
      int row = j * 8 + lrow;
      gload_lds16(xg2 + ((size_t)row * 4096 + n) * 128 + k0 + lcolsw, &As[j * 512]);
    }
#pragma unroll
    for (int i = 0; i < 2; i++) {             // B: 64 rows (o)
      int j = w * 2 + i;
      int row = j * 8 + lrow;
      gload_lds16(wrow + row * 128 + k0 + lcolsw, &Bs[j * 512]);
    }
    __syncthreads();
#pragma unroll
    for (int kk = 0; kk < 4; kk++) {
      int col = (kk * 16 + hi32 * 8) ^ swz;
      f16x8 af = *reinterpret_cast<const f16x8*>(&As[(fm * 32 + r32) * 64 + col]);
      f16x8 bf = *reinterpret_cast<const f16x8*>(&Bs[(fn * 32 + r32) * 64 + col]);
      acc = __builtin_amdgcn_mfma_f32_32x32x16_f16(af, bf, acc, 0, 0, 0);
    }
  }
  int o = fn * 32 + r32;
  float bias = bias_sh[o];
#pragma unroll
  for (int reg = 0; reg < 16; reg++) {
    int brow = fm * 32 + (reg & 3) + 8 * (reg >> 2) + 4 * hi32;
    float val = acc[reg] + bias;
    float e2 = __expf(2.f * val);
    float hc = 1.f - 2.f / (e2 + 1.f);        // tanh
    float rr = (float)rb[(n * 64 + brow) * 64 + o];
    float s = st[((size_t)brow * 4096 + n) * 64 + o];
    out[((size_t)brow * 4096 + n) * 64 + o] = rr * s + (1.f - rr) * hc;
  }
}

extern "C" void kernel_launch(void* const* d_in, const int* in_sizes, int n_in,
                              void* d_out, int out_size, void* d_ws, size_t ws_size,
                              hipStream_t stream) {
  const float* x   = (const float*)d_in[0];
  const float* st  = (const float*)d_in[1];
  const float* emb = (const float*)d_in[2];
  const float* gwp = (const float*)d_in[3];
  const float* gbp = (const float*)d_in[4];
  const float* uwp = (const float*)d_in[5];
  const float* ubp = (const float*)d_in[6];
  float* out = (float*)d_out;
  char* ws = (char*)d_ws;

  // slot A [0,33.55M): S (alive through gemm2). Gate W chunks live in the
  // ENTIRE xs_t (dead between gemm1 and cand), 2 chunks x 2048 nodes linear.
  _Float16* slotA = (_Float16*)(ws + 0);
  _Float16* xs_t  = (_Float16*)(ws + 33554432);   // 67 MB [b][c][m]
  _Float16* xg    = (_Float16*)(ws + 100663296);  // 67 MB (gemm1 out; gemm2 fills c>=64)
  _Float16* zb    = (_Float16*)(ws + 167772160);  // 33.5 MB [n][b][64]; -> W_u chunks after cand
  _Float16* rb    = (_Float16*)(ws + 201326592);  // 33.5 MB [n][b][64] (alive to upd)
  float* wtg = (float*)(ws + 234881024);          // 1 MB
  float* wtu = (float*)(ws + 235929600);          // 0.5 MB
  if (ws_size < 236453888ull) return;  // fail loudly rather than corrupt

  k_wpoolT<<<1536, 256, 0, stream>>>(gwp, uwp, wtg, wtu);
  k_supports<<<1024, 256, 0, stream>>>(emb, slotA);
  k_concat<<<dim3(64, 64), 256, 0, stream>>>(x, st, xs_t);
  k_gemm<<<2048, 256, 0, stream>>>(slotA, xs_t, xg);
  // gate in 2 chunks of 2048 nodes; W chunks fill all of xs_t linearly
  for (int c = 0; c < 2; c++) {
    k_wall<<<dim3(32, 8), 256, 0, stream>>>(emb, c * 2048, wtg, 16384, xs_t);
    k_gate<<<2048, 256, 0, stream>>>(xg, emb, xs_t, gbp, c * 2048, zb, rb);
  }
  k_cand<<<dim3(64, 64), 256, 0, stream>>>(zb, st, xs_t);
  // GEMM2: S still alive in slotA; only the z*state half
  k_gemm2<<<1024, 256, 0, stream>>>(slotA, xs_t, xg);
  // update in 2 chunks of 2048 nodes; W chunk (33.55 MB) reuses zb slot (dead)
  for (int c = 0; c < 2; c++) {
    k_wall<<<dim3(32, 4), 256, 0, stream>>>(emb, c * 2048, wtu, 8192, zb);
    k_upd<<<2048, 256, 0, stream>>>(xg, emb, zb, ubp, c * 2048, rb, st, out);
  }
}

// Round 20
// 739.363 us; speedup vs baseline: 1.5368x; 1.0655x over previous
//
#include <hip/hip_runtime.h>

typedef float f32x4 __attribute__((ext_vector_type(4)));
typedef float f32x16 __attribute__((ext_vector_type(16)));
typedef _Float16 f16x8 __attribute__((ext_vector_type(8)));
typedef _Float16 f16x4 __attribute__((ext_vector_type(4)));
typedef _Float16 f16x2 __attribute__((ext_vector_type(2)));

typedef __attribute__((address_space(1))) const unsigned char gbyte;
typedef __attribute__((address_space(3))) unsigned char sbyte;
__device__ __forceinline__ void gload_lds16(const void* gp, void* lp) {
  __builtin_amdgcn_global_load_lds((gbyte*)gp, (sbyte*)lp, 16, 0, 0);
}

// ---------------- 1. weight-pool transpose to [d][o][i], f32 ----------------
__global__ __launch_bounds__(256) void k_wpoolT(const float* __restrict__ gwp,
                                                const float* __restrict__ uwp,
                                                float* __restrict__ wtg,
                                                float* __restrict__ wtu) {
  int idx = blockIdx.x * 256 + threadIdx.x;
  if (idx < 16 * 128 * 128) {
    int d = idx >> 14, rem = idx & 16383, o = rem >> 7, i = rem & 127;
    wtg[idx] = gwp[(d << 14) + (i << 7) + o];          // gwp[d][i][o]
  } else {
    int j = idx - 16 * 128 * 128;
    if (j < 16 * 64 * 128) {
      int d = j >> 13, rem = j & 8191, o = rem >> 7, i = rem & 127;
      wtu[j] = uwp[(d << 13) + (i << 6) + o];          // uwp[d][i][o(64)]
    }
  }
}

// -------- 2. supports = softmax(relu(E E^T)), 4 rows/block (emb reuse) ------
__global__ __launch_bounds__(256) void k_supports(const float* __restrict__ emb,
                                                  _Float16* __restrict__ S) {
  int n0 = blockIdx.x * 4, tid = threadIdx.x;
  __shared__ float e_sh[4][16];
  __shared__ float red[4][4];
  if (tid < 16) {
    int r = tid >> 2, part = tid & 3;
    f32x4 v = *reinterpret_cast<const f32x4*>(emb + (n0 + r) * 16 + part * 4);
    *reinterpret_cast<f32x4*>(&e_sh[r][part * 4]) = v;
  }
  __syncthreads();
  float v[4][16];
  float sum[4] = {0.f, 0.f, 0.f, 0.f};
#pragma unroll
  for (int i = 0; i < 16; i++) {
    int m = i * 256 + tid;
    const f32x4* em = reinterpret_cast<const f32x4*>(emb + m * 16);
    f32x4 e0 = em[0], e1 = em[1], e2 = em[2], e3 = em[3];
#pragma unroll
    for (int r = 0; r < 4; r++) {
      float acc = 0.f;
#pragma unroll
      for (int q = 0; q < 4; q++) acc += e_sh[r][q] * e0[q];
#pragma unroll
      for (int q = 0; q < 4; q++) acc += e_sh[r][4 + q] * e1[q];
#pragma unroll
      for (int q = 0; q < 4; q++) acc += e_sh[r][8 + q] * e2[q];
#pragma unroll
      for (int q = 0; q < 4; q++) acc += e_sh[r][12 + q] * e3[q];
      acc = fmaxf(acc, 0.f);
      float e = __expf(acc);
      v[r][i] = e;
      sum[r] += e;
    }
  }
#pragma unroll
  for (int r = 0; r < 4; r++)
#pragma unroll
    for (int off = 32; off > 0; off >>= 1) sum[r] += __shfl_down(sum[r], off);
  if ((tid & 63) == 0) {
#pragma unroll
    for (int r = 0; r < 4; r++) red[tid >> 6][r] = sum[r];
  }
  __syncthreads();
  float inv[4];
#pragma unroll
  for (int r = 0; r < 4; r++)
    inv[r] = 1.f / (red[0][r] + red[1][r] + red[2][r] + red[3][r]);
#pragma unroll
  for (int i = 0; i < 16; i++)
#pragma unroll
    for (int r = 0; r < 4; r++)
      S[(size_t)(n0 + r) * 4096 + i * 256 + tid] = (_Float16)(v[r][i] * inv[r]);
}

// ------- 3. xs_t[b][c][m] = f16(concat(x,state))  (c-major for GEMM B) ------
__global__ __launch_bounds__(256) void k_concat(const float* __restrict__ x,
                                                const float* __restrict__ st,
                                                _Float16* __restrict__ xs_t) {
  int m0 = blockIdx.x * 64, b = blockIdx.y, tid = threadIdx.x;
  __shared__ __attribute__((aligned(16))) _Float16 T[64][130];
#pragma unroll
  for (int i = 0; i < 16; i++) {
    int li = i * 256 + tid;
    int ml = li >> 6, c = li & 63;
    int base = (b * 4096 + m0 + ml) * 64 + c;
    T[ml][c] = (_Float16)x[base];
    T[ml][64 + c] = (_Float16)st[base];
  }
  __syncthreads();
  int cg = tid >> 3, mch = tid & 7;
#pragma unroll
  for (int cb = 0; cb < 4; cb++) {
    int c = cb * 32 + cg;
    f16x8 tmp;
#pragma unroll
    for (int j = 0; j < 8; j++) tmp[j] = T[mch * 8 + j][c];
    *reinterpret_cast<f16x8*>(&xs_t[(b * 128 + c) * 4096 + m0 + mch * 8]) = tmp;
  }
}

// -------- 4. GEMM1 (256Mx128N tile, 512 thr, 8 waves 4x2, 64x64 wave-tile) --
// Same MFMA core/fragment maps/swizzle as R11-proven; bigger tile halves the
// per-FLOP staged L2/L3 traffic (2 MB -> 3 MB per 2x blocks). acc stays 64
// VGPR; LDS 48 KB -> 3 blocks/CU.
__global__ __launch_bounds__(512) void k_gemm(const _Float16* __restrict__ S,
                                              const _Float16* __restrict__ Xt,
                                              _Float16* __restrict__ Y) {
  int nt = blockIdx.x, b = blockIdx.y;       // x fastest: consecutive share Xb
  int tid = threadIdx.x, lane = tid & 63, w = tid >> 6;   // w 0..7
  int wr = w >> 1, wc = w & 1;               // 4 x 2 wave grid
  __shared__ __attribute__((aligned(16))) _Float16 As[256 * 64];
  __shared__ __attribute__((aligned(16))) _Float16 Bs[128 * 64];
  const _Float16* Sb = S + (size_t)nt * 256 * 4096;
  const _Float16* Xb = Xt + (size_t)b * 128 * 4096;
  f32x16 acc[2][2];
#pragma unroll
  for (int fm = 0; fm < 2; fm++)
#pragma unroll
    for (int fn = 0; fn < 2; fn++)
#pragma unroll
      for (int q = 0; q < 16; q++) acc[fm][fn][q] = 0.f;

  int lrow = lane >> 3;                       // staging row-within-group
  int lcolsw = (((lane & 7) ^ lrow) * 8);     // pre-swizzled source column
  int r32 = lane & 31, hi32 = lane >> 5;
  int swz = (r32 & 7) * 8;                    // read-side XOR (elem units)
  for (int k0 = 0; k0 < 4096; k0 += 64) {
    __syncthreads();
#pragma unroll
    for (int i = 0; i < 4; i++) {             // A: 256 rows, 32 j-groups
      int j = w * 4 + i;
      int row = j * 8 + lrow;
      gload_lds16(Sb + (size_t)row * 4096 + k0 + lcolsw, &As[j * 512]);
    }
#pragma unroll
    for (int i = 0; i < 2; i++) {             // B: 128 rows, 16 j-groups
      int j = w * 2 + i;
      int row = j * 8 + lrow;
      gload_lds16(Xb + (size_t)row * 4096 + k0 + lcolsw, &Bs[j * 512]);
    }
    __syncthreads();
#pragma unroll
    for (int kk = 0; kk < 4; kk++) {
      int col = (kk * 16 + hi32 * 8) ^ swz;
      f16x8 af[2], bf[2];
#pragma unroll
      for (int fm = 0; fm < 2; fm++)
        af[fm] = *reinterpret_cast<const f16x8*>(&As[(wr * 64 + fm * 32 + r32) * 64 + col]);
#pragma unroll
      for (int fn = 0; fn < 2; fn++)
        bf[fn] = *reinterpret_cast<const f16x8*>(&Bs[(wc * 64 + fn * 32 + r32) * 64 + col]);
#pragma unroll
      for (int fm = 0; fm < 2; fm++)
#pragma unroll
        for (int fn = 0; fn < 2; fn++)
          acc[fm][fn] = __builtin_amdgcn_mfma_f32_32x32x16_f16(af[fm], bf[fn], acc[fm][fn], 0, 0, 0);
    }
  }
#pragma unroll
  for (int fm = 0; fm < 2; fm++)
#pragma unroll
    for (int fn = 0; fn < 2; fn++)
#pragma unroll
      for (int reg = 0; reg < 16; reg++) {
        int row = nt * 256 + wr * 64 + fm * 32 + (reg & 3) + 8 * (reg >> 2) + 4 * hi32;
        int c = wc * 64 + fn * 32 + r32;
        Y[((size_t)b * 4096 + row) * 128 + c] = (_Float16)acc[fm][fn][reg];
      }
}

// -------- 4b. GEMM2 (256Mx128N, 512 thr): c in [64,128) of batch pair -------
__global__ __launch_bounds__(512) void k_gemm2(const _Float16* __restrict__ S,
                                               const _Float16* __restrict__ Xt,
                                               _Float16* __restrict__ Y) {
  int nt = blockIdx.x, bp = blockIdx.y;
  int tid = threadIdx.x, lane = tid & 63, w = tid >> 6;
  int wr = w >> 1, wc = w & 1;
  __shared__ __attribute__((aligned(16))) _Float16 As[256 * 64];
  __shared__ __attribute__((aligned(16))) _Float16 Bs[128 * 64];
  const _Float16* Sb = S + (size_t)nt * 256 * 4096;
  const _Float16* Xb = Xt + (size_t)(256 * bp + 64) * 4096;
  f32x16 acc[2][2];
#pragma unroll
  for (int fm = 0; fm < 2; fm++)
#pragma unroll
    for (int fn = 0; fn < 2; fn++)
#pragma unroll
      for (int q = 0; q < 16; q++) acc[fm][fn][q] = 0.f;

  int lrow = lane >> 3;
  int lcolsw = (((lane & 7) ^ lrow) * 8);
  int r32 = lane & 31, hi32 = lane >> 5;
  int swz = (r32 & 7) * 8;
  for (int k0 = 0; k0 < 4096; k0 += 64) {
    __syncthreads();
#pragma unroll
    for (int i = 0; i < 4; i++) {             // A: 256 rows
      int j = w * 4 + i;
      int row = j * 8 + lrow;
      gload_lds16(Sb + (size_t)row * 4096 + k0 + lcolsw, &As[j * 512]);
    }
#pragma unroll
    for (int i = 0; i < 2; i++) {             // B: 128 rows (batch-pair map)
      int j = w * 2 + i;
      int row = j * 8 + lrow;                              // 0..127 tile row
      int groff = ((row >> 6) * 128 + (row & 63)) * 4096;
      gload_lds16(Xb + (size_t)groff + k0 + lcolsw, &Bs[j * 512]);
    }
    __syncthreads();
#pragma unroll
    for (int kk = 0; kk < 4; kk++) {
      int col = (kk * 16 + hi32 * 8) ^ swz;
      f16x8 af[2], bf[2];
#pragma unroll
      for (int fm = 0; fm < 2; fm++)
        af[fm] = *reinterpret_cast<const f16x8*>(&As[(wr * 64 + fm * 32 + r32) * 64 + col]);
#pragma unroll
      for (int fn = 0; fn < 2; fn++)
        bf[fn] = *reinterpret_cast<const f16x8*>(&Bs[(wc * 64 + fn * 32 + r32) * 64 + col]);
#pragma unroll
      for (int fm = 0; fm < 2; fm++)
#pragma unroll
        for (int fn = 0; fn < 2; fn++)
          acc[fm][fn] = __builtin_amdgcn_mfma_f32_32x32x16_f16(af[fm], bf[fn], acc[fm][fn], 0, 0, 0);
    }
  }
#pragma unroll
  for (int fm = 0; fm < 2; fm++)
#pragma unroll
    for (int fn = 0; fn < 2; fn++)
#pragma unroll
      for (int reg = 0; reg < 16; reg++) {
        int row = nt * 256 + wr * 64 + fm * 32 + (reg & 3) + 8 * (reg >> 2) + 4 * hi32;
        int ct = wc * 64 + fn * 32 + r32;       // 0..127 tile col
        int batch = 2 * bp + (ct >> 6);
        int c = 64 + (ct & 63);
        Y[((size_t)batch * 4096 + row) * 128 + c] = (_Float16)acc[fm][fn][reg];
      }
}

// ---- 5a. k_wall: W_all[node][o*i] = f16( sum_d E[n0+node][d] * wt[d][o*i] )
__global__ __launch_bounds__(256) void k_wall(const float* __restrict__ emb, int n0,
                                              const float* __restrict__ wt, int OI,
                                              _Float16* __restrict__ Wout) {
  int bx = blockIdx.x, by = blockIdx.y, tid = threadIdx.x;
  __shared__ float e_sh[64][16];
  {
    int node = tid >> 2, part = tid & 3;
    f32x4 v = *reinterpret_cast<const f32x4*>(emb + (n0 + bx * 64 + node) * 16 + part * 4);
    *reinterpret_cast<f32x4*>(&e_sh[node][part * 4]) = v;
  }
  __syncthreads();
  int oi0 = by * 2048 + tid * 8;
#pragma unroll
  for (int g = 0; g < 8; g++) {
    f32x4 a0[8], a1[8];
#pragma unroll
    for (int nn = 0; nn < 8; nn++) { a0[nn] = (f32x4){0,0,0,0}; a1[nn] = (f32x4){0,0,0,0}; }
#pragma unroll
    for (int d = 0; d < 16; d++) {
      const f32x4* p = reinterpret_cast<const f32x4*>(wt + d * OI + oi0);
      f32x4 v0 = p[0], v1 = p[1];
#pragma unroll
      for (int nn = 0; nn < 8; nn++) {
        float e = e_sh[g * 8 + nn][d];
        a0[nn] += e * v0;
        a1[nn] += e * v1;
      }
    }
#pragma unroll
    for (int nn = 0; nn < 8; nn++) {
      f16x8 pk;
#pragma unroll
      for (int q = 0; q < 4; q++) { pk[q] = (_Float16)a0[nn][q]; pk[4 + q] = (_Float16)a1[nn][q]; }
      int node = bx * 64 + g * 8 + nn;                 // chunk-local
      *reinterpret_cast<f16x8*>(Wout + (size_t)node * OI + oi0) = pk;
    }
  }
}

// ---- 5b. gate (MFMA, R15-proven): z_r = sigmoid(x_g @ W_n + b_n) -----------
__global__ __launch_bounds__(256) void k_gate(const _Float16* __restrict__ xg,   // [b][n][128]
                                              const float* __restrict__ emb,
                                              const _Float16* __restrict__ Wc,   // chunk [2048][128][128] (in xs_t)
                                              const float* __restrict__ gbp,
                                              int n0,
                                              _Float16* __restrict__ zb,         // [n][b][64]
                                              _Float16* __restrict__ rb) {       // [n][b][64]
  int n = n0 + blockIdx.x, tid = threadIdx.x, lane = tid & 63, w = tid >> 6;
  __shared__ __attribute__((aligned(16))) _Float16 As[64 * 64];
  __shared__ __attribute__((aligned(16))) _Float16 Bs[128 * 64];
  __shared__ float bias_sh[128];
  const _Float16* wrow = Wc + (size_t)blockIdx.x * 16384;
  if (tid < 128) {
    float s = 0.f;
#pragma unroll
    for (int d = 0; d < 16; d++) s += emb[n * 16 + d] * gbp[d * 128 + tid];
    bias_sh[tid] = s;
  }
  f32x16 acc[2];
#pragma unroll
  for (int fm = 0; fm < 2; fm++)
#pragma unroll
    for (int q = 0; q < 16; q++) acc[fm][q] = 0.f;

  int lrow = lane >> 3;                       // staging row-within-group
  int lcolsw = (((lane & 7) ^ lrow) * 8);     // pre-swizzled source column
  int r32 = lane & 31, hi32 = lane >> 5;
  int swz = (r32 & 7) * 8;                    // read-side XOR (elem units)
  for (int k0 = 0; k0 < 128; k0 += 64) {
    __syncthreads();
#pragma unroll
    for (int i = 0; i < 2; i++) {             // A: 64 rows (b)
      int j = w * 2 + i;
      int row = j * 8 + lrow;
      gload_lds16(xg + ((size_t)row * 4096 + n) * 128 + k0 + lcolsw, &As[j * 512]);
    }
#pragma unroll
    for (int i = 0; i < 4; i++) {             // B: 128 rows (o)
      int j = w * 4 + i;
      int row = j * 8 + lrow;
      gload_lds16(wrow + row * 128 + k0 + lcolsw, &Bs[j * 512]);
    }
    __syncthreads();
#pragma unroll
    for (int kk = 0; kk < 4; kk++) {
      int col = (kk * 16 + hi32 * 8) ^ swz;
      f16x8 bf = *reinterpret_cast<const f16x8*>(&Bs[(w * 32 + r32) * 64 + col]);
#pragma unroll
      for (int fm = 0; fm < 2; fm++) {
        f16x8 af = *reinterpret_cast<const f16x8*>(&As[(fm * 32 + r32) * 64 + col]);
        acc[fm] = __builtin_amdgcn_mfma_f32_32x32x16_f16(af, bf, acc[fm], 0, 0, 0);
      }
    }
  }
  int o = w * 32 + r32;                       // wave-uniform half: w<2 -> z
  float bias = bias_sh[o];
#pragma unroll
  for (int fm = 0; fm < 2; fm++)
#pragma unroll
    for (int reg = 0; reg < 16; reg++) {
      int brow = fm * 32 + (reg & 3) + 8 * (reg >> 2) + 4 * hi32;
      float val = acc[fm][reg] + bias;
      float sg = 1.f / (1.f + __expf(-val));
      if (o < 64) zb[(n * 64 + brow) * 64 + o] = (_Float16)sg;
      else        rb[(n * 64 + brow) * 64 + (o - 64)] = (_Float16)sg;
    }
}

// ------------- 6. xs_t[b][64+o][m] = f16(z[m][b][o] * state[b][m][o]) -------
__global__ __launch_bounds__(256) void k_cand(const _Float16* __restrict__ zb,
                                              const float* __restrict__ st,
                                              _Float16* __restrict__ xs_t) {
  int m0 = blockIdx.x * 64, b = blockIdx.y, tid = threadIdx.x;
  __shared__ __attribute__((aligned(16))) _Float16 T[64][66];
#pragma unroll
  for (int i = 0; i < 16; i++) {
    int li = i * 256 + tid, ml = li >> 6, o = li & 63;
    float z = (float)zb[((m0 + ml) * 64 + b) * 64 + o];
    float s = st[(b * 4096 + m0 + ml) * 64 + o];
    T[ml][o] = (_Float16)(z * s);
  }
  __syncthreads();
  int og = tid >> 3, mch = tid & 7;
#pragma unroll
  for (int cb = 0; cb < 2; cb++) {
    int o = cb * 32 + og;
    f16x8 tmp;
#pragma unroll
    for (int j = 0; j < 8; j++) tmp[j] = T[mch * 8 + j][o];
    *reinterpret_cast<f16x8*>(&xs_t[(b * 128 + 64 + o) * 4096 + m0 + mch * 8]) = tmp;
  }
}

// ---- 7. update (MFMA, R16-proven): hc=tanh(xg2 @ Wu_n + bu);
//      h = r*state + (1-r)*hc -> out. Wave w owns fragment (fm=w>>1, fn=w&1).
__global__ __launch_bounds__(256) void k_upd(const _Float16* __restrict__ xg2,   // [b][n][128]
                                             const float* __restrict__ emb,
                                             const _Float16* __restrict__ Wc,    // chunk [2048][64][128]
                                             const float* __restrict__ ubp,
                                             int n0,
                                             const _Float16* __restrict__ rb,    // [n][b][64]
                                             const float* __restrict__ st,
                                             float* __restrict__ out) {
  int n = n0 + blockIdx.x, tid = threadIdx.x, lane = tid & 63, w = tid >> 6;
  int fm = w >> 1, fn = w & 1;
  __shared__ __attribute__((aligned(16))) _Float16 As[64 * 64];
  __shared__ __attribute__((aligned(16))) _Float16 Bs[64 * 64];
  __shared__ float bias_sh[64];
  const _Float16* wrow = Wc + (size_t)blockIdx.x * 8192;
  if (tid < 64) {
    float s = 0.f;
#pragma unroll
    for (int d = 0; d < 16; d++) s += emb[n * 16 + d] * ubp[d * 64 + tid];
    bias_sh[tid] = s;
  }
  f32x16 acc;
#pragma unroll
  for (int q = 0; q < 16; q++) acc[q] = 0.f;

  int lrow = lane >> 3;                       // staging row-within-group
  int lcolsw = (((lane & 7) ^ lrow) * 8);     // pre-swizzled source column
  int r32 = lane & 31, hi32 = lane >> 5;
  int swz = (r32 & 7) * 8;                    // read-side XOR (elem units)
  for (int k0 = 0; k0 < 128; k0 += 64) {
    __syncthreads();
#pragma unroll
    for (int i = 0; i < 2; i++) {             // A: 64 rows (b)
      int j = w * 2 + i;
      int row = j * 8 + lrow;
      gload_lds16(xg2 + ((size_t)row * 4096 + n) * 128 + k0 + lcolsw, &As[j * 512]);
    }
#pragma unroll
    for (int i = 0; i < 2; i++) {             // B: 64 rows (o)
      int j = w * 2 + i;
      int row = j * 8 + lrow;
      gload_lds16(wrow + row * 128 + k0 + lcolsw, &Bs[j * 512]);
    }
    __syncthreads();
#pragma unroll
    for (int kk = 0; kk < 4; kk++) {
      int col = (kk * 16 + hi32 * 8) ^ swz;
      f16x8 af = *reinterpret_cast<const f16x8*>(&As[(fm * 32 + r32) * 64 + col]);
      f16x8 bf = *reinterpret_cast<const f16x8*>(&Bs[(fn * 32 + r32) * 64 + col]);
      acc = __builtin_amdgcn_mfma_f32_32x32x16_f16(af, bf, acc, 0, 0, 0);
    }
  }
  int o = fn * 32 + r32;
  float bias = bias_sh[o];
#pragma unroll
  for (int reg = 0; reg < 16; reg++) {
    int brow = fm * 32 + (reg & 3) + 8 * (reg >> 2) + 4 * hi32;
    float val = acc[reg] + bias;
    float e2 = __expf(2.f * val);
    float hc = 1.f - 2.f / (e2 + 1.f);        // tanh
    float rr = (float)rb[(n * 64 + brow) * 64 + o];
    float s = st[((size_t)brow * 4096 + n) * 64 + o];
    out[((size_t)brow * 4096 + n) * 64 + o] = rr * s + (1.f - rr) * hc;
  }
}

extern "C" void kernel_launch(void* const* d_in, const int* in_sizes, int n_in,
                              void* d_out, int out_size, void* d_ws, size_t ws_size,
                              hipStream_t stream) {
  const float* x   = (const float*)d_in[0];
  const float* st  = (const float*)d_in[1];
  const float* emb = (const float*)d_in[2];
  const float* gwp = (const float*)d_in[3];
  const float* gbp = (const float*)d_in[4];
  const float* uwp = (const float*)d_in[5];
  const float* ubp = (const float*)d_in[6];
  float* out = (float*)d_out;
  char* ws = (char*)d_ws;

  // slot A [0,33.55M): S (alive through gemm2). Gate W chunks live in the
  // ENTIRE xs_t (dead between gemm1 and cand), 2 chunks x 2048 nodes linear.
  _Float16* slotA = (_Float16*)(ws + 0);
  _Float16* xs_t  = (_Float16*)(ws + 33554432);   // 67 MB [b][c][m]
  _Float16* xg    = (_Float16*)(ws + 100663296);  // 67 MB (gemm1 out; gemm2 fills c>=64)
  _Float16* zb    = (_Float16*)(ws + 167772160);  // 33.5 MB [n][b][64]; -> W_u chunks after cand
  _Float16* rb    = (_Float16*)(ws + 201326592);  // 33.5 MB [n][b][64] (alive to upd)
  float* wtg = (float*)(ws + 234881024);          // 1 MB
  float* wtu = (float*)(ws + 235929600);          // 0.5 MB
  if (ws_size < 236453888ull) return;  // fail loudly rather than corrupt

  k_wpoolT<<<1536, 256, 0, stream>>>(gwp, uwp, wtg, wtu);
  k_supports<<<1024, 256, 0, stream>>>(emb, slotA);
  k_concat<<<dim3(64, 64), 256, 0, stream>>>(x, st, xs_t);
  k_gemm<<<dim3(16, 64), 512, 0, stream>>>(slotA, xs_t, xg);
  // gate in 2 chunks of 2048 nodes; W chunks fill all of xs_t linearly
  for (int c = 0; c < 2; c++) {
    k_wall<<<dim3(32, 8), 256, 0, stream>>>(emb, c * 2048, wtg, 16384, xs_t);
    k_gate<<<2048, 256, 0, stream>>>(xg, emb, xs_t, gbp, c * 2048, zb, rb);
  }
  k_cand<<<dim3(64, 64), 256, 0, stream>>>(zb, st, xs_t);
  // GEMM2: S still alive in slotA; only the z*state half
  k_gemm2<<<dim3(16, 32), 512, 0, stream>>>(slotA, xs_t, xg);
  // update in 2 chunks of 2048 nodes; W chunk (33.55 MB) reuses zb slot (dead)
  for (int c = 0; c < 2; c++) {
    k_wall<<<dim3(32, 4), 256, 0, stream>>>(emb, c * 2048, wtu, 8192, zb);
    k_upd<<<2048, 256, 0, stream>>>(xg, emb, zb, ubp, c * 2048, rb, st, out);
  }
}

// Round 21
// 703.214 us; speedup vs baseline: 1.6158x; 1.0514x over previous
//
#include <hip/hip_runtime.h>

typedef float f32x4 __attribute__((ext_vector_type(4)));
typedef float f32x16 __attribute__((ext_vector_type(16)));
typedef _Float16 f16x8 __attribute__((ext_vector_type(8)));
typedef _Float16 f16x4 __attribute__((ext_vector_type(4)));
typedef _Float16 f16x2 __attribute__((ext_vector_type(2)));

typedef __attribute__((address_space(1))) const unsigned char gbyte;
typedef __attribute__((address_space(3))) unsigned char sbyte;
__device__ __forceinline__ void gload_lds16(const void* gp, void* lp) {
  __builtin_amdgcn_global_load_lds((gbyte*)gp, (sbyte*)lp, 16, 0, 0);
}

// ---------------- 1. weight-pool transpose to [d][o][i], f32 ----------------
__global__ __launch_bounds__(256) void k_wpoolT(const float* __restrict__ gwp,
                                                const float* __restrict__ uwp,
                                                float* __restrict__ wtg,
                                                float* __restrict__ wtu) {
  int idx = blockIdx.x * 256 + threadIdx.x;
  if (idx < 16 * 128 * 128) {
    int d = idx >> 14, rem = idx & 16383, o = rem >> 7, i = rem & 127;
    wtg[idx] = gwp[(d << 14) + (i << 7) + o];          // gwp[d][i][o]
  } else {
    int j = idx - 16 * 128 * 128;
    if (j < 16 * 64 * 128) {
      int d = j >> 13, rem = j & 8191, o = rem >> 7, i = rem & 127;
      wtu[j] = uwp[(d << 13) + (i << 6) + o];          // uwp[d][i][o(64)]
    }
  }
}

// -------- 2. supports = softmax(relu(E E^T)), 4 rows/block (emb reuse) ------
__global__ __launch_bounds__(256) void k_supports(const float* __restrict__ emb,
                                                  _Float16* __restrict__ S) {
  int n0 = blockIdx.x * 4, tid = threadIdx.x;
  __shared__ float e_sh[4][16];
  __shared__ float red[4][4];
  if (tid < 16) {
    int r = tid >> 2, part = tid & 3;
    f32x4 v = *reinterpret_cast<const f32x4*>(emb + (n0 + r) * 16 + part * 4);
    *reinterpret_cast<f32x4*>(&e_sh[r][part * 4]) = v;
  }
  __syncthreads();
  float v[4][16];
  float sum[4] = {0.f, 0.f, 0.f, 0.f};
#pragma unroll
  for (int i = 0; i < 16; i++) {
    int m = i * 256 + tid;
    const f32x4* em = reinterpret_cast<const f32x4*>(emb + m * 16);
    f32x4 e0 = em[0], e1 = em[1], e2 = em[2], e3 = em[3];
#pragma unroll
    for (int r = 0; r < 4; r++) {
      float acc = 0.f;
#pragma unroll
      for (int q = 0; q < 4; q++) acc += e_sh[r][q] * e0[q];
#pragma unroll
      for (int q = 0; q < 4; q++) acc += e_sh[r][4 + q] * e1[q];
#pragma unroll
      for (int q = 0; q < 4; q++) acc += e_sh[r][8 + q] * e2[q];
#pragma unroll
      for (int q = 0; q < 4; q++) acc += e_sh[r][12 + q] * e3[q];
      acc = fmaxf(acc, 0.f);
      float e = __expf(acc);
      v[r][i] = e;
      sum[r] += e;
    }
  }
#pragma unroll
  for (int r = 0; r < 4; r++)
#pragma unroll
    for (int off = 32; off > 0; off >>= 1) sum[r] += __shfl_down(sum[r], off);
  if ((tid & 63) == 0) {
#pragma unroll
    for (int r = 0; r < 4; r++) red[tid >> 6][r] = sum[r];
  }
  __syncthreads();
  float inv[4];
#pragma unroll
  for (int r = 0; r < 4; r++)
    inv[r] = 1.f / (red[0][r] + red[1][r] + red[2][r] + red[3][r]);
#pragma unroll
  for (int i = 0; i < 16; i++)
#pragma unroll
    for (int r = 0; r < 4; r++)
      S[(size_t)(n0 + r) * 4096 + i * 256 + tid] = (_Float16)(v[r][i] * inv[r]);
}

// ------- 3. xs_t[b][c][m] = f16(concat(x,state))  (c-major for GEMM B) ------
__global__ __launch_bounds__(256) void k_concat(const float* __restrict__ x,
                                                const float* __restrict__ st,
                                                _Float16* __restrict__ xs_t) {
  int m0 = blockIdx.x * 64, b = blockIdx.y, tid = threadIdx.x;
  __shared__ __attribute__((aligned(16))) _Float16 T[64][130];
#pragma unroll
  for (int i = 0; i < 16; i++) {
    int li = i * 256 + tid;
    int ml = li >> 6, c = li & 63;
    int base = (b * 4096 + m0 + ml) * 64 + c;
    T[ml][c] = (_Float16)x[base];
    T[ml][64 + c] = (_Float16)st[base];
  }
  __syncthreads();
  int cg = tid >> 3, mch = tid & 7;
#pragma unroll
  for (int cb = 0; cb < 4; cb++) {
    int c = cb * 32 + cg;
    f16x8 tmp;
#pragma unroll
    for (int j = 0; j < 8; j++) tmp[j] = T[mch * 8 + j][c];
    *reinterpret_cast<f16x8*>(&xs_t[(b * 128 + c) * 4096 + m0 + mch * 8]) = tmp;
  }
}

// -------- 4. GEMM1 (R20-proven 256Mx128N, 512 thr; Y now [n][b][128]) -------
__global__ __launch_bounds__(512) void k_gemm(const _Float16* __restrict__ S,
                                              const _Float16* __restrict__ Xt,
                                              _Float16* __restrict__ Y) {
  int nt = blockIdx.x, b = blockIdx.y;       // x fastest: consecutive share Xb
  int tid = threadIdx.x, lane = tid & 63, w = tid >> 6;   // w 0..7
  int wr = w >> 1, wc = w & 1;               // 4 x 2 wave grid
  __shared__ __attribute__((aligned(16))) _Float16 As[256 * 64];
  __shared__ __attribute__((aligned(16))) _Float16 Bs[128 * 64];
  const _Float16* Sb = S + (size_t)nt * 256 * 4096;
  const _Float16* Xb = Xt + (size_t)b * 128 * 4096;
  f32x16 acc[2][2];
#pragma unroll
  for (int fm = 0; fm < 2; fm++)
#pragma unroll
    for (int fn = 0; fn < 2; fn++)
#pragma unroll
      for (int q = 0; q < 16; q++) acc[fm][fn][q] = 0.f;

  int lrow = lane >> 3;                       // staging row-within-group
  int lcolsw = (((lane & 7) ^ lrow) * 8);     // pre-swizzled source column
  int r32 = lane & 31, hi32 = lane >> 5;
  int swz = (r32 & 7) * 8;                    // read-side XOR (elem units)
  for (int k0 = 0; k0 < 4096; k0 += 64) {
    __syncthreads();
#pragma unroll
    for (int i = 0; i < 4; i++) {             // A: 256 rows, 32 j-groups
      int j = w * 4 + i;
      int row = j * 8 + lrow;
      gload_lds16(Sb + (size_t)row * 4096 + k0 + lcolsw, &As[j * 512]);
    }
#pragma unroll
    for (int i = 0; i < 2; i++) {             // B: 128 rows, 16 j-groups
      int j = w * 2 + i;
      int row = j * 8 + lrow;
      gload_lds16(Xb + (size_t)row * 4096 + k0 + lcolsw, &Bs[j * 512]);
    }
    __syncthreads();
#pragma unroll
    for (int kk = 0; kk < 4; kk++) {
      int col = (kk * 16 + hi32 * 8) ^ swz;
      f16x8 af[2], bf[2];
#pragma unroll
      for (int fm = 0; fm < 2; fm++)
        af[fm] = *reinterpret_cast<const f16x8*>(&As[(wr * 64 + fm * 32 + r32) * 64 + col]);
#pragma unroll
      for (int fn = 0; fn < 2; fn++)
        bf[fn] = *reinterpret_cast<const f16x8*>(&Bs[(wc * 64 + fn * 32 + r32) * 64 + col]);
#pragma unroll
      for (int fm = 0; fm < 2; fm++)
#pragma unroll
        for (int fn = 0; fn < 2; fn++)
          acc[fm][fn] = __builtin_amdgcn_mfma_f32_32x32x16_f16(af[fm], bf[fn], acc[fm][fn], 0, 0, 0);
    }
  }
#pragma unroll
  for (int fm = 0; fm < 2; fm++)
#pragma unroll
    for (int fn = 0; fn < 2; fn++)
#pragma unroll
      for (int reg = 0; reg < 16; reg++) {
        int row = nt * 256 + wr * 64 + fm * 32 + (reg & 3) + 8 * (reg >> 2) + 4 * hi32;
        int c = wc * 64 + fn * 32 + r32;
        Y[((size_t)row * 64 + b) * 128 + c] = (_Float16)acc[fm][fn][reg];   // [n][b][128]
      }
}

// -------- 4b. GEMM2 (R20-proven half-N, 512 thr; Y [n][b][128]) -------------
__global__ __launch_bounds__(512) void k_gemm2(const _Float16* __restrict__ S,
                                               const _Float16* __restrict__ Xt,
                                               _Float16* __restrict__ Y) {
  int nt = blockIdx.x, bp = blockIdx.y;
  int tid = threadIdx.x, lane = tid & 63, w = tid >> 6;
  int wr = w >> 1, wc = w & 1;
  __shared__ __attribute__((aligned(16))) _Float16 As[256 * 64];
  __shared__ __attribute__((aligned(16))) _Float16 Bs[128 * 64];
  const _Float16* Sb = S + (size_t)nt * 256 * 4096;
  const _Float16* Xb = Xt + (size_t)(256 * bp + 64) * 4096;
  f32x16 acc[2][2];
#pragma unroll
  for (int fm = 0; fm < 2; fm++)
#pragma unroll
    for (int fn = 0; fn < 2; fn++)
#pragma unroll
      for (int q = 0; q < 16; q++) acc[fm][fn][q] = 0.f;

  int lrow = lane >> 3;
  int lcolsw = (((lane & 7) ^ lrow) * 8);
  int r32 = lane & 31, hi32 = lane >> 5;
  int swz = (r32 & 7) * 8;
  for (int k0 = 0; k0 < 4096; k0 += 64) {
    __syncthreads();
#pragma unroll
    for (int i = 0; i < 4; i++) {             // A: 256 rows
      int j = w * 4 + i;
      int row = j * 8 + lrow;
      gload_lds16(Sb + (size_t)row * 4096 + k0 + lcolsw, &As[j * 512]);
    }
#pragma unroll
    for (int i = 0; i < 2; i++) {             // B: 128 rows (batch-pair map)
      int j = w * 2 + i;
      int row = j * 8 + lrow;                              // 0..127 tile row
      int groff = ((row >> 6) * 128 + (row & 63)) * 4096;
      gload_lds16(Xb + (size_t)groff + k0 + lcolsw, &Bs[j * 512]);
    }
    __syncthreads();
#pragma unroll
    for (int kk = 0; kk < 4; kk++) {
      int col = (kk * 16 + hi32 * 8) ^ swz;
      f16x8 af[2], bf[2];
#pragma unroll
      for (int fm = 0; fm < 2; fm++)
        af[fm] = *reinterpret_cast<const f16x8*>(&As[(wr * 64 + fm * 32 + r32) * 64 + col]);
#pragma unroll
      for (int fn = 0; fn < 2; fn++)
        bf[fn] = *reinterpret_cast<const f16x8*>(&Bs[(wc * 64 + fn * 32 + r32) * 64 + col]);
#pragma unroll
      for (int fm = 0; fm < 2; fm++)
#pragma unroll
        for (int fn = 0; fn < 2; fn++)
          acc[fm][fn] = __builtin_amdgcn_mfma_f32_32x32x16_f16(af[fm], bf[fn], acc[fm][fn], 0, 0, 0);
    }
  }
#pragma unroll
  for (int fm = 0; fm < 2; fm++)
#pragma unroll
    for (int fn = 0; fn < 2; fn++)
#pragma unroll
      for (int reg = 0; reg < 16; reg++) {
        int row = nt * 256 + wr * 64 + fm * 32 + (reg & 3) + 8 * (reg >> 2) + 4 * hi32;
        int ct = wc * 64 + fn * 32 + r32;       // 0..127 tile col
        int batch = 2 * bp + (ct >> 6);
        int c = 64 + (ct & 63);
        Y[((size_t)row * 64 + batch) * 128 + c] = (_Float16)acc[fm][fn][reg];  // [n][b][128]
      }
}

// ---- 5a. k_wall: W_all[node][o*i] = f16( sum_d E[n0+node][d] * wt[d][o*i] )
__global__ __launch_bounds__(256) void k_wall(const float* __restrict__ emb, int n0,
                                              const float* __restrict__ wt, int OI,
                                              _Float16* __restrict__ Wout) {
  int bx = blockIdx.x, by = blockIdx.y, tid = threadIdx.x;
  __shared__ float e_sh[64][16];
  {
    int node = tid >> 2, part = tid & 3;
    f32x4 v = *reinterpret_cast<const f32x4*>(emb + (n0 + bx * 64 + node) * 16 + part * 4);
    *reinterpret_cast<f32x4*>(&e_sh[node][part * 4]) = v;
  }
  __syncthreads();
  int oi0 = by * 2048 + tid * 8;
#pragma unroll
  for (int g = 0; g < 8; g++) {
    f32x4 a0[8], a1[8];
#pragma unroll
    for (int nn = 0; nn < 8; nn++) { a0[nn] = (f32x4){0,0,0,0}; a1[nn] = (f32x4){0,0,0,0}; }
#pragma unroll
    for (int d = 0; d < 16; d++) {
      const f32x4* p = reinterpret_cast<const f32x4*>(wt + d * OI + oi0);
      f32x4 v0 = p[0], v1 = p[1];
#pragma unroll
      for (int nn = 0; nn < 8; nn++) {
        float e = e_sh[g * 8 + nn][d];
        a0[nn] += e * v0;
        a1[nn] += e * v1;
      }
    }
#pragma unroll
    for (int nn = 0; nn < 8; nn++) {
      f16x8 pk;
#pragma unroll
      for (int q = 0; q < 4; q++) { pk[q] = (_Float16)a0[nn][q]; pk[4 + q] = (_Float16)a1[nn][q]; }
      int node = bx * 64 + g * 8 + nn;                 // chunk-local
      *reinterpret_cast<f16x8*>(Wout + (size_t)node * OI + oi0) = pk;
    }
  }
}

// ---- 5b. gate (MFMA, R15-proven; xg now [n][b][128] -> contiguous A) -------
__global__ __launch_bounds__(256) void k_gate(const _Float16* __restrict__ xg,   // [n][b][128]
                                              const float* __restrict__ emb,
                                              const _Float16* __restrict__ Wc,   // chunk [2048][128][128] (in xs_t)
                                              const float* __restrict__ gbp,
                                              int n0,
                                              _Float16* __restrict__ zb,         // [n][b][64]
                                              _Float16* __restrict__ rb) {       // [n][b][64]
  int n = n0 + blockIdx.x, tid = threadIdx.x, lane = tid & 63, w = tid >> 6;
  __shared__ __attribute__((aligned(16))) _Float16 As[64 * 64];
  __shared__ __attribute__((aligned(16))) _Float16 Bs[128 * 64];
  __shared__ float bias_sh[128];
  const _Float16* wrow = Wc + (size_t)blockIdx.x * 16384;
  const _Float16* arow = xg + (size_t)n * 8192;        // contiguous [b][128]
  if (tid < 128) {
    float s = 0.f;
#pragma unroll
    for (int d = 0; d < 16; d++) s += emb[n * 16 + d] * gbp[d * 128 + tid];
    bias_sh[tid] = s;
  }
  f32x16 acc[2];
#pragma unroll
  for (int fm = 0; fm < 2; fm++)
#pragma unroll
    for (int q = 0; q < 16; q++) acc[fm][q] = 0.f;

  int lrow = lane >> 3;                       // staging row-within-group
  int lcolsw = (((lane & 7) ^ lrow) * 8);     // pre-swizzled source column
  int r32 = lane & 31, hi32 = lane >> 5;
  int swz = (r32 & 7) * 8;                    // read-side XOR (elem units)
  for (int k0 = 0; k0 < 128; k0 += 64) {
    __syncthreads();
#pragma unroll
    for (int i = 0; i < 2; i++) {             // A: 64 rows (b)
      int j = w * 2 + i;
      int row = j * 8 + lrow;
      gload_lds16(arow + row * 128 + k0 + lcolsw, &As[j * 512]);
    }
#pragma unroll
    for (int i = 0; i < 4; i++) {             // B: 128 rows (o)
      int j = w * 4 + i;
      int row = j * 8 + lrow;
      gload_lds16(wrow + row * 128 + k0 + lcolsw, &Bs[j * 512]);
    }
    __syncthreads();
#pragma unroll
    for (int kk = 0; kk < 4; kk++) {
      int col = (kk * 16 + hi32 * 8) ^ swz;
      f16x8 bf = *reinterpret_cast<const f16x8*>(&Bs[(w * 32 + r32) * 64 + col]);
#pragma unroll
      for (int fm = 0; fm < 2; fm++) {
        f16x8 af = *reinterpret_cast<const f16x8*>(&As[(fm * 32 + r32) * 64 + col]);
        acc[fm] = __builtin_amdgcn_mfma_f32_32x32x16_f16(af, bf, acc[fm], 0, 0, 0);
      }
    }
  }
  int o = w * 32 + r32;                       // wave-uniform half: w<2 -> z
  float bias = bias_sh[o];
#pragma unroll
  for (int fm = 0; fm < 2; fm++)
#pragma unroll
    for (int reg = 0; reg < 16; reg++) {
      int brow = fm * 32 + (reg & 3) + 8 * (reg >> 2) + 4 * hi32;
      float val = acc[fm][reg] + bias;
      float sg = 1.f / (1.f + __expf(-val));
      if (o < 64) zb[(n * 64 + brow) * 64 + o] = (_Float16)sg;
      else        rb[(n * 64 + brow) * 64 + (o - 64)] = (_Float16)sg;
    }
}

// ------------- 6. xs_t[b][64+o][m] = f16(z[m][b][o] * state[b][m][o]) -------
__global__ __launch_bounds__(256) void k_cand(const _Float16* __restrict__ zb,
                                              const float* __restrict__ st,
                                              _Float16* __restrict__ xs_t) {
  int m0 = blockIdx.x * 64, b = blockIdx.y, tid = threadIdx.x;
  __shared__ __attribute__((aligned(16))) _Float16 T[64][66];
#pragma unroll
  for (int i = 0; i < 16; i++) {
    int li = i * 256 + tid, ml = li >> 6, o = li & 63;
    float z = (float)zb[((m0 + ml) * 64 + b) * 64 + o];
    float s = st[(b * 4096 + m0 + ml) * 64 + o];
    T[ml][o] = (_Float16)(z * s);
  }
  __syncthreads();
  int og = tid >> 3, mch = tid & 7;
#pragma unroll
  for (int cb = 0; cb < 2; cb++) {
    int o = cb * 32 + og;
    f16x8 tmp;
#pragma unroll
    for (int j = 0; j < 8; j++) tmp[j] = T[mch * 8 + j][o];
    *reinterpret_cast<f16x8*>(&xs_t[(b * 128 + 64 + o) * 4096 + m0 + mch * 8]) = tmp;
  }
}

// ---- 7. update (MFMA, R16-proven; xg [n][b][128], single 4096-node grid) ---
__global__ __launch_bounds__(256) void k_upd(const _Float16* __restrict__ xg2,   // [n][b][128]
                                             const float* __restrict__ emb,
                                             const _Float16* __restrict__ Wc,    // [4096][64][128] (in xs_t)
                                             const float* __restrict__ ubp,
                                             const _Float16* __restrict__ rb,    // [n][b][64]
                                             const float* __restrict__ st,
                                             float* __restrict__ out) {
  int n = blockIdx.x, tid = threadIdx.x, lane = tid & 63, w = tid >> 6;
  int fm = w >> 1, fn = w & 1;
  __shared__ __attribute__((aligned(16))) _Float16 As[64 * 64];
  __shared__ __attribute__((aligned(16))) _Float16 Bs[64 * 64];
  __shared__ float bias_sh[64];
  const _Float16* wrow = Wc + (size_t)n * 8192;
  const _Float16* arow = xg2 + (size_t)n * 8192;       // contiguous [b][128]
  if (tid < 64) {
    float s = 0.f;
#pragma unroll
    for (int d = 0; d < 16; d++) s += emb[n * 16 + d] * ubp[d * 64 + tid];
    bias_sh[tid] = s;
  }
  f32x16 acc;
#pragma unroll
  for (int q = 0; q < 16; q++) acc[q] = 0.f;

  int lrow = lane >> 3;                       // staging row-within-group
  int lcolsw = (((lane & 7) ^ lrow) * 8);     // pre-swizzled source column
  int r32 = lane & 31, hi32 = lane >> 5;
  int swz = (r32 & 7) * 8;                    // read-side XOR (elem units)
  for (int k0 = 0; k0 < 128; k0 += 64) {
    __syncthreads();
#pragma unroll
    for (int i = 0; i < 2; i++) {             // A: 64 rows (b)
      int j = w * 2 + i;
      int row = j * 8 + lrow;
      gload_lds16(arow + row * 128 + k0 + lcolsw, &As[j * 512]);
    }
#pragma unroll
    for (int i = 0; i < 2; i++) {             // B: 64 rows (o)
      int j = w * 2 + i;
      int row = j * 8 + lrow;
      gload_lds16(wrow + row * 128 + k0 + lcolsw, &Bs[j * 512]);
    }
    __syncthreads();
#pragma unroll
    for (int kk = 0; kk < 4; kk++) {
      int col = (kk * 16 + hi32 * 8) ^ swz;
      f16x8 af = *reinterpret_cast<const f16x8*>(&As[(fm * 32 + r32) * 64 + col]);
      f16x8 bf = *reinterpret_cast<const f16x8*>(&Bs[(fn * 32 + r32) * 64 + col]);
      acc = __builtin_amdgcn_mfma_f32_32x32x16_f16(af, bf, acc, 0, 0, 0);
    }
  }
  int o = fn * 32 + r32;
  float bias = bias_sh[o];
#pragma unroll
  for (int reg = 0; reg < 16; reg++) {
    int brow = fm * 32 + (reg & 3) + 8 * (reg >> 2) + 4 * hi32;
    float val = acc[reg] + bias;
    float e2 = __expf(2.f * val);
    float hc = 1.f - 2.f / (e2 + 1.f);        // tanh
    float rr = (float)rb[(n * 64 + brow) * 64 + o];
    float s = st[((size_t)brow * 4096 + n) * 64 + o];
    out[((size_t)brow * 4096 + n) * 64 + o] = rr * s + (1.f - rr) * hc;
  }
}

extern "C" void kernel_launch(void* const* d_in, const int* in_sizes, int n_in,
                              void* d_out, int out_size, void* d_ws, size_t ws_size,
                              hipStream_t stream) {
  const float* x   = (const float*)d_in[0];
  const float* st  = (const float*)d_in[1];
  const float* emb = (const float*)d_in[2];
  const float* gwp = (const float*)d_in[3];
  const float* gbp = (const float*)d_in[4];
  const float* uwp = (const float*)d_in[5];
  const float* ubp = (const float*)d_in[6];
  float* out = (float*)d_out;
  char* ws = (char*)d_ws;

  // slot A [0,33.55M): S (alive through gemm2). Gate W chunks live in xs_t
  // (dead gemm1->cand), 2 x 2048 nodes. Upd W fills ALL of xs_t (dead after
  // gemm2) in ONE 4096-node chunk. xg is [n][b][128] (transposed).
  _Float16* slotA = (_Float16*)(ws + 0);
  _Float16* xs_t  = (_Float16*)(ws + 33554432);   // 67 MB [b][c][m]
  _Float16* xg    = (_Float16*)(ws + 100663296);  // 67 MB [n][b][128]
  _Float16* zb    = (_Float16*)(ws + 167772160);  // 33.5 MB [n][b][64]
  _Float16* rb    = (_Float16*)(ws + 201326592);  // 33.5 MB [n][b][64] (alive to upd)
  float* wtg = (float*)(ws + 234881024);          // 1 MB
  float* wtu = (float*)(ws + 235929600);          // 0.5 MB
  if (ws_size < 236453888ull) return;  // fail loudly rather than corrupt

  k_wpoolT<<<1536, 256, 0, stream>>>(gwp, uwp, wtg, wtu);
  k_supports<<<1024, 256, 0, stream>>>(emb, slotA);
  k_concat<<<dim3(64, 64), 256, 0, stream>>>(x, st, xs_t);
  k_gemm<<<dim3(16, 64), 512, 0, stream>>>(slotA, xs_t, xg);
  // gate in 2 chunks of 2048 nodes; W chunks fill xs_t linearly
  for (int c = 0; c < 2; c++) {
    k_wall<<<dim3(32, 8), 256, 0, stream>>>(emb, c * 2048, wtg, 16384, xs_t);
    k_gate<<<2048, 256, 0, stream>>>(xg, emb, xs_t, gbp, c * 2048, zb, rb);
  }
  k_cand<<<dim3(64, 64), 256, 0, stream>>>(zb, st, xs_t);
  // GEMM2: S still alive in slotA; only the z*state half
  k_gemm2<<<dim3(16, 32), 512, 0, stream>>>(slotA, xs_t, xg);
  // update: ONE chunk of 4096 nodes; W fills all of xs_t (dead after gemm2)
  k_wall<<<dim3(64, 4), 256, 0, stream>>>(emb, 0, wtu, 8192, xs_t);
  k_upd<<<4096, 256, 0, stream>>>(xg, emb, xs_t, ubp, rb, st, out);
}